// Round 13
// baseline (1004.912 us; speedup 1.0000x reference)
//
#include <hip/hip_runtime.h>

#define OUTC (16ull*1024*64*64)

typedef unsigned short u16;
typedef __attribute__((ext_vector_type(8))) __bf16 bf16x8;
typedef __attribute__((ext_vector_type(4))) float f32x4;

struct GP { const float* w[4]; float* g[4]; };
struct UP { const float* rec[3]; };
struct MGP {
  const u16* A[4]; const u16* B[4]; float* C[4];
  int K[4]; int lda[4]; int ldb[4]; int ldcPP[4]; int CH[4]; int coff[4];
  int base[4]; int gx[4]; int nwg;
};
struct MG2 {
  const u16* A[4]; const u16* B[4]; float* C[4];
  int K[4]; int lda[4]; int ldb[4]; int ldcPP[4]; int CH[4];
  int base[4]; int gx[4]; int nwg;
};
struct RFP {
  u16* S[4]; const u16* x2[4]; const float* W[4]; int T[4];
  u16* nzi[4]; float* nzv[4]; int* cnt[4];
};

__device__ __forceinline__ u16 f2bf(float f) {
  unsigned u = __float_as_uint(f);
  unsigned r = (u + 0x7fffu + ((u >> 16) & 1u)) >> 16;
  return (u16)r;
}
__device__ __forceinline__ float bf2f(u16 h) {
  return __uint_as_float(((unsigned)h) << 16);
}

// async global->LDS, 16B per lane; LDS dest = wave-uniform base + lane*16.
__device__ __forceinline__ void gload16(const void* gsrc, void* ldst) {
  __builtin_amdgcn_global_load_lds(
      (const __attribute__((address_space(1))) void*)gsrc,
      (__attribute__((address_space(3))) void*)ldst, 16, 0, 0);
}

__device__ __forceinline__ float block_sum(float v, float* red) {
  int tid = threadIdx.x;
  red[tid] = v; __syncthreads();
#pragma unroll
  for (int s = 128; s > 0; s >>= 1) {
    if (tid < s) red[tid] += red[tid + s];
    __syncthreads();
  }
  float r = red[0];
  __syncthreads();
  return r;
}

__device__ __forceinline__ float wave_sum(float v) {
#pragma unroll
  for (int m = 32; m > 0; m >>= 1) v += __shfl_xor(v, m, 64);
  return v;
}

__global__ void zero_k(float* part, float* losses) {
  if (blockIdx.x < 12) part[blockIdx.x*256 + threadIdx.x] = 0.f;
  else if (threadIdx.x < 5) losses[threadIdx.x] = 0.f;
}

// ONE pass over x: blk64 token rows (split bf16) AND blk32 pooled level.
__global__ __launch_bounds__(256) void gather_pool_k(const float* __restrict__ x,
    u16* __restrict__ x2s64, u16* __restrict__ x2s32) {
  __shared__ float lds[32][130];
  int tid = threadIdx.x;
  int b = blockIdx.x;
  int orow = b & 31, ct = (b >> 5) & 7, bb = b >> 8;
  const float* xb = x + ((size_t)(bb*256 + ct*32))*4096 + orow*128;
#pragma unroll
  for (int p = 0; p < 4; p++) {
    int s = p*256 + tid;
    int c = s >> 5, f = s & 31;
    float4 v = *(const float4*)(xb + (size_t)c*4096 + f*4);
    lds[c][f*4+0] = v.x; lds[c][f*4+1] = v.y;
    lds[c][f*4+2] = v.z; lds[c][f*4+3] = v.w;
  }
  __syncthreads();
  {
    int cg = (tid & 3) * 8;
#pragma unroll
    for (int it = 0; it < 2; it++) {
      int tl = it*64 + (tid >> 2);
      size_t row = ((size_t)bb*4096 + (size_t)orow*128 + tl)*512 + ct*32 + cg;
      u16 hi[8], lo[8];
#pragma unroll
      for (int e = 0; e < 8; e++) {
        float v = lds[cg + e][tl];
        hi[e] = f2bf(v);
        lo[e] = f2bf(v - bf2f(hi[e]));
      }
      *(uint4*)&x2s64[row]       = *(uint4*)hi;
      *(uint4*)&x2s64[row + 256] = *(uint4*)lo;
    }
  }
  {
    int c = tid & 31;
#pragma unroll
    for (int p = 0; p < 4; p++) {
      int w = p*8 + (tid >> 5);
      float m = fmaxf(fmaxf(lds[c][2*w], lds[c][2*w+1]),
                      fmaxf(lds[c][64+2*w], lds[c][64+2*w+1]));
      u16 h = f2bf(m);
      size_t o = ((size_t)bb*1024 + (size_t)orow*32 + w)*512 + ct*32 + c;
      x2s32[o] = h;
      x2s32[o + 256] = f2bf(m - bf2f(h));
    }
  }
}

__global__ __launch_bounds__(256) void pool_half_k(const u16* __restrict__ src,
    u16* __restrict__ dst, int blk) {
  int t = blockIdx.x, c = threadIdx.x;
  int bb = t / (blk*blk), rw = t - bb*blk*blk;
  int r = rw / blk, w = rw - r*blk;
  int bp = blk*2;
  int pb = bb*bp*bp;
  float m = -INFINITY;
#pragma unroll
  for (int dy = 0; dy < 2; dy++)
#pragma unroll
    for (int dx = 0; dx < 2; dx++) {
      size_t rr = (size_t)(pb + (2*r+dy)*bp + 2*w+dx)*512 + c;
      m = fmaxf(m, bf2f(src[rr]) + bf2f(src[rr+256]));
    }
  u16 h = f2bf(m);
  size_t o = (size_t)t*512 + c;
  dst[o] = h; dst[o+256] = f2bf(m - bf2f(h));
}

// Merged wsplit + wnorm. Ws1 = hi-only [M][256]. grid = 1920.
__global__ __launch_bounds__(256) void wprep_k(GP gp,
    u16* __restrict__ Ws1, float* __restrict__ losses) {
  __shared__ float red[256];
  int b = blockIdx.x;
  int bi, m, M; size_t s1off;
  if (b < 1024)      { bi=0; m=b;      M=1024; s1off=0; }
  else if (b < 1536) { bi=1; m=b-1024; M=512;  s1off=(size_t)1024*256; }
  else if (b < 1792) { bi=2; m=b-1536; M=256;  s1off=(size_t)1536*256; }
  else               { bi=3; m=b-1792; M=128;  s1off=(size_t)1792*256; }
  int c = threadIdx.x;
  float w = gp.w[bi][(size_t)m*256 + c];
  Ws1[s1off + (size_t)m*256 + c] = f2bf(w);
  float s = block_sum(w*w, red);
  if (c == 0) atomicAdd(&losses[2], fabsf(1.f - sqrtf(s)) / (float)M);
}

// Merged exact-f32 W*W^T. grid = 340.
__global__ __launch_bounds__(256) void sgemmbt_all_k(GP gp) {
  __shared__ float As[32][64];
  __shared__ float Bs[32][64];
  int b = blockIdx.x;
  int bi, lt, M, lg;
  if (b < 256)      { bi=0; lt=b;     M=1024; lg=4; }
  else if (b < 320) { bi=1; lt=b-256; M=512;  lg=3; }
  else if (b < 336) { bi=2; lt=b-320; M=256;  lg=2; }
  else              { bi=3; lt=b-336; M=128;  lg=1; }
  const float* A = gp.w[bi];
  float* C = gp.g[bi];
  int gx = 1 << lg;
  int bx = lt & (gx-1), by = lt >> lg;
  int tid = threadIdx.x;
  int tx = tid & 15, ty = tid >> 4;
  int row0 = by << 6, col0 = bx << 6;
  float acc[4][4] = {};
  for (int k0 = 0; k0 < 256; k0 += 32) {
#pragma unroll
    for (int l = 0; l < 2; l++) {
      int i = tid + l*256;
      int kq = i & 7, m = i >> 3;
      float4 v = *(const float4*)(A + (size_t)(row0 + m)*256 + k0 + kq*4);
      As[kq*4+0][m] = v.x; As[kq*4+1][m] = v.y; As[kq*4+2][m] = v.z; As[kq*4+3][m] = v.w;
      float4 w = *(const float4*)(A + (size_t)(col0 + m)*256 + k0 + kq*4);
      Bs[kq*4+0][m] = w.x; Bs[kq*4+1][m] = w.y; Bs[kq*4+2][m] = w.z; Bs[kq*4+3][m] = w.w;
    }
    __syncthreads();
#pragma unroll
    for (int kk = 0; kk < 32; kk++) {
      float4 a = *(const float4*)&As[kk][ty*4];
      float4 bvv = *(const float4*)&Bs[kk][tx*4];
      float av[4] = {a.x, a.y, a.z, a.w};
      float bv[4] = {bvv.x, bvv.y, bvv.z, bvv.w};
#pragma unroll
      for (int i = 0; i < 4; i++)
#pragma unroll
        for (int j = 0; j < 4; j++)
          acc[i][j] = fmaf(av[i], bv[j], acc[i][j]);
    }
    __syncthreads();
  }
#pragma unroll
  for (int i = 0; i < 4; i++)
#pragma unroll
    for (int j = 0; j < 4; j++)
      C[(size_t)(row0 + ty*4 + i)*M + col0 + tx*4 + j] = acc[i][j];
}

// Merged wdist. grid = 5440.
__global__ __launch_bounds__(256) void wdist_all_k(GP gp, float* __restrict__ losses) {
  __shared__ float red[256];
  int b = blockIdx.x;
  int bi, lb, M;
  if (b < 4096)      { bi=0; lb=b;      M=1024; }
  else if (b < 5120) { bi=1; lb=b-4096; M=512; }
  else if (b < 5376) { bi=2; lb=b-5120; M=256; }
  else               { bi=3; lb=b-5376; M=128; }
  const float* G = gp.g[bi];
  int idx = lb*256 + threadIdx.x;
  float acc = 0.f;
  int i = idx / M, j = idx - i*M;
  if (j > i) {
    float d2 = G[(size_t)i*M + i] + G[(size_t)j*M + j] - 2.f*G[(size_t)i*M + j];
    float dist = 1.f - d2;
    if (dist > 0.f) acc = dist;
  }
  float s = block_sum(acc, red);
  if (threadIdx.x == 0) atomicAdd(&losses[4], s * 2.f / ((float)M * (float)(M - 1)));
}

// 128x128-tile MFMA GEMM (2-barrier). !SCATTER: bf16 out (logits path).
template<bool SCATTER>
__global__ __launch_bounds__(256) void mgemm_all_k(MGP P) {
  __shared__ __align__(16) u16 As[128*64];
  __shared__ __align__(16) u16 Bs[128*64];
  int wg = blockIdx.x;
  int nwg = P.nwg;
  int q = nwg >> 3, r = nwg & 7;
  int xcd = wg & 7, cidx = wg >> 3;
  int swz = (xcd < r ? xcd*(q+1) : r*(q+1) + (xcd - r)*q) + cidx;
  int bi = (swz >= P.base[1]) + (swz >= P.base[2]) + (swz >= P.base[3]);
  int lt = swz - P.base[bi];
  int gx = P.gx[bi];
  int bx = lt % gx, by = lt / gx;
  const u16* A = P.A[bi];
  const u16* B = P.B[bi];
  float* C = P.C[bi];
  int K = P.K[bi], lda = P.lda[bi], ldb = P.ldb[bi];

  int tid = threadIdx.x;
  int lane = tid & 63;
  int wid = tid >> 6;
  int wr = wid >> 1, wc = wid & 1;
  int fr = lane & 15, ks = lane >> 4;
  int row0 = by << 7, col0 = bx << 7;
  f32x4 acc[4][4] = {};
  int srow = tid >> 3;
  int scol = ((tid & 7) ^ (srow & 7)) * 8;
  const u16* Ap = A + (size_t)(row0 + srow)*lda + scol;
  const u16* Bp = B + (size_t)(col0 + srow)*ldb + scol;
  char* AsB = (char*)As + (size_t)wid*1024;
  char* BsB = (char*)Bs + (size_t)wid*1024;

  for (int k0 = 0; k0 < K; k0 += 64) {
#pragma unroll
    for (int it = 0; it < 4; it++) {
      gload16(Ap + (size_t)(it*32)*lda + k0, AsB + it*4096);
      gload16(Bp + (size_t)(it*32)*ldb + k0, BsB + it*4096);
    }
    __syncthreads();
#pragma unroll
    for (int kk = 0; kk < 2; kk++) {
      bf16x8 af[4], bg[4];
#pragma unroll
      for (int i = 0; i < 4; i++) {
        int rr = wr*64 + i*16 + fr;
        af[i] = *(const bf16x8*)&As[rr*64 + ((kk*32 + ks*8) ^ ((rr & 7) << 3))];
      }
#pragma unroll
      for (int j = 0; j < 4; j++) {
        int rr = wc*64 + j*16 + fr;
        bg[j] = *(const bf16x8*)&Bs[rr*64 + ((kk*32 + ks*8) ^ ((rr & 7) << 3))];
      }
#pragma unroll
      for (int i = 0; i < 4; i++)
#pragma unroll
        for (int j = 0; j < 4; j++)
          acc[i][j] = __builtin_amdgcn_mfma_f32_16x16x32_bf16(af[i], bg[j], acc[i][j], 0, 0, 0);
    }
    __syncthreads();
  }
#pragma unroll
  for (int i = 0; i < 4; i++) {
#pragma unroll
    for (int j = 0; j < 4; j++) {
      int row = row0 + wr*64 + i*16 + ks*4;
      int col = col0 + wc*64 + j*16 + fr;
      if (SCATTER) {
        int PP = P.ldcPP[bi];
        int bb = row / PP, rw = row - bb*PP;
        *(f32x4*)&C[((size_t)(bb*P.CH[bi] + P.coff[bi] + col))*PP + rw] = acc[i][j];
      } else {
        u16* Cb = (u16*)C;
        int ldc = P.ldcPP[bi];
#pragma unroll
        for (int rr = 0; rr < 4; rr++)
          Cb[(size_t)(row + rr)*ldc + col] = f2bf(acc[i][j][rr]);
      }
    }
  }
}

// 256x256-tile, double-buffered, counted-vmcnt MFMA GEMM. bf16 out.
__global__ __launch_bounds__(512, 2) void mgemm256_k(MG2 P) {
  __shared__ __align__(16) u16 As[2][256*64];
  __shared__ __align__(16) u16 Bs[2][256*64];
  int wg = blockIdx.x;
  int nwg = P.nwg;
  int q = nwg >> 3, r = nwg & 7;
  int xcd = wg & 7, cidx = wg >> 3;
  int swz = (xcd < r ? xcd*(q+1) : r*(q+1) + (xcd - r)*q) + cidx;
  int bi = (swz >= P.base[1]) + (swz >= P.base[2]) + (swz >= P.base[3]);
  int lt = swz - P.base[bi];
  int gx = P.gx[bi];
  int bx = lt % gx, by = lt / gx;
  const u16* A = P.A[bi];
  const u16* Bm = P.B[bi];
  float* C = P.C[bi];
  int K = P.K[bi], lda = P.lda[bi], ldb = P.ldb[bi];
  int row0 = by << 8, col0 = bx << 8;

  int tid = threadIdx.x;
  int lane = tid & 63, wid = tid >> 6;
  int wr = wid >> 2, wc = wid & 3;
  int fr = lane & 15, ks = lane >> 4;

  int arow = tid >> 3;
  int presw = ((tid & 7) ^ (arow & 7)) * 8;
  const u16* Ap = A + (size_t)(row0 + arow)*lda + presw;
  const u16* Bp = Bm + (size_t)(col0 + arow)*ldb + presw;
  char* AL = (char*)&As[0][0] + (size_t)wid*1024;
  char* BL = (char*)&Bs[0][0] + (size_t)wid*1024;

  f32x4 acc[8][4] = {};
  int nt = K >> 6;

#define STAGE256(b, kt) { \
    int k0 = (kt) << 6; \
    _Pragma("unroll") \
    for (int ia = 0; ia < 4; ia++) \
      gload16(Ap + (size_t)(ia*64)*lda + k0, AL + (b)*32768 + ia*8192); \
    _Pragma("unroll") \
    for (int ib = 0; ib < 4; ib++) \
      gload16(Bp + (size_t)(ib*64)*ldb + k0, BL + (b)*32768 + ib*8192); \
  }

  STAGE256(0, 0);
  for (int t = 0; t < nt; t++) {
    int b = t & 1;
    if (t + 1 < nt) {
      STAGE256(b ^ 1, t + 1);
      __builtin_amdgcn_sched_barrier(0);
      asm volatile("s_waitcnt vmcnt(8)" ::: "memory");
    } else {
      __builtin_amdgcn_sched_barrier(0);
      asm volatile("s_waitcnt vmcnt(0)" ::: "memory");
    }
    __builtin_amdgcn_sched_barrier(0);
    __builtin_amdgcn_s_barrier();
    __builtin_amdgcn_sched_barrier(0);
    {
      const u16* Ab = &As[b][0];
      const u16* Bb = &Bs[b][0];
#pragma unroll
      for (int kk = 0; kk < 2; kk++) {
        bf16x8 af[8], bg[4];
#pragma unroll
        for (int i = 0; i < 8; i++) {
          int rr = wr*128 + i*16 + fr;
          af[i] = *(const bf16x8*)&Ab[rr*64 + ((kk*32 + ks*8) ^ ((rr & 7) << 3))];
        }
#pragma unroll
        for (int j = 0; j < 4; j++) {
          int rr = wc*64 + j*16 + fr;
          bg[j] = *(const bf16x8*)&Bb[rr*64 + ((kk*32 + ks*8) ^ ((rr & 7) << 3))];
        }
        __builtin_amdgcn_s_setprio(1);
#pragma unroll
        for (int i = 0; i < 8; i++)
#pragma unroll
          for (int j = 0; j < 4; j++)
            acc[i][j] = __builtin_amdgcn_mfma_f32_16x16x32_bf16(af[i], bg[j], acc[i][j], 0, 0, 0);
        __builtin_amdgcn_s_setprio(0);
      }
    }
    __builtin_amdgcn_sched_barrier(0);
    asm volatile("s_waitcnt lgkmcnt(0)" ::: "memory");
    __builtin_amdgcn_sched_barrier(0);
    __builtin_amdgcn_s_barrier();
    __builtin_amdgcn_sched_barrier(0);
  }
#undef STAGE256

#pragma unroll
  for (int i = 0; i < 8; i++) {
#pragma unroll
    for (int j = 0; j < 4; j++) {
      int row = row0 + wr*128 + i*16 + ks*4;
      int col = col0 + wc*64 + j*16 + fr;
      u16* Cb = (u16*)C;
      int ldc = P.ldcPP[bi];
#pragma unroll
      for (int rr = 0; rr < 4; rr++)
        Cb[(size_t)(row + rr)*ldc + col] = f2bf(acc[i][j][rr]);
    }
  }
}

// One WAVE per token row; reads bf16 logits; emits SPARSE (idx,val) + count.
template<int R>
__device__ __forceinline__ void row_fin_body(const u16* __restrict__ S_all,
    const u16* __restrict__ x2s, const float* __restrict__ Wm,
    int Tblock, float* __restrict__ part, int t,
    u16* __restrict__ nzi, float* __restrict__ nzv, int* __restrict__ cnt) {
  const int M = R*64;
  int lane = threadIdx.x & 63;
  const u16* S = S_all + (size_t)t*M;
  float s[R];
#pragma unroll
  for (int i = 0; i < R; i++) s[i] = bf2f(S[lane + i*64]);

  float v0 = -INFINITY, v1 = -INFINITY; int j0 = 0x7fffffff, j1 = 0x7fffffff;
#pragma unroll
  for (int i = 0; i < R; i++) {
    int j = lane + i*64; float sv = s[i];
    if (sv > v0 || (sv == v0 && j < j0)) { v1 = v0; j1 = j0; v0 = sv; j0 = j; }
    else if (sv > v1 || (sv == v1 && j < j1)) { v1 = sv; j1 = j; }
  }
#pragma unroll
  for (int m = 32; m > 0; m >>= 1) {
    float b0 = __shfl_xor(v0, m, 64); int bi0 = __shfl_xor(j0, m, 64);
    float b1 = __shfl_xor(v1, m, 64); int bi1 = __shfl_xor(j1, m, 64);
    if (b0 > v0 || (b0 == v0 && bi0 < j0)) {
      if (v0 > b1 || (v0 == b1 && j0 < bi1)) { v1 = v0; j1 = j0; }
      else { v1 = b1; j1 = bi1; }
      v0 = b0; j0 = bi0;
    } else {
      if (b0 > v1 || (b0 == v1 && bi0 < j1)) { v1 = b0; j1 = bi0; }
    }
  }

  float z = 0.f;
#pragma unroll
  for (int i = 0; i < R; i++) { float p = expf(s[i] - v0); z += p; s[i] = p; }
  z = wave_sum(z);
  float invZ = 1.f / z;

  float l1 = 0.f;
#pragma unroll
  for (int i = 0; i < R; i++) {
    float attv = s[i] * invZ;
    float r = attv - 0.0025f;
    float a = (r > 0.f) ? (r * attv / (r + 1e-12f)) : 0.f;
    l1 += a; s[i] = a;
  }
  l1 = wave_sum(l1);
  float inv = 1.f / fmaxf(l1, 1e-12f);

  // sparse compaction + entropy
  u16* ip = nzi + (size_t)t*400;
  float* vp = nzv + (size_t)t*400;
  int base = 0;
  float e = 0.f;
#pragma unroll
  for (int i = 0; i < R; i++) {
    float an = s[i] * inv;
    unsigned long long m = __ballot(s[i] > 0.f);
    int pos = __popcll(m & ((1ull << lane) - 1ull));
    if (s[i] > 0.f) {
      ip[base + pos] = (u16)(lane + i*64);
      vp[base + pos] = an;
      e += an * logf(an + 1e-12f);
    }
    base += __popcll(m);
  }
  if (lane == 0) cnt[t] = base;

  float dp2 = 0.f, dn2 = 0.f, cq2 = 0.f;
  const u16* xr = x2s + (size_t)t*512;
  const float* pw = Wm + (size_t)j0*256;
  const float* nw = Wm + (size_t)j1*256;
#pragma unroll
  for (int k2 = 0; k2 < 4; k2++) {
    int c = lane + k2*64;
    float xv = bf2f(xr[c]) + bf2f(xr[256 + c]);
    float p = pw[c], n = nw[c];
    float dp = xv - p + 1e-6f, dn = xv - n + 1e-6f, cq = xv - p;
    dp2 += dp*dp; dn2 += dn*dn; cq2 += cq*cq;
  }
  e = wave_sum(e); dp2 = wave_sum(dp2); dn2 = wave_sum(dn2); cq2 = wave_sum(cq2);
  if (lane == 0) {
    int slot = t & 1023;
    float trip = fmaxf(sqrtf(dp2) - sqrtf(dn2) + 1.f, 0.f);
    atomicAdd(&part[0*1024 + slot], -e / (float)Tblock);
    atomicAdd(&part[1*1024 + slot], trip / (float)Tblock);
    atomicAdd(&part[2*1024 + slot], cq2 / ((float)Tblock * 256.f));
  }
}

// Merged finalize. grid = 21760 (4 waves = 4 tokens/WG).
__global__ __launch_bounds__(256) void row_fin_all_k(RFP P, float* __restrict__ part) {
  int b = blockIdx.x;
  int bi = (b >= 16384) + (b >= 20480) + (b >= 21504);
  int lb = b - (bi == 0 ? 0 : bi == 1 ? 16384 : bi == 2 ? 20480 : 21504);
  int t = lb*4 + (threadIdx.x >> 6);
  switch (bi) {
    case 0: row_fin_body<16>(P.S[0], P.x2[0], P.W[0], P.T[0], part, t, P.nzi[0], P.nzv[0], P.cnt[0]); break;
    case 1: row_fin_body<8> (P.S[1], P.x2[1], P.W[1], P.T[1], part, t, P.nzi[1], P.nzv[1], P.cnt[1]); break;
    case 2: row_fin_body<4> (P.S[2], P.x2[2], P.W[2], P.T[2], part, t, P.nzi[2], P.nzv[2], P.cnt[2]); break;
    default:row_fin_body<2> (P.S[3], P.x2[3], P.W[3], P.T[3], part, t, P.nzi[3], P.nzv[3], P.cnt[3]); break;
  }
}

// Sparse att x W product. Block = 64 tokens (4 waves x 16). grid = 1360.
// out[t][c] = sum_i val[t][i] * W[idx[t][i]][c], f32 exact.
__global__ __launch_bounds__(256) void spmm_k(
    const u16* __restrict__ nzi, const float* __restrict__ nzv,
    const int* __restrict__ cnt, GP gp, float* __restrict__ out,
    float* __restrict__ rec32, float* __restrict__ rec16, float* __restrict__ rec8) {
  __shared__ float tile[64][257];
  int b = blockIdx.x;
  int bi = (b >= 1024) + (b >= 1280) + (b >= 1344);
  int lb = b - (bi == 0 ? 0 : bi == 1 ? 1024 : bi == 2 ? 1280 : 1344);
  int toff = (bi == 0 ? 0 : bi == 1 ? 65536 : bi == 2 ? 81920 : 86016);
  const float4* W4 = (const float4*)gp.w[bi];
  float* C; int PP, CH;
  if (bi == 0)      { C = out;   PP = 4096; CH = 1024; }
  else if (bi == 1) { C = rec32; PP = 1024; CH = 256; }
  else if (bi == 2) { C = rec16; PP = 256;  CH = 256; }
  else              { C = rec8;  PP = 64;   CH = 256; }
  int tid = threadIdx.x, lane = tid & 63, wv = tid >> 6;
  int t0 = lb*64;

#pragma unroll 1
  for (int k = 0; k < 16; k++) {
    int tl = wv*16 + k;
    int t = toff + t0 + tl;
    int n = cnt[t];
    const u16* ip = nzi + (size_t)t*400;
    const float* vp = nzv + (size_t)t*400;
    f32x4 a0 = {0,0,0,0}, a1 = {0,0,0,0};
    int i = 0;
    for (; i + 2 <= n; i += 2) {
      int j0 = ip[i], j1 = ip[i+1];
      float v0 = vp[i], v1 = vp[i+1];
      f32x4 w0 = ((const f32x4*)W4)[(size_t)j0*64 + lane];
      f32x4 w1 = ((const f32x4*)W4)[(size_t)j1*64 + lane];
      a0 += v0 * w0;
      a1 += v1 * w1;
    }
    if (i < n) {
      int j0 = ip[i]; float v0 = vp[i];
      f32x4 w0 = ((const f32x4*)W4)[(size_t)j0*64 + lane];
      a0 += v0 * w0;
    }
    a0 += a1;
    *(f32x4*)&tile[tl][lane*4] = a0;
  }
  __syncthreads();

  int bb = t0 / PP;
  int rw0 = t0 - bb*PP;
#pragma unroll 1
  for (int r = 0; r < 64; r++) {
    int c = r*4 + (tid >> 6);
    int rwl = tid & 63;
    C[((size_t)(bb*CH + c))*PP + rw0 + rwl] = tile[rwl][c];
  }
}

__global__ __launch_bounds__(256) void loss_reduce_k(const float* __restrict__ part,
                                                     float* __restrict__ losses) {
  __shared__ float red[256];
  int l = blockIdx.x;
  int tid = threadIdx.x;
  float v = 0.f;
  for (int i = tid; i < 1024; i += 256) v += part[l*1024 + i];
  float s = block_sum(v, red);
  if (tid == 0) atomicAdd(&losses[l == 2 ? 3 : l], s);
}

// Merged bilinear upsample. grid = 3*65536.
__global__ __launch_bounds__(256) void upsample_all_k(UP up, float* __restrict__ out) {
  int b = blockIdx.x;
  int ri = b >> 16;
  int blk = 32 >> ri;
  int coff = (ri + 1) * 256;
  const float* rec = up.rec[ri];
  int idx = (b & 65535)*256 + threadIdx.x;
  int w = idx & 63, r = (idx >> 6) & 63, c = (idx >> 12) & 255, bb = idx >> 20;
  float s = (float)blk * (1.f/64.f);
  float py = ((float)r + 0.5f)*s - 0.5f;
  float px = ((float)w + 0.5f)*s - 0.5f;
  float fy0 = floorf(py), fx0 = floorf(px);
  float fy = py - fy0, fx = px - fx0;
  int y0 = (int)fy0, x0 = (int)fx0;
  int y0c = min(max(y0, 0), blk-1), y1c = min(max(y0+1, 0), blk-1);
  int x0c = min(max(x0, 0), blk-1), x1c = min(max(x0+1, 0), blk-1);
  const float* rp = rec + (size_t)(bb*256 + c)*blk*blk;
  float v00 = rp[y0c*blk + x0c], v01 = rp[y0c*blk + x1c];
  float v10 = rp[y1c*blk + x0c], v11 = rp[y1c*blk + x1c];
  float v = (1.f-fy)*((1.f-fx)*v00 + fx*v01) + fy*((1.f-fx)*v10 + fx*v11);
  out[((size_t)(bb*1024 + coff + c) << 12) + (r << 6) + w] = v;
}

extern "C" void kernel_launch(void* const* d_in, const int* in_sizes, int n_in,
                              void* d_out, int out_size, void* d_ws, size_t ws_size,
                              hipStream_t stream) {
  const float* x = (const float*)d_in[0];
  GP gp;
  gp.w[0] = (const float*)d_in[2]; gp.w[1] = (const float*)d_in[3];
  gp.w[2] = (const float*)d_in[4]; gp.w[3] = (const float*)d_in[5];
  float* out = (float*)d_out;
  float* losses = out + OUTC;

  char* ws = (char*)d_ws;
  size_t off = 0;
  float* rec32 = (float*)(ws + off); off += (size_t)16384*256*4;
  float* rec16 = (float*)(ws + off); off += (size_t)4096*256*4;
  float* rec8  = (float*)(ws + off); off += (size_t)1024*256*4;
  float* part  = (float*)(ws + off); off += 3*1024*4;
  off = (off + 255) & ~(size_t)255;
  u16* Ws1 = (u16*)(ws + off); off += (size_t)1920*256*2;
  gp.g[0] = (float*)(ws + off); off += (size_t)1024*1024*4;
  gp.g[1] = (float*)(ws + off); off += (size_t)512*512*4;
  gp.g[2] = (float*)(ws + off); off += (size_t)256*256*4;
  gp.g[3] = (float*)(ws + off); off += (size_t)128*128*4;
  u16* x2s64 = (u16*)(ws + off); off += (size_t)65536*512*2;    // 67 MB
  u16* x2s32 = (u16*)(ws + off); off += (size_t)16384*512*2;
  u16* x2s16 = (u16*)(ws + off); off += (size_t)4096*512*2;
  u16* x2s8  = (u16*)(ws + off); off += (size_t)1024*512*2;
  u16* S64 = (u16*)(ws + off); off += (size_t)65536*1024*2;     // 134 MB (bf16)
  u16* S32 = (u16*)(ws + off); off += (size_t)16384*512*2;
  u16* S16 = (u16*)(ws + off); off += (size_t)4096*256*2;
  u16* S8  = (u16*)(ws + off); off += (size_t)1024*128*2;
  int* cnt = (int*)(ws + off); off += (size_t)86016*4;
  off = (off + 255) & ~(size_t)255;
  u16* nzi = (u16*)(ws + off); off += (size_t)86016*400*2;      // 68.8 MB
  off = (off + 255) & ~(size_t)255;
  float* nzv = (float*)(ws + off); off += (size_t)86016*400*4;  // 137.6 MB

  const size_t s1off[4] = {0, (size_t)1024*256, (size_t)1536*256, (size_t)1792*256};
  const u16* x2Arr[4] = {x2s64, x2s32, x2s16, x2s8};
  u16* SArr[4] = {S64, S32, S16, S8};
  const int toff[4] = {0, 65536, 81920, 86016};
  const int MS[4] = {1024, 512, 256, 128};

  zero_k<<<13, 256, 0, stream>>>(part, losses);
  wprep_k<<<1920, 256, 0, stream>>>(gp, Ws1, losses);
  sgemmbt_all_k<<<340, 256, 0, stream>>>(gp);
  wdist_all_k<<<5440, 256, 0, stream>>>(gp, losses);

  gather_pool_k<<<4096, 256, 0, stream>>>(x, x2s64, x2s32);
  pool_half_k<<<4096, 256, 0, stream>>>(x2s32, x2s16, 16);
  pool_half_k<<<1024, 256, 0, stream>>>(x2s16, x2s8, 8);

  // logits GEMMs bi0-2 on 256-tile kernel: Sb(bf16) = x2_hi * Ws1^T, K=256
  MG2 L2;
  {
    int base = 0;
    for (int bi = 0; bi < 3; bi++) {
      L2.A[bi] = x2Arr[bi]; L2.B[bi] = Ws1 + s1off[bi]; L2.C[bi] = (float*)SArr[bi];
      L2.K[bi] = 256; L2.lda[bi] = 512; L2.ldb[bi] = 256;
      L2.ldcPP[bi] = MS[bi]; L2.CH[bi] = 0;
      L2.gx[bi] = MS[bi]/256;
      L2.base[bi] = base;
      int T = 65536 >> (2*bi);
      base += (MS[bi]/256) * (T/256);
    }
    L2.A[3] = L2.A[2]; L2.B[3] = L2.B[2]; L2.C[3] = L2.C[2];
    L2.K[3] = 256; L2.lda[3] = 512; L2.ldb[3] = 256; L2.ldcPP[3] = 256; L2.CH[3] = 0;
    L2.gx[3] = 1; L2.base[3] = base;   // sentinel = nwg
    L2.nwg = base;  // 1168
  }
  mgemm256_k<<<L2.nwg, 512, 0, stream>>>(L2);

  // logits bi3 (cols=128) on the 128-tile kernel
  MGP L3;
  for (int i = 0; i < 4; i++) {
    L3.A[i] = x2s8; L3.B[i] = Ws1 + s1off[3]; L3.C[i] = (float*)S8;
    L3.K[i] = 256; L3.lda[i] = 512; L3.ldb[i] = 256;
    L3.ldcPP[i] = 128; L3.CH[i] = 0; L3.coff[i] = 0;
    L3.gx[i] = 1; L3.base[i] = (i == 0) ? 0 : 8;
  }
  L3.nwg = 8;
  mgemm_all_k<false><<<8, 256, 0, stream>>>(L3);

  // merged row finalize: bf16 logits -> sparse (idx,val,cnt)
  RFP R;
  for (int bi = 0; bi < 4; bi++) {
    R.S[bi] = SArr[bi]; R.x2[bi] = x2Arr[bi];
    R.W[bi] = gp.w[bi]; R.T[bi] = 65536 >> (2*bi);
    R.nzi[bi] = nzi + (size_t)toff[bi]*400;
    R.nzv[bi] = nzv + (size_t)toff[bi]*400;
    R.cnt[bi] = cnt + toff[bi];
  }
  row_fin_all_k<<<21760, 256, 0, stream>>>(R, part);

  // sparse att x W (all 4 blocks), f32 exact
  spmm_k<<<1360, 256, 0, stream>>>(nzi, nzv, cnt, gp, out, rec32, rec16, rec8);

  UP up; up.rec[0] = rec32; up.rec[1] = rec16; up.rec[2] = rec8;
  upsample_all_k<<<3*65536, 256, 0, stream>>>(up, out);

  loss_reduce_k<<<3, 256, 0, stream>>>(part, losses);
}

// Round 14
// 577.177 us; speedup vs baseline: 1.7411x; 1.7411x over previous
//
#include <hip/hip_runtime.h>

#define OUTC (16ull*1024*64*64)

typedef unsigned short u16;
typedef __attribute__((ext_vector_type(8))) __bf16 bf16x8;
typedef __attribute__((ext_vector_type(4))) float f32x4;

struct GP { const float* w[4]; float* g[4]; };
struct UP { const float* rec[3]; };
struct MGP {
  const u16* A[4]; const u16* B[4]; float* C[4];
  int K[4]; int lda[4]; int ldb[4]; int ldcPP[4]; int CH[4]; int coff[4];
  int base[4]; int gx[4]; int nwg;
};
struct MG2 {
  const u16* A[4]; const u16* B[4]; float* C[4];
  int K[4]; int lda[4]; int ldb[4]; int ldcPP[4]; int CH[4];
  int base[4]; int gx[4]; int nwg;
};
struct RFP { u16* S[4]; u16* attB[4]; const u16* x2[4]; const float* W[4]; int T[4]; };

__device__ __forceinline__ u16 f2bf(float f) {
  unsigned u = __float_as_uint(f);
  unsigned r = (u + 0x7fffu + ((u >> 16) & 1u)) >> 16;
  return (u16)r;
}
__device__ __forceinline__ float bf2f(u16 h) {
  return __uint_as_float(((unsigned)h) << 16);
}

// async global->LDS, 16B per lane; LDS dest = wave-uniform base + lane*16.
__device__ __forceinline__ void gload16(const void* gsrc, void* ldst) {
  __builtin_amdgcn_global_load_lds(
      (const __attribute__((address_space(1))) void*)gsrc,
      (__attribute__((address_space(3))) void*)ldst, 16, 0, 0);
}

__device__ __forceinline__ float block_sum(float v, float* red) {
  int tid = threadIdx.x;
  red[tid] = v; __syncthreads();
#pragma unroll
  for (int s = 128; s > 0; s >>= 1) {
    if (tid < s) red[tid] += red[tid + s];
    __syncthreads();
  }
  float r = red[0];
  __syncthreads();
  return r;
}

__device__ __forceinline__ float wave_sum(float v) {
#pragma unroll
  for (int m = 32; m > 0; m >>= 1) v += __shfl_xor(v, m, 64);
  return v;
}

__global__ void zero_k(float* part, float* losses) {
  if (blockIdx.x < 12) part[blockIdx.x*256 + threadIdx.x] = 0.f;
  else if (threadIdx.x < 5) losses[threadIdx.x] = 0.f;
}

// ONE pass over x: blk64 token rows (hi bf16) AND blk32 pooled level (hi bf16).
__global__ __launch_bounds__(256) void gather_pool_k(const float* __restrict__ x,
    u16* __restrict__ x2s64, u16* __restrict__ x2s32) {
  __shared__ float lds[32][130];
  int tid = threadIdx.x;
  int b = blockIdx.x;
  int orow = b & 31, ct = (b >> 5) & 7, bb = b >> 8;
  const float* xb = x + ((size_t)(bb*256 + ct*32))*4096 + orow*128;
#pragma unroll
  for (int p = 0; p < 4; p++) {
    int s = p*256 + tid;
    int c = s >> 5, f = s & 31;
    float4 v = *(const float4*)(xb + (size_t)c*4096 + f*4);
    lds[c][f*4+0] = v.x; lds[c][f*4+1] = v.y;
    lds[c][f*4+2] = v.z; lds[c][f*4+3] = v.w;
  }
  __syncthreads();
  {
    int cg = (tid & 3) * 8;
#pragma unroll
    for (int it = 0; it < 2; it++) {
      int tl = it*64 + (tid >> 2);
      size_t row = ((size_t)bb*4096 + (size_t)orow*128 + tl)*256 + ct*32 + cg;
      u16 hi[8];
#pragma unroll
      for (int e = 0; e < 8; e++) hi[e] = f2bf(lds[cg + e][tl]);
      *(uint4*)&x2s64[row] = *(uint4*)hi;
    }
  }
  {
    int c = tid & 31;
#pragma unroll
    for (int p = 0; p < 4; p++) {
      int w = p*8 + (tid >> 5);
      float m = fmaxf(fmaxf(lds[c][2*w], lds[c][2*w+1]),
                      fmaxf(lds[c][64+2*w], lds[c][64+2*w+1]));
      x2s32[((size_t)bb*1024 + (size_t)orow*32 + w)*256 + ct*32 + c] = f2bf(m);
    }
  }
}

__global__ __launch_bounds__(256) void pool_half_k(const u16* __restrict__ src,
    u16* __restrict__ dst, int blk) {
  int t = blockIdx.x, c = threadIdx.x;
  int bb = t / (blk*blk), rw = t - bb*blk*blk;
  int r = rw / blk, w = rw - r*blk;
  int bp = blk*2;
  int pb = bb*bp*bp;
  float m = -INFINITY;
#pragma unroll
  for (int dy = 0; dy < 2; dy++)
#pragma unroll
    for (int dx = 0; dx < 2; dx++)
      m = fmaxf(m, bf2f(src[(size_t)(pb + (2*r+dy)*bp + 2*w+dx)*256 + c]));
  dst[(size_t)t*256 + c] = f2bf(m);
}

// Merged wsplit + wnorm. Ws1 = hi-only [M][256]; Ws2 = hi-only [256][M]. grid = 1920.
__global__ __launch_bounds__(256) void wprep_k(GP gp,
    u16* __restrict__ Ws1, u16* __restrict__ Ws2, float* __restrict__ losses) {
  __shared__ float red[256];
  int b = blockIdx.x;
  int bi, m, M; size_t s1off, s2off;
  if (b < 1024)      { bi=0; m=b;      M=1024; s1off=0; s2off=0; }
  else if (b < 1536) { bi=1; m=b-1024; M=512;  s1off=(size_t)1024*256; s2off=(size_t)256*1024; }
  else if (b < 1792) { bi=2; m=b-1536; M=256;  s1off=(size_t)1536*256; s2off=(size_t)256*1536; }
  else               { bi=3; m=b-1792; M=128;  s1off=(size_t)1792*256; s2off=(size_t)256*1792; }
  int c = threadIdx.x;
  float w = gp.w[bi][(size_t)m*256 + c];
  u16 h = f2bf(w);
  Ws1[s1off + (size_t)m*256 + c] = h;
  Ws2[s2off + (size_t)c*M + m] = h;
  float s = block_sum(w*w, red);
  if (c == 0) atomicAdd(&losses[2], fabsf(1.f - sqrtf(s)) / (float)M);
}

// Merged exact-f32 W*W^T. grid = 340.
__global__ __launch_bounds__(256) void sgemmbt_all_k(GP gp) {
  __shared__ float As[32][64];
  __shared__ float Bs[32][64];
  int b = blockIdx.x;
  int bi, lt, M, lg;
  if (b < 256)      { bi=0; lt=b;     M=1024; lg=4; }
  else if (b < 320) { bi=1; lt=b-256; M=512;  lg=3; }
  else if (b < 336) { bi=2; lt=b-320; M=256;  lg=2; }
  else              { bi=3; lt=b-336; M=128;  lg=1; }
  const float* A = gp.w[bi];
  float* C = gp.g[bi];
  int gx = 1 << lg;
  int bx = lt & (gx-1), by = lt >> lg;
  int tid = threadIdx.x;
  int tx = tid & 15, ty = tid >> 4;
  int row0 = by << 6, col0 = bx << 6;
  float acc[4][4] = {};
  for (int k0 = 0; k0 < 256; k0 += 32) {
#pragma unroll
    for (int l = 0; l < 2; l++) {
      int i = tid + l*256;
      int kq = i & 7, m = i >> 3;
      float4 v = *(const float4*)(A + (size_t)(row0 + m)*256 + k0 + kq*4);
      As[kq*4+0][m] = v.x; As[kq*4+1][m] = v.y; As[kq*4+2][m] = v.z; As[kq*4+3][m] = v.w;
      float4 w = *(const float4*)(A + (size_t)(col0 + m)*256 + k0 + kq*4);
      Bs[kq*4+0][m] = w.x; Bs[kq*4+1][m] = w.y; Bs[kq*4+2][m] = w.z; Bs[kq*4+3][m] = w.w;
    }
    __syncthreads();
#pragma unroll
    for (int kk = 0; kk < 32; kk++) {
      float4 a = *(const float4*)&As[kk][ty*4];
      float4 bvv = *(const float4*)&Bs[kk][tx*4];
      float av[4] = {a.x, a.y, a.z, a.w};
      float bv[4] = {bvv.x, bvv.y, bvv.z, bvv.w};
#pragma unroll
      for (int i = 0; i < 4; i++)
#pragma unroll
        for (int j = 0; j < 4; j++)
          acc[i][j] = fmaf(av[i], bv[j], acc[i][j]);
    }
    __syncthreads();
  }
#pragma unroll
  for (int i = 0; i < 4; i++)
#pragma unroll
    for (int j = 0; j < 4; j++)
      C[(size_t)(row0 + ty*4 + i)*M + col0 + tx*4 + j] = acc[i][j];
}

// Merged wdist. grid = 5440.
__global__ __launch_bounds__(256) void wdist_all_k(GP gp, float* __restrict__ losses) {
  __shared__ float red[256];
  int b = blockIdx.x;
  int bi, lb, M;
  if (b < 4096)      { bi=0; lb=b;      M=1024; }
  else if (b < 5120) { bi=1; lb=b-4096; M=512; }
  else if (b < 5376) { bi=2; lb=b-5120; M=256; }
  else               { bi=3; lb=b-5376; M=128; }
  const float* G = gp.g[bi];
  int idx = lb*256 + threadIdx.x;
  float acc = 0.f;
  int i = idx / M, j = idx - i*M;
  if (j > i) {
    float d2 = G[(size_t)i*M + i] + G[(size_t)j*M + j] - 2.f*G[(size_t)i*M + j];
    float dist = 1.f - d2;
    if (dist > 0.f) acc = dist;
  }
  float s = block_sum(acc, red);
  if (threadIdx.x == 0) atomicAdd(&losses[4], s * 2.f / ((float)M * (float)(M - 1)));
}

// 128x128-tile MFMA GEMM (2-barrier). SCATTER: f32 scatter-out. !SCATTER: bf16 out.
template<bool SCATTER>
__global__ __launch_bounds__(256) void mgemm_all_k(MGP P) {
  __shared__ __align__(16) u16 As[128*64];
  __shared__ __align__(16) u16 Bs[128*64];
  int wg = blockIdx.x;
  int nwg = P.nwg;
  int q = nwg >> 3, r = nwg & 7;
  int xcd = wg & 7, cidx = wg >> 3;
  int swz = (xcd < r ? xcd*(q+1) : r*(q+1) + (xcd - r)*q) + cidx;
  int bi = (swz >= P.base[1]) + (swz >= P.base[2]) + (swz >= P.base[3]);
  int lt = swz - P.base[bi];
  int gx = P.gx[bi];
  int bx = lt % gx, by = lt / gx;
  const u16* A = P.A[bi];
  const u16* B = P.B[bi];
  float* C = P.C[bi];
  int K = P.K[bi], lda = P.lda[bi], ldb = P.ldb[bi];

  int tid = threadIdx.x;
  int lane = tid & 63;
  int wid = tid >> 6;
  int wr = wid >> 1, wc = wid & 1;
  int fr = lane & 15, ks = lane >> 4;
  int row0 = by << 7, col0 = bx << 7;
  f32x4 acc[4][4] = {};
  int srow = tid >> 3;
  int scol = ((tid & 7) ^ (srow & 7)) * 8;
  const u16* Ap = A + (size_t)(row0 + srow)*lda + scol;
  const u16* Bp = B + (size_t)(col0 + srow)*ldb + scol;
  char* AsB = (char*)As + (size_t)wid*1024;
  char* BsB = (char*)Bs + (size_t)wid*1024;

  for (int k0 = 0; k0 < K; k0 += 64) {
#pragma unroll
    for (int it = 0; it < 4; it++) {
      gload16(Ap + (size_t)(it*32)*lda + k0, AsB + it*4096);
      gload16(Bp + (size_t)(it*32)*ldb + k0, BsB + it*4096);
    }
    __syncthreads();
#pragma unroll
    for (int kk = 0; kk < 2; kk++) {
      bf16x8 af[4], bg[4];
#pragma unroll
      for (int i = 0; i < 4; i++) {
        int rr = wr*64 + i*16 + fr;
        af[i] = *(const bf16x8*)&As[rr*64 + ((kk*32 + ks*8) ^ ((rr & 7) << 3))];
      }
#pragma unroll
      for (int j = 0; j < 4; j++) {
        int rr = wc*64 + j*16 + fr;
        bg[j] = *(const bf16x8*)&Bs[rr*64 + ((kk*32 + ks*8) ^ ((rr & 7) << 3))];
      }
#pragma unroll
      for (int i = 0; i < 4; i++)
#pragma unroll
        for (int j = 0; j < 4; j++)
          acc[i][j] = __builtin_amdgcn_mfma_f32_16x16x32_bf16(af[i], bg[j], acc[i][j], 0, 0, 0);
    }
    __syncthreads();
  }
#pragma unroll
  for (int i = 0; i < 4; i++) {
#pragma unroll
    for (int j = 0; j < 4; j++) {
      int row = row0 + wr*64 + i*16 + ks*4;
      int col = col0 + wc*64 + j*16 + fr;
      if (SCATTER) {
        int PP = P.ldcPP[bi];
        int bb = row / PP, rw = row - bb*PP;
        *(f32x4*)&C[((size_t)(bb*P.CH[bi] + P.coff[bi] + col))*PP + rw] = acc[i][j];
      } else {
        u16* Cb = (u16*)C;
        int ldc = P.ldcPP[bi];
#pragma unroll
        for (int rr = 0; rr < 4; rr++)
          Cb[(size_t)(row + rr)*ldc + col] = f2bf(acc[i][j][rr]);
      }
    }
  }
}

// 256x256-tile, double-buffered, counted-vmcnt MFMA GEMM. bf16 out.
__global__ __launch_bounds__(512, 2) void mgemm256_k(MG2 P) {
  __shared__ __align__(16) u16 As[2][256*64];
  __shared__ __align__(16) u16 Bs[2][256*64];
  int wg = blockIdx.x;
  int nwg = P.nwg;
  int q = nwg >> 3, r = nwg & 7;
  int xcd = wg & 7, cidx = wg >> 3;
  int swz = (xcd < r ? xcd*(q+1) : r*(q+1) + (xcd - r)*q) + cidx;
  int bi = (swz >= P.base[1]) + (swz >= P.base[2]) + (swz >= P.base[3]);
  int lt = swz - P.base[bi];
  int gx = P.gx[bi];
  int bx = lt % gx, by = lt / gx;
  const u16* A = P.A[bi];
  const u16* Bm = P.B[bi];
  float* C = P.C[bi];
  int K = P.K[bi], lda = P.lda[bi], ldb = P.ldb[bi];
  int row0 = by << 8, col0 = bx << 8;

  int tid = threadIdx.x;
  int lane = tid & 63, wid = tid >> 6;
  int wr = wid >> 2, wc = wid & 3;
  int fr = lane & 15, ks = lane >> 4;

  int arow = tid >> 3;
  int presw = ((tid & 7) ^ (arow & 7)) * 8;
  const u16* Ap = A + (size_t)(row0 + arow)*lda + presw;
  const u16* Bp = Bm + (size_t)(col0 + arow)*ldb + presw;
  char* AL = (char*)&As[0][0] + (size_t)wid*1024;
  char* BL = (char*)&Bs[0][0] + (size_t)wid*1024;

  f32x4 acc[8][4] = {};
  int nt = K >> 6;

#define STAGE256(b, kt) { \
    int k0 = (kt) << 6; \
    _Pragma("unroll") \
    for (int ia = 0; ia < 4; ia++) \
      gload16(Ap + (size_t)(ia*64)*lda + k0, AL + (b)*32768 + ia*8192); \
    _Pragma("unroll") \
    for (int ib = 0; ib < 4; ib++) \
      gload16(Bp + (size_t)(ib*64)*ldb + k0, BL + (b)*32768 + ib*8192); \
  }

  STAGE256(0, 0);
  for (int t = 0; t < nt; t++) {
    int b = t & 1;
    if (t + 1 < nt) {
      STAGE256(b ^ 1, t + 1);
      __builtin_amdgcn_sched_barrier(0);
      asm volatile("s_waitcnt vmcnt(8)" ::: "memory");
    } else {
      __builtin_amdgcn_sched_barrier(0);
      asm volatile("s_waitcnt vmcnt(0)" ::: "memory");
    }
    __builtin_amdgcn_sched_barrier(0);
    __builtin_amdgcn_s_barrier();
    __builtin_amdgcn_sched_barrier(0);
    {
      const u16* Ab = &As[b][0];
      const u16* Bb = &Bs[b][0];
#pragma unroll
      for (int kk = 0; kk < 2; kk++) {
        bf16x8 af[8], bg[4];
#pragma unroll
        for (int i = 0; i < 8; i++) {
          int rr = wr*128 + i*16 + fr;
          af[i] = *(const bf16x8*)&Ab[rr*64 + ((kk*32 + ks*8) ^ ((rr & 7) << 3))];
        }
#pragma unroll
        for (int j = 0; j < 4; j++) {
          int rr = wc*64 + j*16 + fr;
          bg[j] = *(const bf16x8*)&Bb[rr*64 + ((kk*32 + ks*8) ^ ((rr & 7) << 3))];
        }
        __builtin_amdgcn_s_setprio(1);
#pragma unroll
        for (int i = 0; i < 8; i++)
#pragma unroll
          for (int j = 0; j < 4; j++)
            acc[i][j] = __builtin_amdgcn_mfma_f32_16x16x32_bf16(af[i], bg[j], acc[i][j], 0, 0, 0);
        __builtin_amdgcn_s_setprio(0);
      }
    }
    __builtin_amdgcn_sched_barrier(0);
    asm volatile("s_waitcnt lgkmcnt(0)" ::: "memory");
    __builtin_amdgcn_sched_barrier(0);
    __builtin_amdgcn_s_barrier();
    __builtin_amdgcn_sched_barrier(0);
  }
#undef STAGE256

#pragma unroll
  for (int i = 0; i < 8; i++) {
#pragma unroll
    for (int j = 0; j < 4; j++) {
      int row = row0 + wr*128 + i*16 + ks*4;
      int col = col0 + wc*64 + j*16 + fr;
      u16* Cb = (u16*)C;
      int ldc = P.ldcPP[bi];
#pragma unroll
      for (int rr = 0; rr < 4; rr++)
        Cb[(size_t)(row + rr)*ldc + col] = f2bf(acc[i][j][rr]);
    }
  }
}

// One WAVE per token row; reads bf16 logits from S, writes packed bf16 att.
template<int R>
__device__ __forceinline__ void row_fin_body(const u16* __restrict__ S_all,
    u16* __restrict__ attB, const u16* __restrict__ x2s, const float* __restrict__ Wm,
    int Tblock, float* __restrict__ part, int t) {
  const int M = R*64;
  int lane = threadIdx.x & 63;
  const u16* S = S_all + (size_t)t*M;
  float s[R];
#pragma unroll
  for (int i = 0; i < R; i++) s[i] = bf2f(S[lane + i*64]);

  float v0 = -INFINITY, v1 = -INFINITY; int j0 = 0x7fffffff, j1 = 0x7fffffff;
#pragma unroll
  for (int i = 0; i < R; i++) {
    int j = lane + i*64; float sv = s[i];
    if (sv > v0 || (sv == v0 && j < j0)) { v1 = v0; j1 = j0; v0 = sv; j0 = j; }
    else if (sv > v1 || (sv == v1 && j < j1)) { v1 = sv; j1 = j; }
  }
#pragma unroll
  for (int m = 32; m > 0; m >>= 1) {
    float b0 = __shfl_xor(v0, m, 64); int bi0 = __shfl_xor(j0, m, 64);
    float b1 = __shfl_xor(v1, m, 64); int bi1 = __shfl_xor(j1, m, 64);
    if (b0 > v0 || (b0 == v0 && bi0 < j0)) {
      if (v0 > b1 || (v0 == b1 && j0 < bi1)) { v1 = v0; j1 = j0; }
      else { v1 = b1; j1 = bi1; }
      v0 = b0; j0 = bi0;
    } else {
      if (b0 > v1 || (b0 == v1 && bi0 < j1)) { v1 = b0; j1 = bi0; }
    }
  }

  float z = 0.f;
#pragma unroll
  for (int i = 0; i < R; i++) { float p = expf(s[i] - v0); z += p; s[i] = p; }
  z = wave_sum(z);
  float invZ = 1.f / z;

  float l1 = 0.f;
#pragma unroll
  for (int i = 0; i < R; i++) {
    float attv = s[i] * invZ;
    float r = attv - 0.0025f;
    float a = (r > 0.f) ? (r * attv / (r + 1e-12f)) : 0.f;
    l1 += a; s[i] = a;
  }
  l1 = wave_sum(l1);
  float inv = 1.f / fmaxf(l1, 1e-12f);

  u16* So = attB + (size_t)t*M;
  float e = 0.f;
#pragma unroll
  for (int i = 0; i < R; i++) {
    float an = s[i] * inv;
    So[lane + i*64] = f2bf(an);
    if (an > 0.f) e += an * logf(an + 1e-12f);
  }

  float dp2 = 0.f, dn2 = 0.f, cq2 = 0.f;
  const u16* xr = x2s + (size_t)t*256;
  const float* pw = Wm + (size_t)j0*256;
  const float* nw = Wm + (size_t)j1*256;
#pragma unroll
  for (int k2 = 0; k2 < 4; k2++) {
    int c = lane + k2*64;
    float xv = bf2f(xr[c]);
    float p = pw[c], n = nw[c];
    float dp = xv - p + 1e-6f, dn = xv - n + 1e-6f, cq = xv - p;
    dp2 += dp*dp; dn2 += dn*dn; cq2 += cq*cq;
  }
  e = wave_sum(e); dp2 = wave_sum(dp2); dn2 = wave_sum(dn2); cq2 = wave_sum(cq2);
  if (lane == 0) {
    int slot = t & 1023;
    float trip = fmaxf(sqrtf(dp2) - sqrtf(dn2) + 1.f, 0.f);
    atomicAdd(&part[0*1024 + slot], -e / (float)Tblock);
    atomicAdd(&part[1*1024 + slot], trip / (float)Tblock);
    atomicAdd(&part[2*1024 + slot], cq2 / ((float)Tblock * 256.f));
  }
}

// Merged finalize. grid = 21760 (4 waves = 4 tokens/WG).
__global__ __launch_bounds__(256) void row_fin_all_k(RFP P, float* __restrict__ part) {
  int b = blockIdx.x;
  int bi = (b >= 16384) + (b >= 20480) + (b >= 21504);
  int lb = b - (bi == 0 ? 0 : bi == 1 ? 16384 : bi == 2 ? 20480 : 21504);
  int t = lb*4 + (threadIdx.x >> 6);
  switch (bi) {
    case 0: row_fin_body<16>(P.S[0], P.attB[0], P.x2[0], P.W[0], P.T[0], part, t); break;
    case 1: row_fin_body<8> (P.S[1], P.attB[1], P.x2[1], P.W[1], P.T[1], part, t); break;
    case 2: row_fin_body<4> (P.S[2], P.attB[2], P.x2[2], P.W[2], P.T[2], part, t); break;
    default:row_fin_body<2> (P.S[3], P.attB[3], P.x2[3], P.W[3], P.T[3], part, t); break;
  }
}

__global__ __launch_bounds__(256) void loss_reduce_k(const float* __restrict__ part,
                                                     float* __restrict__ losses) {
  __shared__ float red[256];
  int l = blockIdx.x;
  int tid = threadIdx.x;
  float v = 0.f;
  for (int i = tid; i < 1024; i += 256) v += part[l*1024 + i];
  float s = block_sum(v, red);
  if (tid == 0) atomicAdd(&losses[l == 2 ? 3 : l], s);
}

// Merged bilinear upsample. grid = 3*65536.
__global__ __launch_bounds__(256) void upsample_all_k(UP up, float* __restrict__ out) {
  int b = blockIdx.x;
  int ri = b >> 16;
  int blk = 32 >> ri;
  int coff = (ri + 1) * 256;
  const float* rec = up.rec[ri];
  int idx = (b & 65535)*256 + threadIdx.x;
  int w = idx & 63, r = (idx >> 6) & 63, c = (idx >> 12) & 255, bb = idx >> 20;
  float s = (float)blk * (1.f/64.f);
  float py = ((float)r + 0.5f)*s - 0.5f;
  float px = ((float)w + 0.5f)*s - 0.5f;
  float fy0 = floorf(py), fx0 = floorf(px);
  float fy = py - fy0, fx = px - fx0;
  int y0 = (int)fy0, x0 = (int)fx0;
  int y0c = min(max(y0, 0), blk-1), y1c = min(max(y0+1, 0), blk-1);
  int x0c = min(max(x0, 0), blk-1), x1c = min(max(x0+1, 0), blk-1);
  const float* rp = rec + (size_t)(bb*256 + c)*blk*blk;
  float v00 = rp[y0c*blk + x0c], v01 = rp[y0c*blk + x1c];
  float v10 = rp[y1c*blk + x0c], v11 = rp[y1c*blk + x1c];
  float v = (1.f-fy)*((1.f-fx)*v00 + fx*v01) + fy*((1.f-fx)*v10 + fx*v11);
  out[((size_t)(bb*1024 + coff + c) << 12) + (r << 6) + w] = v;
}

extern "C" void kernel_launch(void* const* d_in, const int* in_sizes, int n_in,
                              void* d_out, int out_size, void* d_ws, size_t ws_size,
                              hipStream_t stream) {
  const float* x = (const float*)d_in[0];
  GP gp;
  gp.w[0] = (const float*)d_in[2]; gp.w[1] = (const float*)d_in[3];
  gp.w[2] = (const float*)d_in[4]; gp.w[3] = (const float*)d_in[5];
  float* out = (float*)d_out;
  float* losses = out + OUTC;

  char* ws = (char*)d_ws;
  size_t off = 0;
  float* rec32 = (float*)(ws + off); off += (size_t)16384*256*4;
  float* rec16 = (float*)(ws + off); off += (size_t)4096*256*4;
  float* rec8  = (float*)(ws + off); off += (size_t)1024*256*4;
  float* part  = (float*)(ws + off); off += 3*1024*4;
  off = (off + 255) & ~(size_t)255;
  u16* Ws1 = (u16*)(ws + off); off += (size_t)1920*256*2;
  u16* Ws2 = (u16*)(ws + off); off += (size_t)256*1920*2;
  gp.g[0] = (float*)(ws + off); off += (size_t)1024*1024*4;
  gp.g[1] = (float*)(ws + off); off += (size_t)512*512*4;
  gp.g[2] = (float*)(ws + off); off += (size_t)256*256*4;
  gp.g[3] = (float*)(ws + off); off += (size_t)128*128*4;
  u16* x2s64 = (u16*)(ws + off); off += (size_t)65536*256*2;    // 33.5 MB (hi only)
  u16* x2s32 = (u16*)(ws + off); off += (size_t)16384*256*2;
  u16* x2s16 = (u16*)(ws + off); off += (size_t)4096*256*2;
  u16* x2s8  = (u16*)(ws + off); off += (size_t)1024*256*2;
  u16* attB64 = (u16*)(ws + off); off += (size_t)65536*1024*2;  // 134 MB
  u16* attB32 = (u16*)(ws + off); off += (size_t)16384*512*2;
  u16* attB16 = (u16*)(ws + off); off += (size_t)4096*256*2;
  u16* attB8  = (u16*)(ws + off); off += (size_t)1024*128*2;
  u16* S64 = (u16*)(ws + off); off += (size_t)65536*1024*2;     // 134 MB (bf16)
  u16* S32 = (u16*)(ws + off); off += (size_t)16384*512*2;
  u16* S16 = (u16*)(ws + off); off += (size_t)4096*256*2;
  u16* S8  = (u16*)(ws + off); off += (size_t)1024*128*2;

  const size_t s1off[4] = {0, (size_t)1024*256, (size_t)1536*256, (size_t)1792*256};
  const size_t s2off[4] = {0, (size_t)256*1024, (size_t)256*1536, (size_t)256*1792};
  const u16* x2Arr[4] = {x2s64, x2s32, x2s16, x2s8};
  u16* attArr[4] = {attB64, attB32, attB16, attB8};
  u16* SArr[4] = {S64, S32, S16, S8};
  const int MS[4] = {1024, 512, 256, 128};

  zero_k<<<13, 256, 0, stream>>>(part, losses);
  wprep_k<<<1920, 256, 0, stream>>>(gp, Ws1, Ws2, losses);
  sgemmbt_all_k<<<340, 256, 0, stream>>>(gp);
  wdist_all_k<<<5440, 256, 0, stream>>>(gp, losses);

  gather_pool_k<<<4096, 256, 0, stream>>>(x, x2s64, x2s32);
  pool_half_k<<<4096, 256, 0, stream>>>(x2s32, x2s16, 16);
  pool_half_k<<<1024, 256, 0, stream>>>(x2s16, x2s8, 8);

  // logits GEMMs bi0-2 on 256-tile kernel: Sb(bf16) = x2_hi * Ws1^T, K=256
  MG2 L2;
  {
    int base = 0;
    for (int bi = 0; bi < 3; bi++) {
      L2.A[bi] = x2Arr[bi]; L2.B[bi] = Ws1 + s1off[bi]; L2.C[bi] = (float*)SArr[bi];
      L2.K[bi] = 256; L2.lda[bi] = 256; L2.ldb[bi] = 256;
      L2.ldcPP[bi] = MS[bi]; L2.CH[bi] = 0;
      L2.gx[bi] = MS[bi]/256;
      L2.base[bi] = base;
      int T = 65536 >> (2*bi);
      base += (MS[bi]/256) * (T/256);
    }
    L2.A[3] = L2.A[2]; L2.B[3] = L2.B[2]; L2.C[3] = L2.C[2];
    L2.K[3] = 256; L2.lda[3] = 256; L2.ldb[3] = 256; L2.ldcPP[3] = 256; L2.CH[3] = 0;
    L2.gx[3] = 1; L2.base[3] = base;   // sentinel = nwg
    L2.nwg = base;  // 1168
  }
  mgemm256_k<<<L2.nwg, 512, 0, stream>>>(L2);

  // logits bi3 (cols=128) on the 128-tile kernel
  MGP L3;
  for (int i = 0; i < 4; i++) {
    L3.A[i] = x2s8; L3.B[i] = Ws1 + s1off[3]; L3.C[i] = (float*)S8;
    L3.K[i] = 256; L3.lda[i] = 256; L3.ldb[i] = 256;
    L3.ldcPP[i] = 128; L3.CH[i] = 0; L3.coff[i] = 0;
    L3.gx[i] = 1; L3.base[i] = (i == 0) ? 0 : 8;
  }
  L3.nwg = 8;
  mgemm_all_k<false><<<8, 256, 0, stream>>>(L3);

  // merged row finalize (bf16 logits in, bf16 att out)
  RFP R;
  for (int bi = 0; bi < 4; bi++) {
    R.S[bi] = SArr[bi]; R.attB[bi] = attArr[bi]; R.x2[bi] = x2Arr[bi];
    R.W[bi] = gp.w[bi]; R.T[bi] = 65536 >> (2*bi);
  }
  row_fin_all_k<<<21760, 256, 0, stream>>>(R, part);

  // merged attn GEMMs on 128-tile kernel: C = att * Ws2^T
  MGP A;
  float* recArr[4] = {out, rec32, rec16, rec8};
  {
    int base = 0;
    for (int bi = 0; bi < 4; bi++) {
      A.A[bi] = attArr[bi]; A.B[bi] = Ws2 + s2off[bi]; A.C[bi] = recArr[bi];
      A.K[bi] = MS[bi]; A.lda[bi] = MS[bi]; A.ldb[bi] = MS[bi];
      A.ldcPP[bi] = (bi == 0) ? 4096 : (4096 >> (2*bi));
      A.CH[bi] = (bi == 0) ? 1024 : 256;
      A.coff[bi] = 0;
      A.gx[bi] = 2;
      A.base[bi] = base;
      int T = 65536 >> (2*bi);
      base += 2 * (T/128);
    }
    A.nwg = base;  // 1360
  }
  mgemm_all_k<true><<<A.nwg, 256, 0, stream>>>(A);

  UP up; up.rec[0] = rec32; up.rec[1] = rec16; up.rec[2] = rec8;
  upsample_all_k<<<3*65536, 256, 0, stream>>>(up, out);

  loss_reduce_k<<<3, 256, 0, stream>>>(part, losses);
}

// Round 15
// 530.798 us; speedup vs baseline: 1.8932x; 1.0874x over previous
//
#include <hip/hip_runtime.h>

#define OUTC (16ull*1024*64*64)

typedef unsigned short u16;
typedef __attribute__((ext_vector_type(8))) __bf16 bf16x8;
typedef __attribute__((ext_vector_type(4))) float f32x4;

struct GP { const float* w[4]; float* g[4]; };
struct UP { const float* rec[3]; };
struct MGP {
  const u16* A[4]; const u16* B[4]; float* C[4];
  int K[4]; int lda[4]; int ldb[4]; int ldcPP[4]; int CH[4]; int coff[4];
  int base[4]; int gx[4]; int nwg;
};
struct MG2 {
  const u16* A[4]; const u16* B[4]; float* C[4];
  int K[4]; int lda[4]; int ldb[4]; int ldcPP[4]; int CH[4];
  int base[4]; int gx[4]; int nwg;
};
struct RFP { u16* S[4]; u16* attB[4]; const u16* x2[4]; const float* W[4]; int T[4]; int ldS[4]; };

__device__ __forceinline__ u16 f2bf(float f) {
  unsigned u = __float_as_uint(f);
  unsigned r = (u + 0x7fffu + ((u >> 16) & 1u)) >> 16;
  return (u16)r;
}
__device__ __forceinline__ float bf2f(u16 h) {
  return __uint_as_float(((unsigned)h) << 16);
}

// async global->LDS, 16B per lane; LDS dest = wave-uniform base + lane*16.
__device__ __forceinline__ void gload16(const void* gsrc, void* ldst) {
  __builtin_amdgcn_global_load_lds(
      (const __attribute__((address_space(1))) void*)gsrc,
      (__attribute__((address_space(3))) void*)ldst, 16, 0, 0);
}

__device__ __forceinline__ float block_sum(float v, float* red) {
  int tid = threadIdx.x;
  red[tid] = v; __syncthreads();
#pragma unroll
  for (int s = 128; s > 0; s >>= 1) {
    if (tid < s) red[tid] += red[tid + s];
    __syncthreads();
  }
  float r = red[0];
  __syncthreads();
  return r;
}

__device__ __forceinline__ float wave_sum(float v) {
#pragma unroll
  for (int m = 32; m > 0; m >>= 1) v += __shfl_xor(v, m, 64);
  return v;
}

__global__ void zero_k(float* part, float* losses) {
  if (blockIdx.x < 12) part[blockIdx.x*256 + threadIdx.x] = 0.f;
  else if (threadIdx.x < 5) losses[threadIdx.x] = 0.f;
}

// ONE pass over x: blk64 token rows (hi bf16) AND blk32 pooled level (hi bf16).
__global__ __launch_bounds__(256) void gather_pool_k(const float* __restrict__ x,
    u16* __restrict__ x2s64, u16* __restrict__ x2s32) {
  __shared__ float lds[32][130];
  int tid = threadIdx.x;
  int b = blockIdx.x;
  int orow = b & 31, ct = (b >> 5) & 7, bb = b >> 8;
  const float* xb = x + ((size_t)(bb*256 + ct*32))*4096 + orow*128;
#pragma unroll
  for (int p = 0; p < 4; p++) {
    int s = p*256 + tid;
    int c = s >> 5, f = s & 31;
    float4 v = *(const float4*)(xb + (size_t)c*4096 + f*4);
    lds[c][f*4+0] = v.x; lds[c][f*4+1] = v.y;
    lds[c][f*4+2] = v.z; lds[c][f*4+3] = v.w;
  }
  __syncthreads();
  {
    int cg = (tid & 3) * 8;
#pragma unroll
    for (int it = 0; it < 2; it++) {
      int tl = it*64 + (tid >> 2);
      size_t row = ((size_t)bb*4096 + (size_t)orow*128 + tl)*256 + ct*32 + cg;
      u16 hi[8];
#pragma unroll
      for (int e = 0; e < 8; e++) hi[e] = f2bf(lds[cg + e][tl]);
      *(uint4*)&x2s64[row] = *(uint4*)hi;
    }
  }
  {
    int c = tid & 31;
#pragma unroll
    for (int p = 0; p < 4; p++) {
      int w = p*8 + (tid >> 5);
      float m = fmaxf(fmaxf(lds[c][2*w], lds[c][2*w+1]),
                      fmaxf(lds[c][64+2*w], lds[c][64+2*w+1]));
      x2s32[((size_t)bb*1024 + (size_t)orow*32 + w)*256 + ct*32 + c] = f2bf(m);
    }
  }
}

__global__ __launch_bounds__(256) void pool_half_k(const u16* __restrict__ src,
    u16* __restrict__ dst, int blk) {
  int t = blockIdx.x, c = threadIdx.x;
  int bb = t / (blk*blk), rw = t - bb*blk*blk;
  int r = rw / blk, w = rw - r*blk;
  int bp = blk*2;
  int pb = bb*bp*bp;
  float m = -INFINITY;
#pragma unroll
  for (int dy = 0; dy < 2; dy++)
#pragma unroll
    for (int dx = 0; dx < 2; dx++)
      m = fmaxf(m, bf2f(src[(size_t)(pb + (2*r+dy)*bp + 2*w+dx)*256 + c]));
  dst[(size_t)t*256 + c] = f2bf(m);
}

// Merged wsplit + wnorm. Ws1 hi-only [M][256] (bi3 padded to 256 rows of zeros);
// Ws2 hi-only [256][M]. grid = 2048 (1920 real + 128 pad-zero blocks).
__global__ __launch_bounds__(256) void wprep_k(GP gp,
    u16* __restrict__ Ws1, u16* __restrict__ Ws2, float* __restrict__ losses) {
  __shared__ float red[256];
  int b = blockIdx.x;
  if (b >= 1920) {  // zero the bi3 pad rows 128..255
    Ws1[(size_t)1792*256 + (size_t)(128 + (b - 1920))*256 + threadIdx.x] = 0;
    return;
  }
  int bi, m, M; size_t s1off, s2off;
  if (b < 1024)      { bi=0; m=b;      M=1024; s1off=0; s2off=0; }
  else if (b < 1536) { bi=1; m=b-1024; M=512;  s1off=(size_t)1024*256; s2off=(size_t)256*1024; }
  else if (b < 1792) { bi=2; m=b-1536; M=256;  s1off=(size_t)1536*256; s2off=(size_t)256*1536; }
  else               { bi=3; m=b-1792; M=128;  s1off=(size_t)1792*256; s2off=(size_t)256*1792; }
  int c = threadIdx.x;
  float w = gp.w[bi][(size_t)m*256 + c];
  u16 h = f2bf(w);
  Ws1[s1off + (size_t)m*256 + c] = h;
  Ws2[s2off + (size_t)c*M + m] = h;
  float s = block_sum(w*w, red);
  if (c == 0) atomicAdd(&losses[2], fabsf(1.f - sqrtf(s)) / (float)M);
}

// Merged exact-f32 W*W^T. grid = 340.
__global__ __launch_bounds__(256) void sgemmbt_all_k(GP gp) {
  __shared__ float As[32][64];
  __shared__ float Bs[32][64];
  int b = blockIdx.x;
  int bi, lt, M, lg;
  if (b < 256)      { bi=0; lt=b;     M=1024; lg=4; }
  else if (b < 320) { bi=1; lt=b-256; M=512;  lg=3; }
  else if (b < 336) { bi=2; lt=b-320; M=256;  lg=2; }
  else              { bi=3; lt=b-336; M=128;  lg=1; }
  const float* A = gp.w[bi];
  float* C = gp.g[bi];
  int gx = 1 << lg;
  int bx = lt & (gx-1), by = lt >> lg;
  int tid = threadIdx.x;
  int tx = tid & 15, ty = tid >> 4;
  int row0 = by << 6, col0 = bx << 6;
  float acc[4][4] = {};
  for (int k0 = 0; k0 < 256; k0 += 32) {
#pragma unroll
    for (int l = 0; l < 2; l++) {
      int i = tid + l*256;
      int kq = i & 7, m = i >> 3;
      float4 v = *(const float4*)(A + (size_t)(row0 + m)*256 + k0 + kq*4);
      As[kq*4+0][m] = v.x; As[kq*4+1][m] = v.y; As[kq*4+2][m] = v.z; As[kq*4+3][m] = v.w;
      float4 w = *(const float4*)(A + (size_t)(col0 + m)*256 + k0 + kq*4);
      Bs[kq*4+0][m] = w.x; Bs[kq*4+1][m] = w.y; Bs[kq*4+2][m] = w.z; Bs[kq*4+3][m] = w.w;
    }
    __syncthreads();
#pragma unroll
    for (int kk = 0; kk < 32; kk++) {
      float4 a = *(const float4*)&As[kk][ty*4];
      float4 bvv = *(const float4*)&Bs[kk][tx*4];
      float av[4] = {a.x, a.y, a.z, a.w};
      float bv[4] = {bvv.x, bvv.y, bvv.z, bvv.w};
#pragma unroll
      for (int i = 0; i < 4; i++)
#pragma unroll
        for (int j = 0; j < 4; j++)
          acc[i][j] = fmaf(av[i], bv[j], acc[i][j]);
    }
    __syncthreads();
  }
#pragma unroll
  for (int i = 0; i < 4; i++)
#pragma unroll
    for (int j = 0; j < 4; j++)
      C[(size_t)(row0 + ty*4 + i)*M + col0 + tx*4 + j] = acc[i][j];
}

// Merged wdist. grid = 5440.
__global__ __launch_bounds__(256) void wdist_all_k(GP gp, float* __restrict__ losses) {
  __shared__ float red[256];
  int b = blockIdx.x;
  int bi, lb, M;
  if (b < 4096)      { bi=0; lb=b;      M=1024; }
  else if (b < 5120) { bi=1; lb=b-4096; M=512; }
  else if (b < 5376) { bi=2; lb=b-5120; M=256; }
  else               { bi=3; lb=b-5376; M=128; }
  const float* G = gp.g[bi];
  int idx = lb*256 + threadIdx.x;
  float acc = 0.f;
  int i = idx / M, j = idx - i*M;
  if (j > i) {
    float d2 = G[(size_t)i*M + i] + G[(size_t)j*M + j] - 2.f*G[(size_t)i*M + j];
    float dist = 1.f - d2;
    if (dist > 0.f) acc = dist;
  }
  float s = block_sum(acc, red);
  if (threadIdx.x == 0) atomicAdd(&losses[4], s * 2.f / ((float)M * (float)(M - 1)));
}

// 128x128-tile MFMA GEMM (2-barrier). SCATTER: f32 scatter-out. !SCATTER: bf16 out.
template<bool SCATTER>
__global__ __launch_bounds__(256) void mgemm_all_k(MGP P) {
  __shared__ __align__(16) u16 As[128*64];
  __shared__ __align__(16) u16 Bs[128*64];
  int wg = blockIdx.x;
  int nwg = P.nwg;
  int q = nwg >> 3, r = nwg & 7;
  int xcd = wg & 7, cidx = wg >> 3;
  int swz = (xcd < r ? xcd*(q+1) : r*(q+1) + (xcd - r)*q) + cidx;
  int bi = (swz >= P.base[1]) + (swz >= P.base[2]) + (swz >= P.base[3]);
  int lt = swz - P.base[bi];
  int gx = P.gx[bi];
  int bx = lt % gx, by = lt / gx;
  const u16* A = P.A[bi];
  const u16* B = P.B[bi];
  float* C = P.C[bi];
  int K = P.K[bi], lda = P.lda[bi], ldb = P.ldb[bi];

  int tid = threadIdx.x;
  int lane = tid & 63;
  int wid = tid >> 6;
  int wr = wid >> 1, wc = wid & 1;
  int fr = lane & 15, ks = lane >> 4;
  int row0 = by << 7, col0 = bx << 7;
  f32x4 acc[4][4] = {};
  int srow = tid >> 3;
  int scol = ((tid & 7) ^ (srow & 7)) * 8;
  const u16* Ap = A + (size_t)(row0 + srow)*lda + scol;
  const u16* Bp = B + (size_t)(col0 + srow)*ldb + scol;
  char* AsB = (char*)As + (size_t)wid*1024;
  char* BsB = (char*)Bs + (size_t)wid*1024;

  for (int k0 = 0; k0 < K; k0 += 64) {
#pragma unroll
    for (int it = 0; it < 4; it++) {
      gload16(Ap + (size_t)(it*32)*lda + k0, AsB + it*4096);
      gload16(Bp + (size_t)(it*32)*ldb + k0, BsB + it*4096);
    }
    __syncthreads();
#pragma unroll
    for (int kk = 0; kk < 2; kk++) {
      bf16x8 af[4], bg[4];
#pragma unroll
      for (int i = 0; i < 4; i++) {
        int rr = wr*64 + i*16 + fr;
        af[i] = *(const bf16x8*)&As[rr*64 + ((kk*32 + ks*8) ^ ((rr & 7) << 3))];
      }
#pragma unroll
      for (int j = 0; j < 4; j++) {
        int rr = wc*64 + j*16 + fr;
        bg[j] = *(const bf16x8*)&Bs[rr*64 + ((kk*32 + ks*8) ^ ((rr & 7) << 3))];
      }
#pragma unroll
      for (int i = 0; i < 4; i++)
#pragma unroll
        for (int j = 0; j < 4; j++)
          acc[i][j] = __builtin_amdgcn_mfma_f32_16x16x32_bf16(af[i], bg[j], acc[i][j], 0, 0, 0);
    }
    __syncthreads();
  }
#pragma unroll
  for (int i = 0; i < 4; i++) {
#pragma unroll
    for (int j = 0; j < 4; j++) {
      int row = row0 + wr*64 + i*16 + ks*4;
      int col = col0 + wc*64 + j*16 + fr;
      if (SCATTER) {
        int PP = P.ldcPP[bi];
        int bb = row / PP, rw = row - bb*PP;
        *(f32x4*)&C[((size_t)(bb*P.CH[bi] + P.coff[bi] + col))*PP + rw] = acc[i][j];
      } else {
        u16* Cb = (u16*)C;
        int ldc = P.ldcPP[bi];
#pragma unroll
        for (int rr = 0; rr < 4; rr++)
          Cb[(size_t)(row + rr)*ldc + col] = f2bf(acc[i][j][rr]);
      }
    }
  }
}

// 256x256-tile, double-buffered, counted-vmcnt MFMA GEMM. bf16 out.
__global__ __launch_bounds__(512, 2) void mgemm256_k(MG2 P) {
  __shared__ __align__(16) u16 As[2][256*64];
  __shared__ __align__(16) u16 Bs[2][256*64];
  int wg = blockIdx.x;
  int nwg = P.nwg;
  int q = nwg >> 3, r = nwg & 7;
  int xcd = wg & 7, cidx = wg >> 3;
  int swz = (xcd < r ? xcd*(q+1) : r*(q+1) + (xcd - r)*q) + cidx;
  int bi = (swz >= P.base[1]) + (swz >= P.base[2]) + (swz >= P.base[3]);
  int lt = swz - P.base[bi];
  int gx = P.gx[bi];
  int bx = lt % gx, by = lt / gx;
  const u16* A = P.A[bi];
  const u16* Bm = P.B[bi];
  float* C = P.C[bi];
  int K = P.K[bi], lda = P.lda[bi], ldb = P.ldb[bi];
  int row0 = by << 8, col0 = bx << 8;

  int tid = threadIdx.x;
  int lane = tid & 63, wid = tid >> 6;
  int wr = wid >> 2, wc = wid & 3;
  int fr = lane & 15, ks = lane >> 4;

  int arow = tid >> 3;
  int presw = ((tid & 7) ^ (arow & 7)) * 8;
  const u16* Ap = A + (size_t)(row0 + arow)*lda + presw;
  const u16* Bp = Bm + (size_t)(col0 + arow)*ldb + presw;
  char* AL = (char*)&As[0][0] + (size_t)wid*1024;
  char* BL = (char*)&Bs[0][0] + (size_t)wid*1024;

  f32x4 acc[8][4] = {};
  int nt = K >> 6;

#define STAGE256(b, kt) { \
    int k0 = (kt) << 6; \
    _Pragma("unroll") \
    for (int ia = 0; ia < 4; ia++) \
      gload16(Ap + (size_t)(ia*64)*lda + k0, AL + (b)*32768 + ia*8192); \
    _Pragma("unroll") \
    for (int ib = 0; ib < 4; ib++) \
      gload16(Bp + (size_t)(ib*64)*ldb + k0, BL + (b)*32768 + ib*8192); \
  }

  STAGE256(0, 0);
  for (int t = 0; t < nt; t++) {
    int b = t & 1;
    if (t + 1 < nt) {
      STAGE256(b ^ 1, t + 1);
      __builtin_amdgcn_sched_barrier(0);
      asm volatile("s_waitcnt vmcnt(8)" ::: "memory");
    } else {
      __builtin_amdgcn_sched_barrier(0);
      asm volatile("s_waitcnt vmcnt(0)" ::: "memory");
    }
    __builtin_amdgcn_sched_barrier(0);
    __builtin_amdgcn_s_barrier();
    __builtin_amdgcn_sched_barrier(0);
    {
      const u16* Ab = &As[b][0];
      const u16* Bb = &Bs[b][0];
#pragma unroll
      for (int kk = 0; kk < 2; kk++) {
        bf16x8 af[8], bg[4];
#pragma unroll
        for (int i = 0; i < 8; i++) {
          int rr = wr*128 + i*16 + fr;
          af[i] = *(const bf16x8*)&Ab[rr*64 + ((kk*32 + ks*8) ^ ((rr & 7) << 3))];
        }
#pragma unroll
        for (int j = 0; j < 4; j++) {
          int rr = wc*64 + j*16 + fr;
          bg[j] = *(const bf16x8*)&Bb[rr*64 + ((kk*32 + ks*8) ^ ((rr & 7) << 3))];
        }
        __builtin_amdgcn_s_setprio(1);
#pragma unroll
        for (int i = 0; i < 8; i++)
#pragma unroll
          for (int j = 0; j < 4; j++)
            acc[i][j] = __builtin_amdgcn_mfma_f32_16x16x32_bf16(af[i], bg[j], acc[i][j], 0, 0, 0);
        __builtin_amdgcn_s_setprio(0);
      }
    }
    __builtin_amdgcn_sched_barrier(0);
    asm volatile("s_waitcnt lgkmcnt(0)" ::: "memory");
    __builtin_amdgcn_sched_barrier(0);
    __builtin_amdgcn_s_barrier();
    __builtin_amdgcn_sched_barrier(0);
  }
#undef STAGE256

#pragma unroll
  for (int i = 0; i < 8; i++) {
#pragma unroll
    for (int j = 0; j < 4; j++) {
      int row = row0 + wr*128 + i*16 + ks*4;
      int col = col0 + wc*64 + j*16 + fr;
      u16* Cb = (u16*)C;
      int ldc = P.ldcPP[bi];
#pragma unroll
      for (int rr = 0; rr < 4; rr++)
        Cb[(size_t)(row + rr)*ldc + col] = f2bf(acc[i][j][rr]);
    }
  }
}

// One WAVE per token row; vectorized: lane l owns contiguous elements
// j in [l*R, (l+1)*R). Reads bf16 logits (ldS pitch), writes packed bf16 att.
template<int R>
__device__ __forceinline__ void row_fin_body(const u16* __restrict__ S_all,
    u16* __restrict__ attB, const u16* __restrict__ x2s, const float* __restrict__ Wm,
    int Tblock, float* __restrict__ part, int t, int ldS) {
  const int M = R*64;
  int lane = threadIdx.x & 63;
  const u16* S = S_all + (size_t)t*ldS + lane*R;
  u16 sv[R];
  if constexpr (R == 16) {
    *(uint4*)&sv[0] = *(const uint4*)&S[0];
    *(uint4*)&sv[8] = *(const uint4*)&S[8];
  } else if constexpr (R == 8) {
    *(uint4*)&sv[0] = *(const uint4*)&S[0];
  } else if constexpr (R == 4) {
    *(uint2*)&sv[0] = *(const uint2*)&S[0];
  } else {
    *(unsigned*)&sv[0] = *(const unsigned*)&S[0];
  }
  float s[R];
#pragma unroll
  for (int i = 0; i < R; i++) s[i] = bf2f(sv[i]);

  // top-2 (value desc, ties -> lower index); j = lane*R + i
  float v0 = -INFINITY, v1 = -INFINITY; int j0 = 0x7fffffff, j1 = 0x7fffffff;
#pragma unroll
  for (int i = 0; i < R; i++) {
    int j = lane*R + i; float sx = s[i];
    if (sx > v0) { v1 = v0; j1 = j0; v0 = sx; j0 = j; }
    else if (sx > v1) { v1 = sx; j1 = j; }
  }
#pragma unroll
  for (int m = 32; m > 0; m >>= 1) {
    float b0 = __shfl_xor(v0, m, 64); int bi0 = __shfl_xor(j0, m, 64);
    float b1 = __shfl_xor(v1, m, 64); int bi1 = __shfl_xor(j1, m, 64);
    if (b0 > v0 || (b0 == v0 && bi0 < j0)) {
      if (v0 > b1 || (v0 == b1 && j0 < bi1)) { v1 = v0; j1 = j0; }
      else { v1 = b1; j1 = bi1; }
      v0 = b0; j0 = bi0;
    } else {
      if (b0 > v1 || (b0 == v1 && bi0 < j1)) { v1 = b0; j1 = bi0; }
    }
  }

  float z = 0.f;
#pragma unroll
  for (int i = 0; i < R; i++) { float p = expf(s[i] - v0); z += p; s[i] = p; }
  z = wave_sum(z);
  float invZ = 1.f / z;

  float l1 = 0.f;
#pragma unroll
  for (int i = 0; i < R; i++) {
    float attv = s[i] * invZ;
    float r = attv - 0.0025f;
    float a = (r > 0.f) ? (r * attv / (r + 1e-12f)) : 0.f;
    l1 += a; s[i] = a;
  }
  l1 = wave_sum(l1);
  float inv = 1.f / fmaxf(l1, 1e-12f);

  u16 ov[R];
  float e = 0.f;
#pragma unroll
  for (int i = 0; i < R; i++) {
    float an = s[i] * inv;
    ov[i] = f2bf(an);
    if (an > 0.f) e += an * logf(an + 1e-12f);
  }
  u16* So = attB + (size_t)t*M + lane*R;
  if constexpr (R == 16) {
    *(uint4*)&So[0] = *(uint4*)&ov[0];
    *(uint4*)&So[8] = *(uint4*)&ov[8];
  } else if constexpr (R == 8) {
    *(uint4*)&So[0] = *(uint4*)&ov[0];
  } else if constexpr (R == 4) {
    *(uint2*)&So[0] = *(uint2*)&ov[0];
  } else {
    *(unsigned*)&So[0] = *(unsigned*)&ov[0];
  }

  float dp2 = 0.f, dn2 = 0.f, cq2 = 0.f;
  const u16* xr = x2s + (size_t)t*256;
  const float* pw = Wm + (size_t)j0*256;
  const float* nw = Wm + (size_t)j1*256;
#pragma unroll
  for (int k2 = 0; k2 < 4; k2++) {
    int c = lane + k2*64;
    float xv = bf2f(xr[c]);
    float p = pw[c], n = nw[c];
    float dp = xv - p + 1e-6f, dn = xv - n + 1e-6f, cq = xv - p;
    dp2 += dp*dp; dn2 += dn*dn; cq2 += cq*cq;
  }
  e = wave_sum(e); dp2 = wave_sum(dp2); dn2 = wave_sum(dn2); cq2 = wave_sum(cq2);
  if (lane == 0) {
    int slot = t & 1023;
    float trip = fmaxf(sqrtf(dp2) - sqrtf(dn2) + 1.f, 0.f);
    atomicAdd(&part[0*1024 + slot], -e / (float)Tblock);
    atomicAdd(&part[1*1024 + slot], trip / (float)Tblock);
    atomicAdd(&part[2*1024 + slot], cq2 / ((float)Tblock * 256.f));
  }
}

// Merged finalize. grid = 21760 (4 waves = 4 tokens/WG).
__global__ __launch_bounds__(256) void row_fin_all_k(RFP P, float* __restrict__ part) {
  int b = blockIdx.x;
  int bi = (b >= 16384) + (b >= 20480) + (b >= 21504);
  int lb = b - (bi == 0 ? 0 : bi == 1 ? 16384 : bi == 2 ? 20480 : 21504);
  int t = lb*4 + (threadIdx.x >> 6);
  switch (bi) {
    case 0: row_fin_body<16>(P.S[0], P.attB[0], P.x2[0], P.W[0], P.T[0], part, t, P.ldS[0]); break;
    case 1: row_fin_body<8> (P.S[1], P.attB[1], P.x2[1], P.W[1], P.T[1], part, t, P.ldS[1]); break;
    case 2: row_fin_body<4> (P.S[2], P.attB[2], P.x2[2], P.W[2], P.T[2], part, t, P.ldS[2]); break;
    default:row_fin_body<2> (P.S[3], P.attB[3], P.x2[3], P.W[3], P.T[3], part, t, P.ldS[3]); break;
  }
}

__global__ __launch_bounds__(256) void loss_reduce_k(const float* __restrict__ part,
                                                     float* __restrict__ losses) {
  __shared__ float red[256];
  int l = blockIdx.x;
  int tid = threadIdx.x;
  float v = 0.f;
  for (int i = tid; i < 1024; i += 256) v += part[l*1024 + i];
  float s = block_sum(v, red);
  if (tid == 0) atomicAdd(&losses[l == 2 ? 3 : l], s);
}

// Merged bilinear upsample, 4 pixels/thread + float4 store. grid = 3*16384.
__global__ __launch_bounds__(256) void upsample_all_k(UP up, float* __restrict__ out) {
  int b = blockIdx.x;
  int ri = b >> 14;
  int blk = 32 >> ri;
  int coff = (ri + 1) * 256;
  const float* rec = up.rec[ri];
  int idx = (b & 16383)*256 + threadIdx.x;
  int w4 = (idx & 15) * 4;
  int r = (idx >> 4) & 63;
  int c = (idx >> 10) & 255;
  int bb = idx >> 18;
  float s = (float)blk * (1.f/64.f);
  float py = ((float)r + 0.5f)*s - 0.5f;
  float fy0 = floorf(py);
  float fy = py - fy0;
  int y0 = (int)fy0;
  int y0c = min(max(y0, 0), blk-1), y1c = min(max(y0+1, 0), blk-1);
  const float* rp = rec + (size_t)(bb*256 + c)*blk*blk;
  const float* r0 = rp + y0c*blk;
  const float* r1 = rp + y1c*blk;
  float ov[4];
#pragma unroll
  for (int e = 0; e < 4; e++) {
    int w = w4 + e;
    float px = ((float)w + 0.5f)*s - 0.5f;
    float fx0 = floorf(px);
    float fx = px - fx0;
    int x0 = (int)fx0;
    int x0c = min(max(x0, 0), blk-1), x1c = min(max(x0+1, 0), blk-1);
    float v00 = r0[x0c], v01 = r0[x1c], v10 = r1[x0c], v11 = r1[x1c];
    ov[e] = (1.f-fy)*((1.f-fx)*v00 + fx*v01) + fy*((1.f-fx)*v10 + fx*v11);
  }
  *(float4*)&out[((size_t)(bb*1024 + coff + c) << 12) + (r << 6) + w4] = *(float4*)ov;
}

extern "C" void kernel_launch(void* const* d_in, const int* in_sizes, int n_in,
                              void* d_out, int out_size, void* d_ws, size_t ws_size,
                              hipStream_t stream) {
  const float* x = (const float*)d_in[0];
  GP gp;
  gp.w[0] = (const float*)d_in[2]; gp.w[1] = (const float*)d_in[3];
  gp.w[2] = (const float*)d_in[4]; gp.w[3] = (const float*)d_in[5];
  float* out = (float*)d_out;
  float* losses = out + OUTC;

  char* ws = (char*)d_ws;
  size_t off = 0;
  float* rec32 = (float*)(ws + off); off += (size_t)16384*256*4;
  float* rec16 = (float*)(ws + off); off += (size_t)4096*256*4;
  float* rec8  = (float*)(ws + off); off += (size_t)1024*256*4;
  float* part  = (float*)(ws + off); off += 3*1024*4;
  off = (off + 255) & ~(size_t)255;
  u16* Ws1 = (u16*)(ws + off); off += (size_t)2048*256*2;       // bi3 padded to 256 rows
  u16* Ws2 = (u16*)(ws + off); off += (size_t)256*1920*2;
  gp.g[0] = (float*)(ws + off); off += (size_t)1024*1024*4;
  gp.g[1] = (float*)(ws + off); off += (size_t)512*512*4;
  gp.g[2] = (float*)(ws + off); off += (size_t)256*256*4;
  gp.g[3] = (float*)(ws + off); off += (size_t)128*128*4;
  u16* x2s64 = (u16*)(ws + off); off += (size_t)65536*256*2;    // 33.5 MB (hi only)
  u16* x2s32 = (u16*)(ws + off); off += (size_t)16384*256*2;
  u16* x2s16 = (u16*)(ws + off); off += (size_t)4096*256*2;
  u16* x2s8  = (u16*)(ws + off); off += (size_t)1024*256*2;
  u16* attB64 = (u16*)(ws + off); off += (size_t)65536*1024*2;  // 134 MB
  u16* attB32 = (u16*)(ws + off); off += (size_t)16384*512*2;
  u16* attB16 = (u16*)(ws + off); off += (size_t)4096*256*2;
  u16* attB8  = (u16*)(ws + off); off += (size_t)1024*128*2;
  u16* S64 = (u16*)(ws + off); off += (size_t)65536*1024*2;     // 134 MB (bf16)
  u16* S32 = (u16*)(ws + off); off += (size_t)16384*512*2;
  u16* S16 = (u16*)(ws + off); off += (size_t)4096*256*2;
  u16* S8  = (u16*)(ws + off); off += (size_t)1024*256*2;       // ld 256 (padded)

  const size_t s1off[4] = {0, (size_t)1024*256, (size_t)1536*256, (size_t)1792*256};
  const size_t s2off[4] = {0, (size_t)256*1024, (size_t)256*1536, (size_t)256*1792};
  const u16* x2Arr[4] = {x2s64, x2s32, x2s16, x2s8};
  u16* attArr[4] = {attB64, attB32, attB16, attB8};
  u16* SArr[4] = {S64, S32, S16, S8};
  const int MS[4] = {1024, 512, 256, 128};

  zero_k<<<13, 256, 0, stream>>>(part, losses);
  wprep_k<<<2048, 256, 0, stream>>>(gp, Ws1, Ws2, losses);
  sgemmbt_all_k<<<340, 256, 0, stream>>>(gp);
  wdist_all_k<<<5440, 256, 0, stream>>>(gp, losses);

  gather_pool_k<<<4096, 256, 0, stream>>>(x, x2s64, x2s32);
  pool_half_k<<<4096, 256, 0, stream>>>(x2s32, x2s16, 16);
  pool_half_k<<<1024, 256, 0, stream>>>(x2s16, x2s8, 8);

  // ALL logits GEMMs on 256-tile kernel: Sb(bf16) = x2_hi * Ws1^T, K=256
  // (bi3 rides along via zero-padded Ws1 rows and ld-256 S8)
  MG2 L2;
  {
    int base = 0;
    for (int bi = 0; bi < 3; bi++) {
      L2.A[bi] = x2Arr[bi]; L2.B[bi] = Ws1 + s1off[bi]; L2.C[bi] = (float*)SArr[bi];
      L2.K[bi] = 256; L2.lda[bi] = 256; L2.ldb[bi] = 256;
      L2.ldcPP[bi] = MS[bi]; L2.CH[bi] = 0;
      L2.gx[bi] = MS[bi]/256;
      L2.base[bi] = base;
      int T = 65536 >> (2*bi);
      base += (MS[bi]/256) * (T/256);
    }
    L2.A[3] = x2s8; L2.B[3] = Ws1 + s1off[3]; L2.C[3] = (float*)S8;
    L2.K[3] = 256; L2.lda[3] = 256; L2.ldb[3] = 256; L2.ldcPP[3] = 256; L2.CH[3] = 0;
    L2.gx[3] = 1; L2.base[3] = base;
    base += 4;                        // 1024 tokens / 256 = 4 row-tiles
    L2.nwg = base;  // 1024 + 128 + 16 + 4 = 1172
  }
  mgemm256_k<<<L2.nwg, 512, 0, stream>>>(L2);

  // merged row finalize (bf16 logits in, bf16 att out, vectorized)
  RFP R;
  for (int bi = 0; bi < 4; bi++) {
    R.S[bi] = SArr[bi]; R.attB[bi] = attArr[bi]; R.x2[bi] = x2Arr[bi];
    R.W[bi] = gp.w[bi]; R.T[bi] = 65536 >> (2*bi);
    R.ldS[bi] = (bi == 3) ? 256 : MS[bi];
  }
  row_fin_all_k<<<21760, 256, 0, stream>>>(R, part);

  // merged attn GEMMs on 128-tile kernel: C = att * Ws2^T
  MGP A;
  float* recArr[4] = {out, rec32, rec16, rec8};
  {
    int base = 0;
    for (int bi = 0; bi < 4; bi++) {
      A.A[bi] = attArr[bi]; A.B[bi] = Ws2 + s2off[bi]; A.C[bi] = recArr[bi];
      A.K[bi] = MS[bi]; A.lda[bi] = MS[bi]; A.ldb[bi] = MS[bi];
      A.ldcPP[bi] = (bi == 0) ? 4096 : (4096 >> (2*bi));
      A.CH[bi] = (bi == 0) ? 1024 : 256;
      A.coff[bi] = 0;
      A.gx[bi] = 2;
      A.base[bi] = base;
      int T = 65536 >> (2*bi);
      base += 2 * (T/128);
    }
    A.nwg = base;  // 1360
  }
  mgemm_all_k<true><<<A.nwg, 256, 0, stream>>>(A);

  UP up; up.rec[0] = rec32; up.rec[1] = rec16; up.rec[2] = rec8;
  upsample_all_k<<<3*16384, 256, 0, stream>>>(up, out);

  loss_reduce_k<<<3, 256, 0, stream>>>(part, losses);
}

// Round 16
// 497.295 us; speedup vs baseline: 2.0208x; 1.0674x over previous
//
#include <hip/hip_runtime.h>

#define OUTC (16ull*1024*64*64)

typedef unsigned short u16;
typedef __attribute__((ext_vector_type(8))) __bf16 bf16x8;
typedef __attribute__((ext_vector_type(4))) float f32x4;

struct GP { const float* w[4]; float* g[4]; };
struct UP { const u16* rec[3]; };
struct MGP {
  const u16* A[4]; const u16* B[4]; float* C[4];
  int K[4]; int lda[4]; int ldb[4]; int ldcPP[4]; int CH[4]; int obf[4];
  int base[4]; int gx[4]; int nwg;
};
struct MG2 {
  const u16* A[4]; const u16* B[4]; float* C[4];
  int K[4]; int lda[4]; int ldb[4]; int ldcPP[4]; int CH[4];
  int base[4]; int gx[4]; int nwg;
};
struct RFP { u16* S[4]; const u16* x2[4]; const float* W[4]; int T[4]; int ldS[4]; };

__device__ __forceinline__ u16 f2bf(float f) {
  unsigned u = __float_as_uint(f);
  unsigned r = (u + 0x7fffu + ((u >> 16) & 1u)) >> 16;
  return (u16)r;
}
__device__ __forceinline__ float bf2f(u16 h) {
  return __uint_as_float(((unsigned)h) << 16);
}

// async global->LDS, 16B per lane; LDS dest = wave-uniform base + lane*16.
__device__ __forceinline__ void gload16(const void* gsrc, void* ldst) {
  __builtin_amdgcn_global_load_lds(
      (const __attribute__((address_space(1))) void*)gsrc,
      (__attribute__((address_space(3))) void*)ldst, 16, 0, 0);
}

__device__ __forceinline__ float block_sum(float v, float* red) {
  int tid = threadIdx.x;
  red[tid] = v; __syncthreads();
#pragma unroll
  for (int s = 128; s > 0; s >>= 1) {
    if (tid < s) red[tid] += red[tid + s];
    __syncthreads();
  }
  float r = red[0];
  __syncthreads();
  return r;
}

__device__ __forceinline__ float wave_sum(float v) {
#pragma unroll
  for (int m = 32; m > 0; m >>= 1) v += __shfl_xor(v, m, 64);
  return v;
}

__global__ void zero_k(float* part, float* losses) {
  if (blockIdx.x < 12) part[blockIdx.x*256 + threadIdx.x] = 0.f;
  else if (threadIdx.x < 5) losses[threadIdx.x] = 0.f;
}

// ONE pass over x: blk64 token rows (hi bf16) AND blk32 pooled level (hi bf16).
__global__ __launch_bounds__(256) void gather_pool_k(const float* __restrict__ x,
    u16* __restrict__ x2s64, u16* __restrict__ x2s32) {
  __shared__ float lds[32][130];
  int tid = threadIdx.x;
  int b = blockIdx.x;
  int orow = b & 31, ct = (b >> 5) & 7, bb = b >> 8;
  const float* xb = x + ((size_t)(bb*256 + ct*32))*4096 + orow*128;
#pragma unroll
  for (int p = 0; p < 4; p++) {
    int s = p*256 + tid;
    int c = s >> 5, f = s & 31;
    float4 v = *(const float4*)(xb + (size_t)c*4096 + f*4);
    lds[c][f*4+0] = v.x; lds[c][f*4+1] = v.y;
    lds[c][f*4+2] = v.z; lds[c][f*4+3] = v.w;
  }
  __syncthreads();
  {
    int cg = (tid & 3) * 8;
#pragma unroll
    for (int it = 0; it < 2; it++) {
      int tl = it*64 + (tid >> 2);
      size_t row = ((size_t)bb*4096 + (size_t)orow*128 + tl)*256 + ct*32 + cg;
      u16 hi[8];
#pragma unroll
      for (int e = 0; e < 8; e++) hi[e] = f2bf(lds[cg + e][tl]);
      *(uint4*)&x2s64[row] = *(uint4*)hi;
    }
  }
  {
    int c = tid & 31;
#pragma unroll
    for (int p = 0; p < 4; p++) {
      int w = p*8 + (tid >> 5);
      float m = fmaxf(fmaxf(lds[c][2*w], lds[c][2*w+1]),
                      fmaxf(lds[c][64+2*w], lds[c][64+2*w+1]));
      x2s32[((size_t)bb*1024 + (size_t)orow*32 + w)*256 + ct*32 + c] = f2bf(m);
    }
  }
}

__global__ __launch_bounds__(256) void pool_half_k(const u16* __restrict__ src,
    u16* __restrict__ dst, int blk) {
  int t = blockIdx.x, c = threadIdx.x;
  int bb = t / (blk*blk), rw = t - bb*blk*blk;
  int r = rw / blk, w = rw - r*blk;
  int bp = blk*2;
  int pb = bb*bp*bp;
  float m = -INFINITY;
#pragma unroll
  for (int dy = 0; dy < 2; dy++)
#pragma unroll
    for (int dx = 0; dx < 2; dx++)
      m = fmaxf(m, bf2f(src[(size_t)(pb + (2*r+dy)*bp + 2*w+dx)*256 + c]));
  dst[(size_t)t*256 + c] = f2bf(m);
}

// Merged wsplit + wnorm. Ws1 hi-only [M][256] (bi3 padded to 256 rows of zeros);
// Ws2 hi-only [256][M]. grid = 2048 (1920 real + 128 pad-zero blocks).
__global__ __launch_bounds__(256) void wprep_k(GP gp,
    u16* __restrict__ Ws1, u16* __restrict__ Ws2, float* __restrict__ losses) {
  __shared__ float red[256];
  int b = blockIdx.x;
  if (b >= 1920) {
    Ws1[(size_t)1792*256 + (size_t)(128 + (b - 1920))*256 + threadIdx.x] = 0;
    return;
  }
  int bi, m, M; size_t s1off, s2off;
  if (b < 1024)      { bi=0; m=b;      M=1024; s1off=0; s2off=0; }
  else if (b < 1536) { bi=1; m=b-1024; M=512;  s1off=(size_t)1024*256; s2off=(size_t)256*1024; }
  else if (b < 1792) { bi=2; m=b-1536; M=256;  s1off=(size_t)1536*256; s2off=(size_t)256*1536; }
  else               { bi=3; m=b-1792; M=128;  s1off=(size_t)1792*256; s2off=(size_t)256*1792; }
  int c = threadIdx.x;
  float w = gp.w[bi][(size_t)m*256 + c];
  u16 h = f2bf(w);
  Ws1[s1off + (size_t)m*256 + c] = h;
  Ws2[s2off + (size_t)c*M + m] = h;
  float s = block_sum(w*w, red);
  if (c == 0) atomicAdd(&losses[2], fabsf(1.f - sqrtf(s)) / (float)M);
}

// Merged exact-f32 W*W^T. grid = 340.
__global__ __launch_bounds__(256) void sgemmbt_all_k(GP gp) {
  __shared__ float As[32][64];
  __shared__ float Bs[32][64];
  int b = blockIdx.x;
  int bi, lt, M, lg;
  if (b < 256)      { bi=0; lt=b;     M=1024; lg=4; }
  else if (b < 320) { bi=1; lt=b-256; M=512;  lg=3; }
  else if (b < 336) { bi=2; lt=b-320; M=256;  lg=2; }
  else              { bi=3; lt=b-336; M=128;  lg=1; }
  const float* A = gp.w[bi];
  float* C = gp.g[bi];
  int gx = 1 << lg;
  int bx = lt & (gx-1), by = lt >> lg;
  int tid = threadIdx.x;
  int tx = tid & 15, ty = tid >> 4;
  int row0 = by << 6, col0 = bx << 6;
  float acc[4][4] = {};
  for (int k0 = 0; k0 < 256; k0 += 32) {
#pragma unroll
    for (int l = 0; l < 2; l++) {
      int i = tid + l*256;
      int kq = i & 7, m = i >> 3;
      float4 v = *(const float4*)(A + (size_t)(row0 + m)*256 + k0 + kq*4);
      As[kq*4+0][m] = v.x; As[kq*4+1][m] = v.y; As[kq*4+2][m] = v.z; As[kq*4+3][m] = v.w;
      float4 w = *(const float4*)(A + (size_t)(col0 + m)*256 + k0 + kq*4);
      Bs[kq*4+0][m] = w.x; Bs[kq*4+1][m] = w.y; Bs[kq*4+2][m] = w.z; Bs[kq*4+3][m] = w.w;
    }
    __syncthreads();
#pragma unroll
    for (int kk = 0; kk < 32; kk++) {
      float4 a = *(const float4*)&As[kk][ty*4];
      float4 bvv = *(const float4*)&Bs[kk][tx*4];
      float av[4] = {a.x, a.y, a.z, a.w};
      float bv[4] = {bvv.x, bvv.y, bvv.z, bvv.w};
#pragma unroll
      for (int i = 0; i < 4; i++)
#pragma unroll
        for (int j = 0; j < 4; j++)
          acc[i][j] = fmaf(av[i], bv[j], acc[i][j]);
    }
    __syncthreads();
  }
#pragma unroll
  for (int i = 0; i < 4; i++)
#pragma unroll
    for (int j = 0; j < 4; j++)
      C[(size_t)(row0 + ty*4 + i)*M + col0 + tx*4 + j] = acc[i][j];
}

// Merged wdist. grid = 5440.
__global__ __launch_bounds__(256) void wdist_all_k(GP gp, float* __restrict__ losses) {
  __shared__ float red[256];
  int b = blockIdx.x;
  int bi, lb, M;
  if (b < 4096)      { bi=0; lb=b;      M=1024; }
  else if (b < 5120) { bi=1; lb=b-4096; M=512; }
  else if (b < 5376) { bi=2; lb=b-5120; M=256; }
  else               { bi=3; lb=b-5376; M=128; }
  const float* G = gp.g[bi];
  int idx = lb*256 + threadIdx.x;
  float acc = 0.f;
  int i = idx / M, j = idx - i*M;
  if (j > i) {
    float d2 = G[(size_t)i*M + i] + G[(size_t)j*M + j] - 2.f*G[(size_t)i*M + j];
    float dist = 1.f - d2;
    if (dist > 0.f) acc = dist;
  }
  float s = block_sum(acc, red);
  if (threadIdx.x == 0) atomicAdd(&losses[4], s * 2.f / ((float)M * (float)(M - 1)));
}

// 128x128-tile MFMA GEMM (2-barrier). Scatter epilogue: f32 (obf=0) or bf16 (obf=1).
__global__ __launch_bounds__(256) void mgemm_all_k(MGP P) {
  __shared__ __align__(16) u16 As[128*64];
  __shared__ __align__(16) u16 Bs[128*64];
  int wg = blockIdx.x;
  int nwg = P.nwg;
  int q = nwg >> 3, r = nwg & 7;
  int xcd = wg & 7, cidx = wg >> 3;
  int swz = (xcd < r ? xcd*(q+1) : r*(q+1) + (xcd - r)*q) + cidx;
  int bi = (swz >= P.base[1]) + (swz >= P.base[2]) + (swz >= P.base[3]);
  int lt = swz - P.base[bi];
  int gx = P.gx[bi];
  int bx = lt % gx, by = lt / gx;
  const u16* A = P.A[bi];
  const u16* B = P.B[bi];
  float* C = P.C[bi];
  int K = P.K[bi], lda = P.lda[bi], ldb = P.ldb[bi];

  int tid = threadIdx.x;
  int lane = tid & 63;
  int wid = tid >> 6;
  int wr = wid >> 1, wc = wid & 1;
  int fr = lane & 15, ks = lane >> 4;
  int row0 = by << 7, col0 = bx << 7;
  f32x4 acc[4][4] = {};
  int srow = tid >> 3;
  int scol = ((tid & 7) ^ (srow & 7)) * 8;
  const u16* Ap = A + (size_t)(row0 + srow)*lda + scol;
  const u16* Bp = B + (size_t)(col0 + srow)*ldb + scol;
  char* AsB = (char*)As + (size_t)wid*1024;
  char* BsB = (char*)Bs + (size_t)wid*1024;

  for (int k0 = 0; k0 < K; k0 += 64) {
#pragma unroll
    for (int it = 0; it < 4; it++) {
      gload16(Ap + (size_t)(it*32)*lda + k0, AsB + it*4096);
      gload16(Bp + (size_t)(it*32)*ldb + k0, BsB + it*4096);
    }
    __syncthreads();
#pragma unroll
    for (int kk = 0; kk < 2; kk++) {
      bf16x8 af[4], bg[4];
#pragma unroll
      for (int i = 0; i < 4; i++) {
        int rr = wr*64 + i*16 + fr;
        af[i] = *(const bf16x8*)&As[rr*64 + ((kk*32 + ks*8) ^ ((rr & 7) << 3))];
      }
#pragma unroll
      for (int j = 0; j < 4; j++) {
        int rr = wc*64 + j*16 + fr;
        bg[j] = *(const bf16x8*)&Bs[rr*64 + ((kk*32 + ks*8) ^ ((rr & 7) << 3))];
      }
#pragma unroll
      for (int i = 0; i < 4; i++)
#pragma unroll
        for (int j = 0; j < 4; j++)
          acc[i][j] = __builtin_amdgcn_mfma_f32_16x16x32_bf16(af[i], bg[j], acc[i][j], 0, 0, 0);
    }
    __syncthreads();
  }
  int PP = P.ldcPP[bi];
  int obf = P.obf[bi];
#pragma unroll
  for (int i = 0; i < 4; i++) {
#pragma unroll
    for (int j = 0; j < 4; j++) {
      int row = row0 + wr*64 + i*16 + ks*4;
      int col = col0 + wc*64 + j*16 + fr;
      int bb = row / PP, rw = row - bb*PP;
      size_t o = ((size_t)(bb*P.CH[bi] + col))*PP + rw;
      if (obf) {
        u16 ov[4];
#pragma unroll
        for (int rr2 = 0; rr2 < 4; rr2++) ov[rr2] = f2bf(acc[i][j][rr2]);
        *(uint2*)&((u16*)C)[o] = *(uint2*)ov;
      } else {
        *(f32x4*)&C[o] = acc[i][j];
      }
    }
  }
}

// 256x256-tile, double-buffered, counted-vmcnt MFMA GEMM. bf16 out.
__global__ __launch_bounds__(512, 2) void mgemm256_k(MG2 P) {
  __shared__ __align__(16) u16 As[2][256*64];
  __shared__ __align__(16) u16 Bs[2][256*64];
  int wg = blockIdx.x;
  int nwg = P.nwg;
  int q = nwg >> 3, r = nwg & 7;
  int xcd = wg & 7, cidx = wg >> 3;
  int swz = (xcd < r ? xcd*(q+1) : r*(q+1) + (xcd - r)*q) + cidx;
  int bi = (swz >= P.base[1]) + (swz >= P.base[2]) + (swz >= P.base[3]);
  int lt = swz - P.base[bi];
  int gx = P.gx[bi];
  int bx = lt % gx, by = lt / gx;
  const u16* A = P.A[bi];
  const u16* Bm = P.B[bi];
  float* C = P.C[bi];
  int K = P.K[bi], lda = P.lda[bi], ldb = P.ldb[bi];
  int row0 = by << 8, col0 = bx << 8;

  int tid = threadIdx.x;
  int lane = tid & 63, wid = tid >> 6;
  int wr = wid >> 2, wc = wid & 3;
  int fr = lane & 15, ks = lane >> 4;

  int arow = tid >> 3;
  int presw = ((tid & 7) ^ (arow & 7)) * 8;
  const u16* Ap = A + (size_t)(row0 + arow)*lda + presw;
  const u16* Bp = Bm + (size_t)(col0 + arow)*ldb + presw;
  char* AL = (char*)&As[0][0] + (size_t)wid*1024;
  char* BL = (char*)&Bs[0][0] + (size_t)wid*1024;

  f32x4 acc[8][4] = {};
  int nt = K >> 6;

#define STAGE256(b, kt) { \
    int k0 = (kt) << 6; \
    _Pragma("unroll") \
    for (int ia = 0; ia < 4; ia++) \
      gload16(Ap + (size_t)(ia*64)*lda + k0, AL + (b)*32768 + ia*8192); \
    _Pragma("unroll") \
    for (int ib = 0; ib < 4; ib++) \
      gload16(Bp + (size_t)(ib*64)*ldb + k0, BL + (b)*32768 + ib*8192); \
  }

  STAGE256(0, 0);
  for (int t = 0; t < nt; t++) {
    int b = t & 1;
    if (t + 1 < nt) {
      STAGE256(b ^ 1, t + 1);
      __builtin_amdgcn_sched_barrier(0);
      asm volatile("s_waitcnt vmcnt(8)" ::: "memory");
    } else {
      __builtin_amdgcn_sched_barrier(0);
      asm volatile("s_waitcnt vmcnt(0)" ::: "memory");
    }
    __builtin_amdgcn_sched_barrier(0);
    __builtin_amdgcn_s_barrier();
    __builtin_amdgcn_sched_barrier(0);
    {
      const u16* Ab = &As[b][0];
      const u16* Bb = &Bs[b][0];
#pragma unroll
      for (int kk = 0; kk < 2; kk++) {
        bf16x8 af[8], bg[4];
#pragma unroll
        for (int i = 0; i < 8; i++) {
          int rr = wr*128 + i*16 + fr;
          af[i] = *(const bf16x8*)&Ab[rr*64 + ((kk*32 + ks*8) ^ ((rr & 7) << 3))];
        }
#pragma unroll
        for (int j = 0; j < 4; j++) {
          int rr = wc*64 + j*16 + fr;
          bg[j] = *(const bf16x8*)&Bb[rr*64 + ((kk*32 + ks*8) ^ ((rr & 7) << 3))];
        }
        __builtin_amdgcn_s_setprio(1);
#pragma unroll
        for (int i = 0; i < 8; i++)
#pragma unroll
          for (int j = 0; j < 4; j++)
            acc[i][j] = __builtin_amdgcn_mfma_f32_16x16x32_bf16(af[i], bg[j], acc[i][j], 0, 0, 0);
        __builtin_amdgcn_s_setprio(0);
      }
    }
    __builtin_amdgcn_sched_barrier(0);
    asm volatile("s_waitcnt lgkmcnt(0)" ::: "memory");
    __builtin_amdgcn_sched_barrier(0);
    __builtin_amdgcn_s_barrier();
    __builtin_amdgcn_sched_barrier(0);
  }
#undef STAGE256

#pragma unroll
  for (int i = 0; i < 8; i++) {
#pragma unroll
    for (int j = 0; j < 4; j++) {
      int row = row0 + wr*128 + i*16 + ks*4;
      int col = col0 + wc*64 + j*16 + fr;
      u16* Cb = (u16*)C;
      int ldc = P.ldcPP[bi];
#pragma unroll
      for (int rr = 0; rr < 4; rr++)
        Cb[(size_t)(row + rr)*ldc + col] = f2bf(acc[i][j][rr]);
    }
  }
}

// One WAVE per token row; vectorized; writes att IN PLACE over S (same row,
// read-fully-then-write, single owning wave -> race-free).
template<int R>
__device__ __forceinline__ void row_fin_body(u16* __restrict__ S_all,
    const u16* __restrict__ x2s, const float* __restrict__ Wm,
    int Tblock, float* __restrict__ part, int t, int ldS) {
  int lane = threadIdx.x & 63;
  u16* S = S_all + (size_t)t*ldS + lane*R;
  u16 sv[R];
  if constexpr (R == 16) {
    *(uint4*)&sv[0] = *(const uint4*)&S[0];
    *(uint4*)&sv[8] = *(const uint4*)&S[8];
  } else if constexpr (R == 8) {
    *(uint4*)&sv[0] = *(const uint4*)&S[0];
  } else if constexpr (R == 4) {
    *(uint2*)&sv[0] = *(const uint2*)&S[0];
  } else {
    *(unsigned*)&sv[0] = *(const unsigned*)&S[0];
  }
  float s[R];
#pragma unroll
  for (int i = 0; i < R; i++) s[i] = bf2f(sv[i]);

  float v0 = -INFINITY, v1 = -INFINITY; int j0 = 0x7fffffff, j1 = 0x7fffffff;
#pragma unroll
  for (int i = 0; i < R; i++) {
    int j = lane*R + i; float sx = s[i];
    if (sx > v0) { v1 = v0; j1 = j0; v0 = sx; j0 = j; }
    else if (sx > v1) { v1 = sx; j1 = j; }
  }
#pragma unroll
  for (int m = 32; m > 0; m >>= 1) {
    float b0 = __shfl_xor(v0, m, 64); int bi0 = __shfl_xor(j0, m, 64);
    float b1 = __shfl_xor(v1, m, 64); int bi1 = __shfl_xor(j1, m, 64);
    if (b0 > v0 || (b0 == v0 && bi0 < j0)) {
      if (v0 > b1 || (v0 == b1 && j0 < bi1)) { v1 = v0; j1 = j0; }
      else { v1 = b1; j1 = bi1; }
      v0 = b0; j0 = bi0;
    } else {
      if (b0 > v1 || (b0 == v1 && bi0 < j1)) { v1 = b0; j1 = bi0; }
    }
  }

  float z = 0.f;
#pragma unroll
  for (int i = 0; i < R; i++) { float p = expf(s[i] - v0); z += p; s[i] = p; }
  z = wave_sum(z);
  float invZ = 1.f / z;

  float l1 = 0.f;
#pragma unroll
  for (int i = 0; i < R; i++) {
    float attv = s[i] * invZ;
    float r = attv - 0.0025f;
    float a = (r > 0.f) ? (r * attv / (r + 1e-12f)) : 0.f;
    l1 += a; s[i] = a;
  }
  l1 = wave_sum(l1);
  float inv = 1.f / fmaxf(l1, 1e-12f);

  u16 ov[R];
  float e = 0.f;
#pragma unroll
  for (int i = 0; i < R; i++) {
    float an = s[i] * inv;
    ov[i] = f2bf(an);
    if (an > 0.f) e += an * logf(an + 1e-12f);
  }
  if constexpr (R == 16) {
    *(uint4*)&S[0] = *(uint4*)&ov[0];
    *(uint4*)&S[8] = *(uint4*)&ov[8];
  } else if constexpr (R == 8) {
    *(uint4*)&S[0] = *(uint4*)&ov[0];
  } else if constexpr (R == 4) {
    *(uint2*)&S[0] = *(uint2*)&ov[0];
  } else {
    *(unsigned*)&S[0] = *(unsigned*)&ov[0];
  }

  float dp2 = 0.f, dn2 = 0.f, cq2 = 0.f;
  const u16* xr = x2s + (size_t)t*256;
  const float* pw = Wm + (size_t)j0*256;
  const float* nw = Wm + (size_t)j1*256;
#pragma unroll
  for (int k2 = 0; k2 < 4; k2++) {
    int c = lane + k2*64;
    float xv = bf2f(xr[c]);
    float p = pw[c], n = nw[c];
    float dp = xv - p + 1e-6f, dn = xv - n + 1e-6f, cq = xv - p;
    dp2 += dp*dp; dn2 += dn*dn; cq2 += cq*cq;
  }
  e = wave_sum(e); dp2 = wave_sum(dp2); dn2 = wave_sum(dn2); cq2 = wave_sum(cq2);
  if (lane == 0) {
    int slot = t & 1023;
    float trip = fmaxf(sqrtf(dp2) - sqrtf(dn2) + 1.f, 0.f);
    atomicAdd(&part[0*1024 + slot], -e / (float)Tblock);
    atomicAdd(&part[1*1024 + slot], trip / (float)Tblock);
    atomicAdd(&part[2*1024 + slot], cq2 / ((float)Tblock * 256.f));
  }
}

// Merged finalize. grid = 21760 (4 waves = 4 tokens/WG).
__global__ __launch_bounds__(256) void row_fin_all_k(RFP P, float* __restrict__ part) {
  int b = blockIdx.x;
  int bi = (b >= 16384) + (b >= 20480) + (b >= 21504);
  int lb = b - (bi == 0 ? 0 : bi == 1 ? 16384 : bi == 2 ? 20480 : 21504);
  int t = lb*4 + (threadIdx.x >> 6);
  switch (bi) {
    case 0: row_fin_body<16>(P.S[0], P.x2[0], P.W[0], P.T[0], part, t, P.ldS[0]); break;
    case 1: row_fin_body<8> (P.S[1], P.x2[1], P.W[1], P.T[1], part, t, P.ldS[1]); break;
    case 2: row_fin_body<4> (P.S[2], P.x2[2], P.W[2], P.T[2], part, t, P.ldS[2]); break;
    default:row_fin_body<2> (P.S[3], P.x2[3], P.W[3], P.T[3], part, t, P.ldS[3]); break;
  }
}

__global__ __launch_bounds__(256) void loss_reduce_k(const float* __restrict__ part,
                                                     float* __restrict__ losses) {
  __shared__ float red[256];
  int l = blockIdx.x;
  int tid = threadIdx.x;
  float v = 0.f;
  for (int i = tid; i < 1024; i += 256) v += part[l*1024 + i];
  float s = block_sum(v, red);
  if (tid == 0) atomicAdd(&losses[l == 2 ? 3 : l], s);
}

// Merged bilinear upsample from bf16 rec, 4 pixels/thread + float4 store. grid = 3*16384.
__global__ __launch_bounds__(256) void upsample_all_k(UP up, float* __restrict__ out) {
  int b = blockIdx.x;
  int ri = b >> 14;
  int blk = 32 >> ri;
  int coff = (ri + 1) * 256;
  const u16* rec = up.rec[ri];
  int idx = (b & 16383)*256 + threadIdx.x;
  int w4 = (idx & 15) * 4;
  int r = (idx >> 4) & 63;
  int c = (idx >> 10) & 255;
  int bb = idx >> 18;
  float s = (float)blk * (1.f/64.f);
  float py = ((float)r + 0.5f)*s - 0.5f;
  float fy0 = floorf(py);
  float fy = py - fy0;
  int y0 = (int)fy0;
  int y0c = min(max(y0, 0), blk-1), y1c = min(max(y0+1, 0), blk-1);
  const u16* rp = rec + (size_t)(bb*256 + c)*blk*blk;
  const u16* r0 = rp + y0c*blk;
  const u16* r1 = rp + y1c*blk;
  float ov[4];
#pragma unroll
  for (int e = 0; e < 4; e++) {
    int w = w4 + e;
    float px = ((float)w + 0.5f)*s - 0.5f;
    float fx0 = floorf(px);
    float fx = px - fx0;
    int x0 = (int)fx0;
    int x0c = min(max(x0, 0), blk-1), x1c = min(max(x0+1, 0), blk-1);
    float v00 = bf2f(r0[x0c]), v01 = bf2f(r0[x1c]);
    float v10 = bf2f(r1[x0c]), v11 = bf2f(r1[x1c]);
    ov[e] = (1.f-fy)*((1.f-fx)*v00 + fx*v01) + fy*((1.f-fx)*v10 + fx*v11);
  }
  *(float4*)&out[((size_t)(bb*1024 + coff + c) << 12) + (r << 6) + w4] = *(float4*)ov;
}

extern "C" void kernel_launch(void* const* d_in, const int* in_sizes, int n_in,
                              void* d_out, int out_size, void* d_ws, size_t ws_size,
                              hipStream_t stream) {
  const float* x = (const float*)d_in[0];
  GP gp;
  gp.w[0] = (const float*)d_in[2]; gp.w[1] = (const float*)d_in[3];
  gp.w[2] = (const float*)d_in[4]; gp.w[3] = (const float*)d_in[5];
  float* out = (float*)d_out;
  float* losses = out + OUTC;

  char* ws = (char*)d_ws;
  size_t off = 0;
  u16* rec32 = (u16*)(ws + off); off += (size_t)16384*256*2;    // bf16 rec
  u16* rec16 = (u16*)(ws + off); off += (size_t)4096*256*2;
  u16* rec8  = (u16*)(ws + off); off += (size_t)1024*256*2;
  float* part  = (float*)(ws + off); off += 3*1024*4;
  off = (off + 255) & ~(size_t)255;
  u16* Ws1 = (u16*)(ws + off); off += (size_t)2048*256*2;
  u16* Ws2 = (u16*)(ws + off); off += (size_t)256*1920*2;
  gp.g[0] = (float*)(ws + off); off += (size_t)1024*1024*4;
  gp.g[1] = (float*)(ws + off); off += (size_t)512*512*4;
  gp.g[2] = (float*)(ws + off); off += (size_t)256*256*4;
  gp.g[3] = (float*)(ws + off); off += (size_t)128*128*4;
  u16* x2s64 = (u16*)(ws + off); off += (size_t)65536*256*2;    // 33.5 MB
  u16* x2s32 = (u16*)(ws + off); off += (size_t)16384*256*2;
  u16* x2s16 = (u16*)(ws + off); off += (size_t)4096*256*2;
  u16* x2s8  = (u16*)(ws + off); off += (size_t)1024*256*2;
  u16* S64 = (u16*)(ws + off); off += (size_t)65536*1024*2;     // 134 MB; att in place
  u16* S32 = (u16*)(ws + off); off += (size_t)16384*512*2;
  u16* S16 = (u16*)(ws + off); off += (size_t)4096*256*2;
  u16* S8  = (u16*)(ws + off); off += (size_t)1024*256*2;       // ld 256

  const size_t s1off[4] = {0, (size_t)1024*256, (size_t)1536*256, (size_t)1792*256};
  const size_t s2off[4] = {0, (size_t)256*1024, (size_t)256*1536, (size_t)256*1792};
  const u16* x2Arr[4] = {x2s64, x2s32, x2s16, x2s8};
  u16* SArr[4] = {S64, S32, S16, S8};
  const int MS[4] = {1024, 512, 256, 128};
  const int ldSArr[4] = {1024, 512, 256, 256};

  zero_k<<<13, 256, 0, stream>>>(part, losses);
  wprep_k<<<2048, 256, 0, stream>>>(gp, Ws1, Ws2, losses);
  sgemmbt_all_k<<<340, 256, 0, stream>>>(gp);
  wdist_all_k<<<5440, 256, 0, stream>>>(gp, losses);

  gather_pool_k<<<4096, 256, 0, stream>>>(x, x2s64, x2s32);
  pool_half_k<<<4096, 256, 0, stream>>>(x2s32, x2s16, 16);
  pool_half_k<<<1024, 256, 0, stream>>>(x2s16, x2s8, 8);

  // ALL logits GEMMs on 256-tile kernel: Sb(bf16) = x2_hi * Ws1^T, K=256
  MG2 L2;
  {
    int base = 0;
    for (int bi = 0; bi < 3; bi++) {
      L2.A[bi] = x2Arr[bi]; L2.B[bi] = Ws1 + s1off[bi]; L2.C[bi] = (float*)SArr[bi];
      L2.K[bi] = 256; L2.lda[bi] = 256; L2.ldb[bi] = 256;
      L2.ldcPP[bi] = MS[bi]; L2.CH[bi] = 0;
      L2.gx[bi] = MS[bi]/256;
      L2.base[bi] = base;
      int T = 65536 >> (2*bi);
      base += (MS[bi]/256) * (T/256);
    }
    L2.A[3] = x2s8; L2.B[3] = Ws1 + s1off[3]; L2.C[3] = (float*)S8;
    L2.K[3] = 256; L2.lda[3] = 256; L2.ldb[3] = 256; L2.ldcPP[3] = 256; L2.CH[3] = 0;
    L2.gx[3] = 1; L2.base[3] = base;
    base += 4;
    L2.nwg = base;  // 1172
  }
  mgemm256_k<<<L2.nwg, 512, 0, stream>>>(L2);

  // merged row finalize (in-place att over S)
  RFP R;
  for (int bi = 0; bi < 4; bi++) {
    R.S[bi] = SArr[bi]; R.x2[bi] = x2Arr[bi];
    R.W[bi] = gp.w[bi]; R.T[bi] = 65536 >> (2*bi);
    R.ldS[bi] = ldSArr[bi];
  }
  row_fin_all_k<<<21760, 256, 0, stream>>>(R, part);

  // merged attn GEMMs on 128-tile kernel: C = att(in S) * Ws2^T
  MGP A;
  float* recArr[4] = {out, (float*)rec32, (float*)rec16, (float*)rec8};
  {
    int base = 0;
    for (int bi = 0; bi < 4; bi++) {
      A.A[bi] = SArr[bi]; A.B[bi] = Ws2 + s2off[bi]; A.C[bi] = recArr[bi];
      A.K[bi] = MS[bi]; A.lda[bi] = ldSArr[bi]; A.ldb[bi] = MS[bi];
      A.ldcPP[bi] = (bi == 0) ? 4096 : (4096 >> (2*bi));
      A.CH[bi] = (bi == 0) ? 1024 : 256;
      A.obf[bi] = (bi == 0) ? 0 : 1;
      A.gx[bi] = 2;
      A.base[bi] = base;
      int T = 65536 >> (2*bi);
      base += 2 * (T/128);
    }
    A.nwg = base;  // 1360
  }
  mgemm_all_k<<<A.nwg, 256, 0, stream>>>(A);

  UP up; up.rec[0] = rec32; up.rec[1] = rec16; up.rec[2] = rec8;
  upsample_all_k<<<3*16384, 256, 0, stream>>>(up, out);

  loss_reduce_k<<<3, 256, 0, stream>>>(part, losses);
}

// Round 17
// 489.877 us; speedup vs baseline: 2.0514x; 1.0151x over previous
//
#include <hip/hip_runtime.h>

#define OUTC (16ull*1024*64*64)

typedef unsigned short u16;
typedef __attribute__((ext_vector_type(8))) __bf16 bf16x8;
typedef __attribute__((ext_vector_type(4))) float f32x4;

struct GP { const float* w[4]; float* g[4]; };
struct UP { const u16* rec[3]; };
struct MGP {
  const u16* A[4]; const u16* B[4]; float* C[4];
  int K[4]; int lda[4]; int ldb[4]; int ldcPP[4]; int CH[4]; int obf[4];
  int base[4]; int gx[4]; int nwg;
};
struct MG2 {
  const u16* A[4]; const u16* B[4]; float* C[4];
  int K[4]; int lda[4]; int ldb[4]; int ldcPP[4]; int CH[4];
  int base[4]; int gx[4]; int nwg;
};
struct RFP { u16* S[4]; const u16* x2[4]; const float* W[4]; int T[4]; int ldS[4]; };

__device__ __forceinline__ u16 f2bf(float f) {
  unsigned u = __float_as_uint(f);
  unsigned r = (u + 0x7fffu + ((u >> 16) & 1u)) >> 16;
  return (u16)r;
}
__device__ __forceinline__ float bf2f(u16 h) {
  return __uint_as_float(((unsigned)h) << 16);
}

// async global->LDS, 16B per lane; LDS dest = wave-uniform base + lane*16.
__device__ __forceinline__ void gload16(const void* gsrc, void* ldst) {
  __builtin_amdgcn_global_load_lds(
      (const __attribute__((address_space(1))) void*)gsrc,
      (__attribute__((address_space(3))) void*)ldst, 16, 0, 0);
}

__device__ __forceinline__ float block_sum(float v, float* red) {
  int tid = threadIdx.x;
  red[tid] = v; __syncthreads();
#pragma unroll
  for (int s = 128; s > 0; s >>= 1) {
    if (tid < s) red[tid] += red[tid + s];
    __syncthreads();
  }
  float r = red[0];
  __syncthreads();
  return r;
}

__device__ __forceinline__ float wave_sum(float v) {
#pragma unroll
  for (int m = 32; m > 0; m >>= 1) v += __shfl_xor(v, m, 64);
  return v;
}

__global__ void zero_k(float* part, float* losses) {
  if (blockIdx.x < 12) part[blockIdx.x*256 + threadIdx.x] = 0.f;
  else if (threadIdx.x < 5) losses[threadIdx.x] = 0.f;
}

// ONE pass over x: blk64 token rows (hi bf16) AND blk32 pooled level (hi bf16).
__global__ __launch_bounds__(256) void gather_pool_k(const float* __restrict__ x,
    u16* __restrict__ x2s64, u16* __restrict__ x2s32) {
  __shared__ float lds[32][130];
  int tid = threadIdx.x;
  int b = blockIdx.x;
  int orow = b & 31, ct = (b >> 5) & 7, bb = b >> 8;
  const float* xb = x + ((size_t)(bb*256 + ct*32))*4096 + orow*128;
#pragma unroll
  for (int p = 0; p < 4; p++) {
    int s = p*256 + tid;
    int c = s >> 5, f = s & 31;
    float4 v = *(const float4*)(xb + (size_t)c*4096 + f*4);
    lds[c][f*4+0] = v.x; lds[c][f*4+1] = v.y;
    lds[c][f*4+2] = v.z; lds[c][f*4+3] = v.w;
  }
  __syncthreads();
  {
    int cg = (tid & 3) * 8;
#pragma unroll
    for (int it = 0; it < 2; it++) {
      int tl = it*64 + (tid >> 2);
      size_t row = ((size_t)bb*4096 + (size_t)orow*128 + tl)*256 + ct*32 + cg;
      u16 hi[8];
#pragma unroll
      for (int e = 0; e < 8; e++) hi[e] = f2bf(lds[cg + e][tl]);
      *(uint4*)&x2s64[row] = *(uint4*)hi;
    }
  }
  {
    int c = tid & 31;
#pragma unroll
    for (int p = 0; p < 4; p++) {
      int w = p*8 + (tid >> 5);
      float m = fmaxf(fmaxf(lds[c][2*w], lds[c][2*w+1]),
                      fmaxf(lds[c][64+2*w], lds[c][64+2*w+1]));
      x2s32[((size_t)bb*1024 + (size_t)orow*32 + w)*256 + ct*32 + c] = f2bf(m);
    }
  }
}

__global__ __launch_bounds__(256) void pool_half_k(const u16* __restrict__ src,
    u16* __restrict__ dst, int blk) {
  int t = blockIdx.x, c = threadIdx.x;
  int bb = t / (blk*blk), rw = t - bb*blk*blk;
  int r = rw / blk, w = rw - r*blk;
  int bp = blk*2;
  int pb = bb*bp*bp;
  float m = -INFINITY;
#pragma unroll
  for (int dy = 0; dy < 2; dy++)
#pragma unroll
    for (int dx = 0; dx < 2; dx++)
      m = fmaxf(m, bf2f(src[(size_t)(pb + (2*r+dy)*bp + 2*w+dx)*256 + c]));
  dst[(size_t)t*256 + c] = f2bf(m);
}

// Merged wsplit + wnorm. Ws1 hi-only [M][256] (bi3 padded to 256 rows of zeros);
// Ws2 hi-only [256][M]. grid = 2048.
__global__ __launch_bounds__(256) void wprep_k(GP gp,
    u16* __restrict__ Ws1, u16* __restrict__ Ws2, float* __restrict__ losses) {
  __shared__ float red[256];
  int b = blockIdx.x;
  if (b >= 1920) {
    Ws1[(size_t)1792*256 + (size_t)(128 + (b - 1920))*256 + threadIdx.x] = 0;
    return;
  }
  int bi, m, M; size_t s1off, s2off;
  if (b < 1024)      { bi=0; m=b;      M=1024; s1off=0; s2off=0; }
  else if (b < 1536) { bi=1; m=b-1024; M=512;  s1off=(size_t)1024*256; s2off=(size_t)256*1024; }
  else if (b < 1792) { bi=2; m=b-1536; M=256;  s1off=(size_t)1536*256; s2off=(size_t)256*1536; }
  else               { bi=3; m=b-1792; M=128;  s1off=(size_t)1792*256; s2off=(size_t)256*1792; }
  int c = threadIdx.x;
  float w = gp.w[bi][(size_t)m*256 + c];
  u16 h = f2bf(w);
  Ws1[s1off + (size_t)m*256 + c] = h;
  Ws2[s2off + (size_t)c*M + m] = h;
  float s = block_sum(w*w, red);
  if (c == 0) atomicAdd(&losses[2], fabsf(1.f - sqrtf(s)) / (float)M);
}

// Merged exact-f32 W*W^T. grid = 340.
__global__ __launch_bounds__(256) void sgemmbt_all_k(GP gp) {
  __shared__ float As[32][64];
  __shared__ float Bs[32][64];
  int b = blockIdx.x;
  int bi, lt, M, lg;
  if (b < 256)      { bi=0; lt=b;     M=1024; lg=4; }
  else if (b < 320) { bi=1; lt=b-256; M=512;  lg=3; }
  else if (b < 336) { bi=2; lt=b-320; M=256;  lg=2; }
  else              { bi=3; lt=b-336; M=128;  lg=1; }
  const float* A = gp.w[bi];
  float* C = gp.g[bi];
  int gx = 1 << lg;
  int bx = lt & (gx-1), by = lt >> lg;
  int tid = threadIdx.x;
  int tx = tid & 15, ty = tid >> 4;
  int row0 = by << 6, col0 = bx << 6;
  float acc[4][4] = {};
  for (int k0 = 0; k0 < 256; k0 += 32) {
#pragma unroll
    for (int l = 0; l < 2; l++) {
      int i = tid + l*256;
      int kq = i & 7, m = i >> 3;
      float4 v = *(const float4*)(A + (size_t)(row0 + m)*256 + k0 + kq*4);
      As[kq*4+0][m] = v.x; As[kq*4+1][m] = v.y; As[kq*4+2][m] = v.z; As[kq*4+3][m] = v.w;
      float4 w = *(const float4*)(A + (size_t)(col0 + m)*256 + k0 + kq*4);
      Bs[kq*4+0][m] = w.x; Bs[kq*4+1][m] = w.y; Bs[kq*4+2][m] = w.z; Bs[kq*4+3][m] = w.w;
    }
    __syncthreads();
#pragma unroll
    for (int kk = 0; kk < 32; kk++) {
      float4 a = *(const float4*)&As[kk][ty*4];
      float4 bvv = *(const float4*)&Bs[kk][tx*4];
      float av[4] = {a.x, a.y, a.z, a.w};
      float bv[4] = {bvv.x, bvv.y, bvv.z, bvv.w};
#pragma unroll
      for (int i = 0; i < 4; i++)
#pragma unroll
        for (int j = 0; j < 4; j++)
          acc[i][j] = fmaf(av[i], bv[j], acc[i][j]);
    }
    __syncthreads();
  }
#pragma unroll
  for (int i = 0; i < 4; i++)
#pragma unroll
    for (int j = 0; j < 4; j++)
      C[(size_t)(row0 + ty*4 + i)*M + col0 + tx*4 + j] = acc[i][j];
}

// Merged wdist. grid = 5440.
__global__ __launch_bounds__(256) void wdist_all_k(GP gp, float* __restrict__ losses) {
  __shared__ float red[256];
  int b = blockIdx.x;
  int bi, lb, M;
  if (b < 4096)      { bi=0; lb=b;      M=1024; }
  else if (b < 5120) { bi=1; lb=b-4096; M=512; }
  else if (b < 5376) { bi=2; lb=b-5120; M=256; }
  else               { bi=3; lb=b-5376; M=128; }
  const float* G = gp.g[bi];
  int idx = lb*256 + threadIdx.x;
  float acc = 0.f;
  int i = idx / M, j = idx - i*M;
  if (j > i) {
    float d2 = G[(size_t)i*M + i] + G[(size_t)j*M + j] - 2.f*G[(size_t)i*M + j];
    float dist = 1.f - d2;
    if (dist > 0.f) acc = dist;
  }
  float s = block_sum(acc, red);
  if (threadIdx.x == 0) atomicAdd(&losses[4], s * 2.f / ((float)M * (float)(M - 1)));
}

// 128x128-tile, DOUBLE-BUFFERED counted-vmcnt MFMA GEMM (mgemm256 schedule at
// 128^2; 64 KB LDS -> 2 blocks/CU). Scatter epilogue: f32 (obf=0) or bf16 (obf=1).
__global__ __launch_bounds__(256) void mgemm128db_k(MGP P) {
  __shared__ __align__(16) u16 As[2][128*64];
  __shared__ __align__(16) u16 Bs[2][128*64];
  int wg = blockIdx.x;
  int nwg = P.nwg;
  int q = nwg >> 3, r = nwg & 7;
  int xcd = wg & 7, cidx = wg >> 3;
  int swz = (xcd < r ? xcd*(q+1) : r*(q+1) + (xcd - r)*q) + cidx;
  int bi = (swz >= P.base[1]) + (swz >= P.base[2]) + (swz >= P.base[3]);
  int lt = swz - P.base[bi];
  int gx = P.gx[bi];
  int bx = lt % gx, by = lt / gx;
  const u16* A = P.A[bi];
  const u16* B = P.B[bi];
  float* C = P.C[bi];
  int K = P.K[bi], lda = P.lda[bi], ldb = P.ldb[bi];

  int tid = threadIdx.x;
  int lane = tid & 63;
  int wid = tid >> 6;
  int wr = wid >> 1, wc = wid & 1;
  int fr = lane & 15, ks = lane >> 4;
  int row0 = by << 7, col0 = bx << 7;
  f32x4 acc[4][4] = {};
  int srow = tid >> 3;
  int scol = ((tid & 7) ^ (srow & 7)) * 8;
  const u16* Ap = A + (size_t)(row0 + srow)*lda + scol;
  const u16* Bp = B + (size_t)(col0 + srow)*ldb + scol;
  char* AL = (char*)&As[0][0] + (size_t)wid*1024;
  char* BL = (char*)&Bs[0][0] + (size_t)wid*1024;
  int nt = K >> 6;

#define STAGE128(b, kt) { \
    int k0 = (kt) << 6; \
    _Pragma("unroll") \
    for (int it = 0; it < 4; it++) { \
      gload16(Ap + (size_t)(it*32)*lda + k0, AL + (b)*16384 + it*4096); \
      gload16(Bp + (size_t)(it*32)*ldb + k0, BL + (b)*16384 + it*4096); \
    } \
  }

  STAGE128(0, 0);
  for (int t = 0; t < nt; t++) {
    int b = t & 1;
    if (t + 1 < nt) {
      STAGE128(b ^ 1, t + 1);
      __builtin_amdgcn_sched_barrier(0);
      asm volatile("s_waitcnt vmcnt(8)" ::: "memory");   // tile t landed; t+1 in flight
    } else {
      __builtin_amdgcn_sched_barrier(0);
      asm volatile("s_waitcnt vmcnt(0)" ::: "memory");
    }
    __builtin_amdgcn_sched_barrier(0);
    __builtin_amdgcn_s_barrier();
    __builtin_amdgcn_sched_barrier(0);
    {
      const u16* Ab = &As[b][0];
      const u16* Bb = &Bs[b][0];
#pragma unroll
      for (int kk = 0; kk < 2; kk++) {
        bf16x8 af[4], bg[4];
#pragma unroll
        for (int i = 0; i < 4; i++) {
          int rr = wr*64 + i*16 + fr;
          af[i] = *(const bf16x8*)&Ab[rr*64 + ((kk*32 + ks*8) ^ ((rr & 7) << 3))];
        }
#pragma unroll
        for (int j = 0; j < 4; j++) {
          int rr = wc*64 + j*16 + fr;
          bg[j] = *(const bf16x8*)&Bb[rr*64 + ((kk*32 + ks*8) ^ ((rr & 7) << 3))];
        }
        __builtin_amdgcn_s_setprio(1);
#pragma unroll
        for (int i = 0; i < 4; i++)
#pragma unroll
          for (int j = 0; j < 4; j++)
            acc[i][j] = __builtin_amdgcn_mfma_f32_16x16x32_bf16(af[i], bg[j], acc[i][j], 0, 0, 0);
        __builtin_amdgcn_s_setprio(0);
      }
    }
    __builtin_amdgcn_sched_barrier(0);
    asm volatile("s_waitcnt lgkmcnt(0)" ::: "memory");
    __builtin_amdgcn_sched_barrier(0);
    __builtin_amdgcn_s_barrier();
    __builtin_amdgcn_sched_barrier(0);
  }
#undef STAGE128

  int PP = P.ldcPP[bi];
  int obf = P.obf[bi];
#pragma unroll
  for (int i = 0; i < 4; i++) {
#pragma unroll
    for (int j = 0; j < 4; j++) {
      int row = row0 + wr*64 + i*16 + ks*4;
      int col = col0 + wc*64 + j*16 + fr;
      int bb = row / PP, rw = row - bb*PP;
      size_t o = ((size_t)(bb*P.CH[bi] + col))*PP + rw;
      if (obf) {
        u16 ov[4];
#pragma unroll
        for (int rr2 = 0; rr2 < 4; rr2++) ov[rr2] = f2bf(acc[i][j][rr2]);
        *(uint2*)&((u16*)C)[o] = *(uint2*)ov;
      } else {
        *(f32x4*)&C[o] = acc[i][j];
      }
    }
  }
}

// 256x256-tile, double-buffered, counted-vmcnt MFMA GEMM. bf16 out.
__global__ __launch_bounds__(512, 2) void mgemm256_k(MG2 P) {
  __shared__ __align__(16) u16 As[2][256*64];
  __shared__ __align__(16) u16 Bs[2][256*64];
  int wg = blockIdx.x;
  int nwg = P.nwg;
  int q = nwg >> 3, r = nwg & 7;
  int xcd = wg & 7, cidx = wg >> 3;
  int swz = (xcd < r ? xcd*(q+1) : r*(q+1) + (xcd - r)*q) + cidx;
  int bi = (swz >= P.base[1]) + (swz >= P.base[2]) + (swz >= P.base[3]);
  int lt = swz - P.base[bi];
  int gx = P.gx[bi];
  int bx = lt % gx, by = lt / gx;
  const u16* A = P.A[bi];
  const u16* Bm = P.B[bi];
  float* C = P.C[bi];
  int K = P.K[bi], lda = P.lda[bi], ldb = P.ldb[bi];
  int row0 = by << 8, col0 = bx << 8;

  int tid = threadIdx.x;
  int lane = tid & 63, wid = tid >> 6;
  int wr = wid >> 2, wc = wid & 3;
  int fr = lane & 15, ks = lane >> 4;

  int arow = tid >> 3;
  int presw = ((tid & 7) ^ (arow & 7)) * 8;
  const u16* Ap = A + (size_t)(row0 + arow)*lda + presw;
  const u16* Bp = Bm + (size_t)(col0 + arow)*ldb + presw;
  char* AL = (char*)&As[0][0] + (size_t)wid*1024;
  char* BL = (char*)&Bs[0][0] + (size_t)wid*1024;

  f32x4 acc[8][4] = {};
  int nt = K >> 6;

#define STAGE256(b, kt) { \
    int k0 = (kt) << 6; \
    _Pragma("unroll") \
    for (int ia = 0; ia < 4; ia++) \
      gload16(Ap + (size_t)(ia*64)*lda + k0, AL + (b)*32768 + ia*8192); \
    _Pragma("unroll") \
    for (int ib = 0; ib < 4; ib++) \
      gload16(Bp + (size_t)(ib*64)*ldb + k0, BL + (b)*32768 + ib*8192); \
  }

  STAGE256(0, 0);
  for (int t = 0; t < nt; t++) {
    int b = t & 1;
    if (t + 1 < nt) {
      STAGE256(b ^ 1, t + 1);
      __builtin_amdgcn_sched_barrier(0);
      asm volatile("s_waitcnt vmcnt(8)" ::: "memory");
    } else {
      __builtin_amdgcn_sched_barrier(0);
      asm volatile("s_waitcnt vmcnt(0)" ::: "memory");
    }
    __builtin_amdgcn_sched_barrier(0);
    __builtin_amdgcn_s_barrier();
    __builtin_amdgcn_sched_barrier(0);
    {
      const u16* Ab = &As[b][0];
      const u16* Bb = &Bs[b][0];
#pragma unroll
      for (int kk = 0; kk < 2; kk++) {
        bf16x8 af[8], bg[4];
#pragma unroll
        for (int i = 0; i < 8; i++) {
          int rr = wr*128 + i*16 + fr;
          af[i] = *(const bf16x8*)&Ab[rr*64 + ((kk*32 + ks*8) ^ ((rr & 7) << 3))];
        }
#pragma unroll
        for (int j = 0; j < 4; j++) {
          int rr = wc*64 + j*16 + fr;
          bg[j] = *(const bf16x8*)&Bb[rr*64 + ((kk*32 + ks*8) ^ ((rr & 7) << 3))];
        }
        __builtin_amdgcn_s_setprio(1);
#pragma unroll
        for (int i = 0; i < 8; i++)
#pragma unroll
          for (int j = 0; j < 4; j++)
            acc[i][j] = __builtin_amdgcn_mfma_f32_16x16x32_bf16(af[i], bg[j], acc[i][j], 0, 0, 0);
        __builtin_amdgcn_s_setprio(0);
      }
    }
    __builtin_amdgcn_sched_barrier(0);
    asm volatile("s_waitcnt lgkmcnt(0)" ::: "memory");
    __builtin_amdgcn_sched_barrier(0);
    __builtin_amdgcn_s_barrier();
    __builtin_amdgcn_sched_barrier(0);
  }
#undef STAGE256

#pragma unroll
  for (int i = 0; i < 8; i++) {
#pragma unroll
    for (int j = 0; j < 4; j++) {
      int row = row0 + wr*128 + i*16 + ks*4;
      int col = col0 + wc*64 + j*16 + fr;
      u16* Cb = (u16*)C;
      int ldc = P.ldcPP[bi];
#pragma unroll
      for (int rr = 0; rr < 4; rr++)
        Cb[(size_t)(row + rr)*ldc + col] = f2bf(acc[i][j][rr]);
    }
  }
}

// One WAVE per token row; vectorized; writes att IN PLACE over S.
template<int R>
__device__ __forceinline__ void row_fin_body(u16* __restrict__ S_all,
    const u16* __restrict__ x2s, const float* __restrict__ Wm,
    int Tblock, float* __restrict__ part, int t, int ldS) {
  int lane = threadIdx.x & 63;
  u16* S = S_all + (size_t)t*ldS + lane*R;
  u16 sv[R];
  if constexpr (R == 16) {
    *(uint4*)&sv[0] = *(const uint4*)&S[0];
    *(uint4*)&sv[8] = *(const uint4*)&S[8];
  } else if constexpr (R == 8) {
    *(uint4*)&sv[0] = *(const uint4*)&S[0];
  } else if constexpr (R == 4) {
    *(uint2*)&sv[0] = *(const uint2*)&S[0];
  } else {
    *(unsigned*)&sv[0] = *(const unsigned*)&S[0];
  }
  float s[R];
#pragma unroll
  for (int i = 0; i < R; i++) s[i] = bf2f(sv[i]);

  float v0 = -INFINITY, v1 = -INFINITY; int j0 = 0x7fffffff, j1 = 0x7fffffff;
#pragma unroll
  for (int i = 0; i < R; i++) {
    int j = lane*R + i; float sx = s[i];
    if (sx > v0) { v1 = v0; j1 = j0; v0 = sx; j0 = j; }
    else if (sx > v1) { v1 = sx; j1 = j; }
  }
#pragma unroll
  for (int m = 32; m > 0; m >>= 1) {
    float b0 = __shfl_xor(v0, m, 64); int bi0 = __shfl_xor(j0, m, 64);
    float b1 = __shfl_xor(v1, m, 64); int bi1 = __shfl_xor(j1, m, 64);
    if (b0 > v0 || (b0 == v0 && bi0 < j0)) {
      if (v0 > b1 || (v0 == b1 && j0 < bi1)) { v1 = v0; j1 = j0; }
      else { v1 = b1; j1 = bi1; }
      v0 = b0; j0 = bi0;
    } else {
      if (b0 > v1 || (b0 == v1 && bi0 < j1)) { v1 = b0; j1 = bi0; }
    }
  }

  float z = 0.f;
#pragma unroll
  for (int i = 0; i < R; i++) { float p = expf(s[i] - v0); z += p; s[i] = p; }
  z = wave_sum(z);
  float invZ = 1.f / z;

  float l1 = 0.f;
#pragma unroll
  for (int i = 0; i < R; i++) {
    float attv = s[i] * invZ;
    float r = attv - 0.0025f;
    float a = (r > 0.f) ? (r * attv / (r + 1e-12f)) : 0.f;
    l1 += a; s[i] = a;
  }
  l1 = wave_sum(l1);
  float inv = 1.f / fmaxf(l1, 1e-12f);

  u16 ov[R];
  float e = 0.f;
#pragma unroll
  for (int i = 0; i < R; i++) {
    float an = s[i] * inv;
    ov[i] = f2bf(an);
    if (an > 0.f) e += an * logf(an + 1e-12f);
  }
  if constexpr (R == 16) {
    *(uint4*)&S[0] = *(uint4*)&ov[0];
    *(uint4*)&S[8] = *(uint4*)&ov[8];
  } else if constexpr (R == 8) {
    *(uint4*)&S[0] = *(uint4*)&ov[0];
  } else if constexpr (R == 4) {
    *(uint2*)&S[0] = *(uint2*)&ov[0];
  } else {
    *(unsigned*)&S[0] = *(unsigned*)&ov[0];
  }

  float dp2 = 0.f, dn2 = 0.f, cq2 = 0.f;
  const u16* xr = x2s + (size_t)t*256;
  const float* pw = Wm + (size_t)j0*256;
  const float* nw = Wm + (size_t)j1*256;
#pragma unroll
  for (int k2 = 0; k2 < 4; k2++) {
    int c = lane + k2*64;
    float xv = bf2f(xr[c]);
    float p = pw[c], n = nw[c];
    float dp = xv - p + 1e-6f, dn = xv - n + 1e-6f, cq = xv - p;
    dp2 += dp*dp; dn2 += dn*dn; cq2 += cq*cq;
  }
  e = wave_sum(e); dp2 = wave_sum(dp2); dn2 = wave_sum(dn2); cq2 = wave_sum(cq2);
  if (lane == 0) {
    int slot = t & 1023;
    float trip = fmaxf(sqrtf(dp2) - sqrtf(dn2) + 1.f, 0.f);
    atomicAdd(&part[0*1024 + slot], -e / (float)Tblock);
    atomicAdd(&part[1*1024 + slot], trip / (float)Tblock);
    atomicAdd(&part[2*1024 + slot], cq2 / ((float)Tblock * 256.f));
  }
}

// Merged finalize. grid = 21760 (4 waves = 4 tokens/WG).
__global__ __launch_bounds__(256) void row_fin_all_k(RFP P, float* __restrict__ part) {
  int b = blockIdx.x;
  int bi = (b >= 16384) + (b >= 20480) + (b >= 21504);
  int lb = b - (bi == 0 ? 0 : bi == 1 ? 16384 : bi == 2 ? 20480 : 21504);
  int t = lb*4 + (threadIdx.x >> 6);
  switch (bi) {
    case 0: row_fin_body<16>(P.S[0], P.x2[0], P.W[0], P.T[0], part, t, P.ldS[0]); break;
    case 1: row_fin_body<8> (P.S[1], P.x2[1], P.W[1], P.T[1], part, t, P.ldS[1]); break;
    case 2: row_fin_body<4> (P.S[2], P.x2[2], P.W[2], P.T[2], part, t, P.ldS[2]); break;
    default:row_fin_body<2> (P.S[3], P.x2[3], P.W[3], P.T[3], part, t, P.ldS[3]); break;
  }
}

__global__ __launch_bounds__(256) void loss_reduce_k(const float* __restrict__ part,
                                                     float* __restrict__ losses) {
  __shared__ float red[256];
  int l = blockIdx.x;
  int tid = threadIdx.x;
  float v = 0.f;
  for (int i = tid; i < 1024; i += 256) v += part[l*1024 + i];
  float s = block_sum(v, red);
  if (tid == 0) atomicAdd(&losses[l == 2 ? 3 : l], s);
}

// Merged bilinear upsample from bf16 rec, 4 pixels/thread + float4 store. grid = 3*16384.
__global__ __launch_bounds__(256) void upsample_all_k(UP up, float* __restrict__ out) {
  int b = blockIdx.x;
  int ri = b >> 14;
  int blk = 32 >> ri;
  int coff = (ri + 1) * 256;
  const u16* rec = up.rec[ri];
  int idx = (b & 16383)*256 + threadIdx.x;
  int w4 = (idx & 15) * 4;
  int r = (idx >> 4) & 63;
  int c = (idx >> 10) & 255;
  int bb = idx >> 18;
  float s = (float)blk * (1.f/64.f);
  float py = ((float)r + 0.5f)*s - 0.5f;
  float fy0 = floorf(py);
  float fy = py - fy0;
  int y0 = (int)fy0;
  int y0c = min(max(y0, 0), blk-1), y1c = min(max(y0+1, 0), blk-1);
  const u16* rp = rec + (size_t)(bb*256 + c)*blk*blk;
  const u16* r0 = rp + y0c*blk;
  const u16* r1 = rp + y1c*blk;
  float ov[4];
#pragma unroll
  for (int e = 0; e < 4; e++) {
    int w = w4 + e;
    float px = ((float)w + 0.5f)*s - 0.5f;
    float fx0 = floorf(px);
    float fx = px - fx0;
    int x0 = (int)fx0;
    int x0c = min(max(x0, 0), blk-1), x1c = min(max(x0+1, 0), blk-1);
    float v00 = bf2f(r0[x0c]), v01 = bf2f(r0[x1c]);
    float v10 = bf2f(r1[x0c]), v11 = bf2f(r1[x1c]);
    ov[e] = (1.f-fy)*((1.f-fx)*v00 + fx*v01) + fy*((1.f-fx)*v10 + fx*v11);
  }
  *(float4*)&out[((size_t)(bb*1024 + coff + c) << 12) + (r << 6) + w4] = *(float4*)ov;
}

extern "C" void kernel_launch(void* const* d_in, const int* in_sizes, int n_in,
                              void* d_out, int out_size, void* d_ws, size_t ws_size,
                              hipStream_t stream) {
  const float* x = (const float*)d_in[0];
  GP gp;
  gp.w[0] = (const float*)d_in[2]; gp.w[1] = (const float*)d_in[3];
  gp.w[2] = (const float*)d_in[4]; gp.w[3] = (const float*)d_in[5];
  float* out = (float*)d_out;
  float* losses = out + OUTC;

  char* ws = (char*)d_ws;
  size_t off = 0;
  u16* rec32 = (u16*)(ws + off); off += (size_t)16384*256*2;
  u16* rec16 = (u16*)(ws + off); off += (size_t)4096*256*2;
  u16* rec8  = (u16*)(ws + off); off += (size_t)1024*256*2;
  float* part  = (float*)(ws + off); off += 3*1024*4;
  off = (off + 255) & ~(size_t)255;
  u16* Ws1 = (u16*)(ws + off); off += (size_t)2048*256*2;
  u16* Ws2 = (u16*)(ws + off); off += (size_t)256*1920*2;
  gp.g[0] = (float*)(ws + off); off += (size_t)1024*1024*4;
  gp.g[1] = (float*)(ws + off); off += (size_t)512*512*4;
  gp.g[2] = (float*)(ws + off); off += (size_t)256*256*4;
  gp.g[3] = (float*)(ws + off); off += (size_t)128*128*4;
  u16* x2s64 = (u16*)(ws + off); off += (size_t)65536*256*2;
  u16* x2s32 = (u16*)(ws + off); off += (size_t)16384*256*2;
  u16* x2s16 = (u16*)(ws + off); off += (size_t)4096*256*2;
  u16* x2s8  = (u16*)(ws + off); off += (size_t)1024*256*2;
  u16* S64 = (u16*)(ws + off); off += (size_t)65536*1024*2;
  u16* S32 = (u16*)(ws + off); off += (size_t)16384*512*2;
  u16* S16 = (u16*)(ws + off); off += (size_t)4096*256*2;
  u16* S8  = (u16*)(ws + off); off += (size_t)1024*256*2;

  const size_t s1off[4] = {0, (size_t)1024*256, (size_t)1536*256, (size_t)1792*256};
  const size_t s2off[4] = {0, (size_t)256*1024, (size_t)256*1536, (size_t)256*1792};
  const u16* x2Arr[4] = {x2s64, x2s32, x2s16, x2s8};
  u16* SArr[4] = {S64, S32, S16, S8};
  const int MS[4] = {1024, 512, 256, 128};
  const int ldSArr[4] = {1024, 512, 256, 256};

  zero_k<<<13, 256, 0, stream>>>(part, losses);
  wprep_k<<<2048, 256, 0, stream>>>(gp, Ws1, Ws2, losses);
  sgemmbt_all_k<<<340, 256, 0, stream>>>(gp);
  wdist_all_k<<<5440, 256, 0, stream>>>(gp, losses);

  gather_pool_k<<<4096, 256, 0, stream>>>(x, x2s64, x2s32);
  pool_half_k<<<4096, 256, 0, stream>>>(x2s32, x2s16, 16);
  pool_half_k<<<1024, 256, 0, stream>>>(x2s16, x2s8, 8);

  // ALL logits GEMMs on 256-tile kernel: Sb(bf16) = x2_hi * Ws1^T, K=256
  MG2 L2;
  {
    int base = 0;
    for (int bi = 0; bi < 3; bi++) {
      L2.A[bi] = x2Arr[bi]; L2.B[bi] = Ws1 + s1off[bi]; L2.C[bi] = (float*)SArr[bi];
      L2.K[bi] = 256; L2.lda[bi] = 256; L2.ldb[bi] = 256;
      L2.ldcPP[bi] = MS[bi]; L2.CH[bi] = 0;
      L2.gx[bi] = MS[bi]/256;
      L2.base[bi] = base;
      int T = 65536 >> (2*bi);
      base += (MS[bi]/256) * (T/256);
    }
    L2.A[3] = x2s8; L2.B[3] = Ws1 + s1off[3]; L2.C[3] = (float*)S8;
    L2.K[3] = 256; L2.lda[3] = 256; L2.ldb[3] = 256; L2.ldcPP[3] = 256; L2.CH[3] = 0;
    L2.gx[3] = 1; L2.base[3] = base;
    base += 4;
    L2.nwg = base;  // 1172
  }
  mgemm256_k<<<L2.nwg, 512, 0, stream>>>(L2);

  // merged row finalize (in-place att over S)
  RFP R;
  for (int bi = 0; bi < 4; bi++) {
    R.S[bi] = SArr[bi]; R.x2[bi] = x2Arr[bi];
    R.W[bi] = gp.w[bi]; R.T[bi] = 65536 >> (2*bi);
    R.ldS[bi] = ldSArr[bi];
  }
  row_fin_all_k<<<21760, 256, 0, stream>>>(R, part);

  // merged attn GEMMs on 128^2 DOUBLE-BUFFERED kernel: C = att(in S) * Ws2^T
  MGP A;
  float* recArr[4] = {out, (float*)rec32, (float*)rec16, (float*)rec8};
  {
    int base = 0;
    for (int bi = 0; bi < 4; bi++) {
      A.A[bi] = SArr[bi]; A.B[bi] = Ws2 + s2off[bi]; A.C[bi] = recArr[bi];
      A.K[bi] = MS[bi]; A.lda[bi] = ldSArr[bi]; A.ldb[bi] = MS[bi];
      A.ldcPP[bi] = (bi == 0) ? 4096 : (4096 >> (2*bi));
      A.CH[bi] = (bi == 0) ? 1024 : 256;
      A.obf[bi] = (bi == 0) ? 0 : 1;
      A.gx[bi] = 2;
      A.base[bi] = base;
      int T = 65536 >> (2*bi);
      base += 2 * (T/128);
    }
    A.nwg = base;  // 1360
  }
  mgemm128db_k<<<A.nwg, 256, 0, stream>>>(A);

  UP up; up.rec[0] = rec32; up.rec[1] = rec16; up.rec[2] = rec8;
  upsample_all_k<<<3*16384, 256, 0, stream>>>(up, out);

  loss_reduce_k<<<3, 256, 0, stream>>>(part, losses);
}

// Round 18
// 407.367 us; speedup vs baseline: 2.4668x; 1.2025x over previous
//
#include <hip/hip_runtime.h>

#define OUTC (16ull*1024*64*64)

typedef unsigned short u16;
typedef __attribute__((ext_vector_type(8))) __bf16 bf16x8;
typedef __attribute__((ext_vector_type(4))) float f32x4;

struct GP { const float* w[4]; float* g[4]; };
struct UP { const u16* rec[3]; };
struct MGP {
  const u16* A[4]; const u16* B[4]; float* C[4];
  int K[4]; int lda[4]; int ldb[4]; int ldcPP[4]; int CH[4]; int obf[4];
  int base[4]; int gx[4]; int nwg;
};
struct MG2 {
  const u16* A[4]; const u16* B[4]; float* C[4];
  int K[4]; int lda[4]; int ldb[4]; int ldcPP[4]; int CH[4];
  int base[4]; int gx[4]; int nwg;
};
struct RFP { u16* S[4]; const u16* x2[4]; const float* W[4]; int T[4]; int ldS[4]; };

__device__ __forceinline__ u16 f2bf(float f) {
  unsigned u = __float_as_uint(f);
  unsigned r = (u + 0x7fffu + ((u >> 16) & 1u)) >> 16;
  return (u16)r;
}
__device__ __forceinline__ float bf2f(u16 h) {
  return __uint_as_float(((unsigned)h) << 16);
}

// async global->LDS, 16B per lane; LDS dest = wave-uniform base + lane*16.
__device__ __forceinline__ void gload16(const void* gsrc, void* ldst) {
  __builtin_amdgcn_global_load_lds(
      (const __attribute__((address_space(1))) void*)gsrc,
      (__attribute__((address_space(3))) void*)ldst, 16, 0, 0);
}

__device__ __forceinline__ float block_sum(float v, float* red) {
  int tid = threadIdx.x;
  red[tid] = v; __syncthreads();
#pragma unroll
  for (int s = 128; s > 0; s >>= 1) {
    if (tid < s) red[tid] += red[tid + s];
    __syncthreads();
  }
  float r = red[0];
  __syncthreads();
  return r;
}

__device__ __forceinline__ float wave_sum(float v) {
#pragma unroll
  for (int m = 32; m > 0; m >>= 1) v += __shfl_xor(v, m, 64);
  return v;
}

// MERGED: part-zero (12) | wprep (2048: 1920 real + 128 pad) | W*W^T (340).
// grid = 2400. wnorm terms -> wnp[1920] (every slot written, no zero needed).
__global__ __launch_bounds__(256) void prep_k(GP gp,
    u16* __restrict__ Ws1, u16* __restrict__ Ws2,
    float* __restrict__ part, float* __restrict__ wnp) {
  __shared__ float As[32][64];
  __shared__ float Bs[32][64];
  __shared__ float red[256];
  int b = blockIdx.x;
  int tid = threadIdx.x;
  if (b < 12) { part[b*256 + tid] = 0.f; return; }
  if (b < 2060) {
    int wb = b - 12;
    if (wb >= 1920) {  // zero bi3 pad rows 128..255 of Ws1
      Ws1[(size_t)1792*256 + (size_t)(128 + (wb - 1920))*256 + tid] = 0;
      return;
    }
    int bi, m, M; size_t s1off, s2off;
    if (wb < 1024)      { bi=0; m=wb;      M=1024; s1off=0; s2off=0; }
    else if (wb < 1536) { bi=1; m=wb-1024; M=512;  s1off=(size_t)1024*256; s2off=(size_t)256*1024; }
    else if (wb < 1792) { bi=2; m=wb-1536; M=256;  s1off=(size_t)1536*256; s2off=(size_t)256*1536; }
    else                { bi=3; m=wb-1792; M=128;  s1off=(size_t)1792*256; s2off=(size_t)256*1792; }
    float w = gp.w[bi][(size_t)m*256 + tid];
    u16 h = f2bf(w);
    Ws1[s1off + (size_t)m*256 + tid] = h;
    Ws2[s2off + (size_t)tid*M + m] = h;
    float s = block_sum(w*w, red);
    if (tid == 0) wnp[wb] = fabsf(1.f - sqrtf(s)) / (float)M;
    return;
  }
  // exact-f32 W*W^T
  int sb = b - 2060;
  int bi, lt, M, lg;
  if (sb < 256)      { bi=0; lt=sb;     M=1024; lg=4; }
  else if (sb < 320) { bi=1; lt=sb-256; M=512;  lg=3; }
  else if (sb < 336) { bi=2; lt=sb-320; M=256;  lg=2; }
  else               { bi=3; lt=sb-336; M=128;  lg=1; }
  const float* A = gp.w[bi];
  float* C = gp.g[bi];
  int gx = 1 << lg;
  int bx = lt & (gx-1), by = lt >> lg;
  int tx = tid & 15, ty = tid >> 4;
  int row0 = by << 6, col0 = bx << 6;
  float acc[4][4] = {};
  for (int k0 = 0; k0 < 256; k0 += 32) {
#pragma unroll
    for (int l = 0; l < 2; l++) {
      int i = tid + l*256;
      int kq = i & 7, m = i >> 3;
      float4 v = *(const float4*)(A + (size_t)(row0 + m)*256 + k0 + kq*4);
      As[kq*4+0][m] = v.x; As[kq*4+1][m] = v.y; As[kq*4+2][m] = v.z; As[kq*4+3][m] = v.w;
      float4 w = *(const float4*)(A + (size_t)(col0 + m)*256 + k0 + kq*4);
      Bs[kq*4+0][m] = w.x; Bs[kq*4+1][m] = w.y; Bs[kq*4+2][m] = w.z; Bs[kq*4+3][m] = w.w;
    }
    __syncthreads();
#pragma unroll
    for (int kk = 0; kk < 32; kk++) {
      float4 a = *(const float4*)&As[kk][ty*4];
      float4 bvv = *(const float4*)&Bs[kk][tx*4];
      float av[4] = {a.x, a.y, a.z, a.w};
      float bv[4] = {bvv.x, bvv.y, bvv.z, bvv.w};
#pragma unroll
      for (int i = 0; i < 4; i++)
#pragma unroll
        for (int j = 0; j < 4; j++)
          acc[i][j] = fmaf(av[i], bv[j], acc[i][j]);
    }
    __syncthreads();
  }
#pragma unroll
  for (int i = 0; i < 4; i++)
#pragma unroll
    for (int j = 0; j < 4; j++)
      C[(size_t)(row0 + ty*4 + i)*M + col0 + tx*4 + j] = acc[i][j];
}

// MERGED: wdist (5440 -> wdp per-block partials) | gather_pool (4096).
// grid = 9536.
__global__ __launch_bounds__(256) void wdist_gather_k(GP gp,
    float* __restrict__ wdp, const float* __restrict__ x,
    u16* __restrict__ x2s64, u16* __restrict__ x2s32) {
  __shared__ float lds[32][130];
  __shared__ float red[256];
  int b = blockIdx.x;
  int tid = threadIdx.x;
  if (b < 5440) {
    int bi, lb, M;
    if (b < 4096)      { bi=0; lb=b;      M=1024; }
    else if (b < 5120) { bi=1; lb=b-4096; M=512; }
    else if (b < 5376) { bi=2; lb=b-5120; M=256; }
    else               { bi=3; lb=b-5376; M=128; }
    const float* G = gp.g[bi];
    int idx = lb*256 + tid;
    float acc = 0.f;
    int i = idx / M, j = idx - i*M;
    if (j > i) {
      float d2 = G[(size_t)i*M + i] + G[(size_t)j*M + j] - 2.f*G[(size_t)i*M + j];
      float dist = 1.f - d2;
      if (dist > 0.f) acc = dist;
    }
    float s = block_sum(acc, red);
    if (tid == 0) wdp[b] = s * 2.f / ((float)M * (float)(M - 1));
    return;
  }
  int gb = b - 5440;
  int orow = gb & 31, ct = (gb >> 5) & 7, bb = gb >> 8;
  const float* xb = x + ((size_t)(bb*256 + ct*32))*4096 + orow*128;
#pragma unroll
  for (int p = 0; p < 4; p++) {
    int s = p*256 + tid;
    int c = s >> 5, f = s & 31;
    float4 v = *(const float4*)(xb + (size_t)c*4096 + f*4);
    lds[c][f*4+0] = v.x; lds[c][f*4+1] = v.y;
    lds[c][f*4+2] = v.z; lds[c][f*4+3] = v.w;
  }
  __syncthreads();
  {
    int cg = (tid & 3) * 8;
#pragma unroll
    for (int it = 0; it < 2; it++) {
      int tl = it*64 + (tid >> 2);
      size_t row = ((size_t)bb*4096 + (size_t)orow*128 + tl)*256 + ct*32 + cg;
      u16 hi[8];
#pragma unroll
      for (int e = 0; e < 8; e++) hi[e] = f2bf(lds[cg + e][tl]);
      *(uint4*)&x2s64[row] = *(uint4*)hi;
    }
  }
  {
    int c = tid & 31;
#pragma unroll
    for (int p = 0; p < 4; p++) {
      int w = p*8 + (tid >> 5);
      float m = fmaxf(fmaxf(lds[c][2*w], lds[c][2*w+1]),
                      fmaxf(lds[c][64+2*w], lds[c][64+2*w+1]));
      x2s32[((size_t)bb*1024 + (size_t)orow*32 + w)*256 + ct*32 + c] = f2bf(m);
    }
  }
}

__global__ __launch_bounds__(256) void pool_half_k(const u16* __restrict__ src,
    u16* __restrict__ dst, int blk) {
  int t = blockIdx.x, c = threadIdx.x;
  int bb = t / (blk*blk), rw = t - bb*blk*blk;
  int r = rw / blk, w = rw - r*blk;
  int bp = blk*2;
  int pb = bb*bp*bp;
  float m = -INFINITY;
#pragma unroll
  for (int dy = 0; dy < 2; dy++)
#pragma unroll
    for (int dx = 0; dx < 2; dx++)
      m = fmaxf(m, bf2f(src[(size_t)(pb + (2*r+dy)*bp + 2*w+dx)*256 + c]));
  dst[(size_t)t*256 + c] = f2bf(m);
}

// 128x128-tile, DOUBLE-BUFFERED counted-vmcnt MFMA GEMM.
// Scatter epilogue: f32 (obf=0) or bf16 (obf=1).
__global__ __launch_bounds__(256) void mgemm128db_k(MGP P) {
  __shared__ __align__(16) u16 As[2][128*64];
  __shared__ __align__(16) u16 Bs[2][128*64];
  int wg = blockIdx.x;
  int nwg = P.nwg;
  int q = nwg >> 3, r = nwg & 7;
  int xcd = wg & 7, cidx = wg >> 3;
  int swz = (xcd < r ? xcd*(q+1) : r*(q+1) + (xcd - r)*q) + cidx;
  int bi = (swz >= P.base[1]) + (swz >= P.base[2]) + (swz >= P.base[3]);
  int lt = swz - P.base[bi];
  int gx = P.gx[bi];
  int bx = lt % gx, by = lt / gx;
  const u16* A = P.A[bi];
  const u16* B = P.B[bi];
  float* C = P.C[bi];
  int K = P.K[bi], lda = P.lda[bi], ldb = P.ldb[bi];

  int tid = threadIdx.x;
  int lane = tid & 63;
  int wid = tid >> 6;
  int wr = wid >> 1, wc = wid & 1;
  int fr = lane & 15, ks = lane >> 4;
  int row0 = by << 7, col0 = bx << 7;
  f32x4 acc[4][4] = {};
  int srow = tid >> 3;
  int scol = ((tid & 7) ^ (srow & 7)) * 8;
  const u16* Ap = A + (size_t)(row0 + srow)*lda + scol;
  const u16* Bp = B + (size_t)(col0 + srow)*ldb + scol;
  char* AL = (char*)&As[0][0] + (size_t)wid*1024;
  char* BL = (char*)&Bs[0][0] + (size_t)wid*1024;
  int nt = K >> 6;

#define STAGE128(b, kt) { \
    int k0 = (kt) << 6; \
    _Pragma("unroll") \
    for (int it = 0; it < 4; it++) { \
      gload16(Ap + (size_t)(it*32)*lda + k0, AL + (b)*16384 + it*4096); \
      gload16(Bp + (size_t)(it*32)*ldb + k0, BL + (b)*16384 + it*4096); \
    } \
  }

  STAGE128(0, 0);
  for (int t = 0; t < nt; t++) {
    int b = t & 1;
    if (t + 1 < nt) {
      STAGE128(b ^ 1, t + 1);
      __builtin_amdgcn_sched_barrier(0);
      asm volatile("s_waitcnt vmcnt(8)" ::: "memory");
    } else {
      __builtin_amdgcn_sched_barrier(0);
      asm volatile("s_waitcnt vmcnt(0)" ::: "memory");
    }
    __builtin_amdgcn_sched_barrier(0);
    __builtin_amdgcn_s_barrier();
    __builtin_amdgcn_sched_barrier(0);
    {
      const u16* Ab = &As[b][0];
      const u16* Bb = &Bs[b][0];
#pragma unroll
      for (int kk = 0; kk < 2; kk++) {
        bf16x8 af[4], bg[4];
#pragma unroll
        for (int i = 0; i < 4; i++) {
          int rr = wr*64 + i*16 + fr;
          af[i] = *(const bf16x8*)&Ab[rr*64 + ((kk*32 + ks*8) ^ ((rr & 7) << 3))];
        }
#pragma unroll
        for (int j = 0; j < 4; j++) {
          int rr = wc*64 + j*16 + fr;
          bg[j] = *(const bf16x8*)&Bb[rr*64 + ((kk*32 + ks*8) ^ ((rr & 7) << 3))];
        }
        __builtin_amdgcn_s_setprio(1);
#pragma unroll
        for (int i = 0; i < 4; i++)
#pragma unroll
          for (int j = 0; j < 4; j++)
            acc[i][j] = __builtin_amdgcn_mfma_f32_16x16x32_bf16(af[i], bg[j], acc[i][j], 0, 0, 0);
        __builtin_amdgcn_s_setprio(0);
      }
    }
    __builtin_amdgcn_sched_barrier(0);
    asm volatile("s_waitcnt lgkmcnt(0)" ::: "memory");
    __builtin_amdgcn_sched_barrier(0);
    __builtin_amdgcn_s_barrier();
    __builtin_amdgcn_sched_barrier(0);
  }
#undef STAGE128

  int PP = P.ldcPP[bi];
  int obf = P.obf[bi];
#pragma unroll
  for (int i = 0; i < 4; i++) {
#pragma unroll
    for (int j = 0; j < 4; j++) {
      int row = row0 + wr*64 + i*16 + ks*4;
      int col = col0 + wc*64 + j*16 + fr;
      int bb = row / PP, rw = row - bb*PP;
      size_t o = ((size_t)(bb*P.CH[bi] + col))*PP + rw;
      if (obf) {
        u16 ov[4];
#pragma unroll
        for (int rr2 = 0; rr2 < 4; rr2++) ov[rr2] = f2bf(acc[i][j][rr2]);
        *(uint2*)&((u16*)C)[o] = *(uint2*)ov;
      } else {
        *(f32x4*)&C[o] = acc[i][j];
      }
    }
  }
}

// 256x256-tile, double-buffered, counted-vmcnt MFMA GEMM. bf16 out.
__global__ __launch_bounds__(512, 2) void mgemm256_k(MG2 P) {
  __shared__ __align__(16) u16 As[2][256*64];
  __shared__ __align__(16) u16 Bs[2][256*64];
  int wg = blockIdx.x;
  int nwg = P.nwg;
  int q = nwg >> 3, r = nwg & 7;
  int xcd = wg & 7, cidx = wg >> 3;
  int swz = (xcd < r ? xcd*(q+1) : r*(q+1) + (xcd - r)*q) + cidx;
  int bi = (swz >= P.base[1]) + (swz >= P.base[2]) + (swz >= P.base[3]);
  int lt = swz - P.base[bi];
  int gx = P.gx[bi];
  int bx = lt % gx, by = lt / gx;
  const u16* A = P.A[bi];
  const u16* Bm = P.B[bi];
  float* C = P.C[bi];
  int K = P.K[bi], lda = P.lda[bi], ldb = P.ldb[bi];
  int row0 = by << 8, col0 = bx << 8;

  int tid = threadIdx.x;
  int lane = tid & 63, wid = tid >> 6;
  int wr = wid >> 2, wc = wid & 3;
  int fr = lane & 15, ks = lane >> 4;

  int arow = tid >> 3;
  int presw = ((tid & 7) ^ (arow & 7)) * 8;
  const u16* Ap = A + (size_t)(row0 + arow)*lda + presw;
  const u16* Bp = Bm + (size_t)(col0 + arow)*ldb + presw;
  char* AL = (char*)&As[0][0] + (size_t)wid*1024;
  char* BL = (char*)&Bs[0][0] + (size_t)wid*1024;

  f32x4 acc[8][4] = {};
  int nt = K >> 6;

#define STAGE256(b, kt) { \
    int k0 = (kt) << 6; \
    _Pragma("unroll") \
    for (int ia = 0; ia < 4; ia++) \
      gload16(Ap + (size_t)(ia*64)*lda + k0, AL + (b)*32768 + ia*8192); \
    _Pragma("unroll") \
    for (int ib = 0; ib < 4; ib++) \
      gload16(Bp + (size_t)(ib*64)*ldb + k0, BL + (b)*32768 + ib*8192); \
  }

  STAGE256(0, 0);
  for (int t = 0; t < nt; t++) {
    int b = t & 1;
    if (t + 1 < nt) {
      STAGE256(b ^ 1, t + 1);
      __builtin_amdgcn_sched_barrier(0);
      asm volatile("s_waitcnt vmcnt(8)" ::: "memory");
    } else {
      __builtin_amdgcn_sched_barrier(0);
      asm volatile("s_waitcnt vmcnt(0)" ::: "memory");
    }
    __builtin_amdgcn_sched_barrier(0);
    __builtin_amdgcn_s_barrier();
    __builtin_amdgcn_sched_barrier(0);
    {
      const u16* Ab = &As[b][0];
      const u16* Bb = &Bs[b][0];
#pragma unroll
      for (int kk = 0; kk < 2; kk++) {
        bf16x8 af[8], bg[4];
#pragma unroll
        for (int i = 0; i < 8; i++) {
          int rr = wr*128 + i*16 + fr;
          af[i] = *(const bf16x8*)&Ab[rr*64 + ((kk*32 + ks*8) ^ ((rr & 7) << 3))];
        }
#pragma unroll
        for (int j = 0; j < 4; j++) {
          int rr = wc*64 + j*16 + fr;
          bg[j] = *(const bf16x8*)&Bb[rr*64 + ((kk*32 + ks*8) ^ ((rr & 7) << 3))];
        }
        __builtin_amdgcn_s_setprio(1);
#pragma unroll
        for (int i = 0; i < 8; i++)
#pragma unroll
          for (int j = 0; j < 4; j++)
            acc[i][j] = __builtin_amdgcn_mfma_f32_16x16x32_bf16(af[i], bg[j], acc[i][j], 0, 0, 0);
        __builtin_amdgcn_s_setprio(0);
      }
    }
    __builtin_amdgcn_sched_barrier(0);
    asm volatile("s_waitcnt lgkmcnt(0)" ::: "memory");
    __builtin_amdgcn_sched_barrier(0);
    __builtin_amdgcn_s_barrier();
    __builtin_amdgcn_sched_barrier(0);
  }
#undef STAGE256

#pragma unroll
  for (int i = 0; i < 8; i++) {
#pragma unroll
    for (int j = 0; j < 4; j++) {
      int row = row0 + wr*128 + i*16 + ks*4;
      int col = col0 + wc*64 + j*16 + fr;
      u16* Cb = (u16*)C;
      int ldc = P.ldcPP[bi];
#pragma unroll
      for (int rr = 0; rr < 4; rr++)
        Cb[(size_t)(row + rr)*ldc + col] = f2bf(acc[i][j][rr]);
    }
  }
}

// One WAVE per token row; vectorized; writes att IN PLACE over S.
template<int R>
__device__ __forceinline__ void row_fin_body(u16* __restrict__ S_all,
    const u16* __restrict__ x2s, const float* __restrict__ Wm,
    int Tblock, float* __restrict__ part, int t, int ldS) {
  int lane = threadIdx.x & 63;
  u16* S = S_all + (size_t)t*ldS + lane*R;
  u16 sv[R];
  if constexpr (R == 16) {
    *(uint4*)&sv[0] = *(const uint4*)&S[0];
    *(uint4*)&sv[8] = *(const uint4*)&S[8];
  } else if constexpr (R == 8) {
    *(uint4*)&sv[0] = *(const uint4*)&S[0];
  } else if constexpr (R == 4) {
    *(uint2*)&sv[0] = *(const uint2*)&S[0];
  } else {
    *(unsigned*)&sv[0] = *(const unsigned*)&S[0];
  }
  float s[R];
#pragma unroll
  for (int i = 0; i < R; i++) s[i] = bf2f(sv[i]);

  float v0 = -INFINITY, v1 = -INFINITY; int j0 = 0x7fffffff, j1 = 0x7fffffff;
#pragma unroll
  for (int i = 0; i < R; i++) {
    int j = lane*R + i; float sx = s[i];
    if (sx > v0) { v1 = v0; j1 = j0; v0 = sx; j0 = j; }
    else if (sx > v1) { v1 = sx; j1 = j; }
  }
#pragma unroll
  for (int m = 32; m > 0; m >>= 1) {
    float b0 = __shfl_xor(v0, m, 64); int bi0 = __shfl_xor(j0, m, 64);
    float b1 = __shfl_xor(v1, m, 64); int bi1 = __shfl_xor(j1, m, 64);
    if (b0 > v0 || (b0 == v0 && bi0 < j0)) {
      if (v0 > b1 || (v0 == b1 && j0 < bi1)) { v1 = v0; j1 = j0; }
      else { v1 = b1; j1 = bi1; }
      v0 = b0; j0 = bi0;
    } else {
      if (b0 > v1 || (b0 == v1 && bi0 < j1)) { v1 = b0; j1 = bi0; }
    }
  }

  float z = 0.f;
#pragma unroll
  for (int i = 0; i < R; i++) { float p = expf(s[i] - v0); z += p; s[i] = p; }
  z = wave_sum(z);
  float invZ = 1.f / z;

  float l1 = 0.f;
#pragma unroll
  for (int i = 0; i < R; i++) {
    float attv = s[i] * invZ;
    float r = attv - 0.0025f;
    float a = (r > 0.f) ? (r * attv / (r + 1e-12f)) : 0.f;
    l1 += a; s[i] = a;
  }
  l1 = wave_sum(l1);
  float inv = 1.f / fmaxf(l1, 1e-12f);

  u16 ov[R];
  float e = 0.f;
#pragma unroll
  for (int i = 0; i < R; i++) {
    float an = s[i] * inv;
    ov[i] = f2bf(an);
    if (an > 0.f) e += an * logf(an + 1e-12f);
  }
  if constexpr (R == 16) {
    *(uint4*)&S[0] = *(uint4*)&ov[0];
    *(uint4*)&S[8] = *(uint4*)&ov[8];
  } else if constexpr (R == 8) {
    *(uint4*)&S[0] = *(uint4*)&ov[0];
  } else if constexpr (R == 4) {
    *(uint2*)&S[0] = *(uint2*)&ov[0];
  } else {
    *(unsigned*)&S[0] = *(unsigned*)&ov[0];
  }

  float dp2 = 0.f, dn2 = 0.f, cq2 = 0.f;
  const u16* xr = x2s + (size_t)t*256;
  const float* pw = Wm + (size_t)j0*256;
  const float* nw = Wm + (size_t)j1*256;
#pragma unroll
  for (int k2 = 0; k2 < 4; k2++) {
    int c = lane + k2*64;
    float xv = bf2f(xr[c]);
    float p = pw[c], n = nw[c];
    float dp = xv - p + 1e-6f, dn = xv - n + 1e-6f, cq = xv - p;
    dp2 += dp*dp; dn2 += dn*dn; cq2 += cq*cq;
  }
  e = wave_sum(e); dp2 = wave_sum(dp2); dn2 = wave_sum(dn2); cq2 = wave_sum(cq2);
  if (lane == 0) {
    int slot = t & 1023;
    float trip = fmaxf(sqrtf(dp2) - sqrtf(dn2) + 1.f, 0.f);
    atomicAdd(&part[0*1024 + slot], -e / (float)Tblock);
    atomicAdd(&part[1*1024 + slot], trip / (float)Tblock);
    atomicAdd(&part[2*1024 + slot], cq2 / ((float)Tblock * 256.f));
  }
}

// Merged finalize. grid = 21760 (4 waves = 4 tokens/WG).
__global__ __launch_bounds__(256) void row_fin_all_k(RFP P, float* __restrict__ part) {
  int b = blockIdx.x;
  int bi = (b >= 16384) + (b >= 20480) + (b >= 21504);
  int lb = b - (bi == 0 ? 0 : bi == 1 ? 16384 : bi == 2 ? 20480 : 21504);
  int t = lb*4 + (threadIdx.x >> 6);
  switch (bi) {
    case 0: row_fin_body<16>(P.S[0], P.x2[0], P.W[0], P.T[0], part, t, P.ldS[0]); break;
    case 1: row_fin_body<8> (P.S[1], P.x2[1], P.W[1], P.T[1], part, t, P.ldS[1]); break;
    case 2: row_fin_body<4> (P.S[2], P.x2[2], P.W[2], P.T[2], part, t, P.ldS[2]); break;
    default:row_fin_body<2> (P.S[3], P.x2[3], P.W[3], P.T[3], part, t, P.ldS[3]); break;
  }
}

// MERGED: bilinear upsample (3*16384) | loss finalize (5 blocks). grid = 49157.
// losses written directly (no atomics; no pre-zero needed).
__global__ __launch_bounds__(256) void upsample_loss_k(UP up, float* __restrict__ out,
    const float* __restrict__ part, const float* __restrict__ wnp,
    const float* __restrict__ wdp, float* __restrict__ losses) {
  __shared__ float red[256];
  int b = blockIdx.x;
  int tid = threadIdx.x;
  if (b >= 49152) {
    int l = b - 49152;           // 0,1,2: part rows -> losses[0],[1],[3]; 3: wnorm; 4: wdist
    float v = 0.f;
    if (l < 3) {
      for (int i = tid; i < 1024; i += 256) v += part[l*1024 + i];
    } else if (l == 3) {
      for (int i = tid; i < 1920; i += 256) v += wnp[i];
    } else {
      for (int i = tid; i < 5440; i += 256) v += wdp[i];
    }
    float s = block_sum(v, red);
    if (tid == 0) {
      int dst = (l == 0) ? 0 : (l == 1) ? 1 : (l == 2) ? 3 : (l == 3) ? 2 : 4;
      losses[dst] = s;
    }
    return;
  }
  int ri = b >> 14;
  int blk = 32 >> ri;
  int coff = (ri + 1) * 256;
  const u16* rec = up.rec[ri];
  int idx = (b & 16383)*256 + tid;
  int w4 = (idx & 15) * 4;
  int r = (idx >> 4) & 63;
  int c = (idx >> 10) & 255;
  int bb = idx >> 18;
  float s = (float)blk * (1.f/64.f);
  float py = ((float)r + 0.5f)*s - 0.5f;
  float fy0 = floorf(py);
  float fy = py - fy0;
  int y0 = (int)fy0;
  int y0c = min(max(y0, 0), blk-1), y1c = min(max(y0+1, 0), blk-1);
  const u16* rp = rec + (size_t)(bb*256 + c)*blk*blk;
  const u16* r0 = rp + y0c*blk;
  const u16* r1 = rp + y1c*blk;
  float ov[4];
#pragma unroll
  for (int e = 0; e < 4; e++) {
    int w = w4 + e;
    float px = ((float)w + 0.5f)*s - 0.5f;
    float fx0 = floorf(px);
    float fx = px - fx0;
    int x0 = (int)fx0;
    int x0c = min(max(x0, 0), blk-1), x1c = min(max(x0+1, 0), blk-1);
    float v00 = bf2f(r0[x0c]), v01 = bf2f(r0[x1c]);
    float v10 = bf2f(r1[x0c]), v11 = bf2f(r1[x1c]);
    ov[e] = (1.f-fy)*((1.f-fx)*v00 + fx*v01) + fy*((1.f-fx)*v10 + fx*v11);
  }
  *(float4*)&out[((size_t)(bb*1024 + coff + c) << 12) + (r << 6) + w4] = *(float4*)ov;
}

extern "C" void kernel_launch(void* const* d_in, const int* in_sizes, int n_in,
                              void* d_out, int out_size, void* d_ws, size_t ws_size,
                              hipStream_t stream) {
  const float* x = (const float*)d_in[0];
  GP gp;
  gp.w[0] = (const float*)d_in[2]; gp.w[1] = (const float*)d_in[3];
  gp.w[2] = (const float*)d_in[4]; gp.w[3] = (const float*)d_in[5];
  float* out = (float*)d_out;
  float* losses = out + OUTC;

  char* ws = (char*)d_ws;
  size_t off = 0;
  u16* rec32 = (u16*)(ws + off); off += (size_t)16384*256*2;
  u16* rec16 = (u16*)(ws + off); off += (size_t)4096*256*2;
  u16* rec8  = (u16*)(ws + off); off += (size_t)1024*256*2;
  float* part  = (float*)(ws + off); off += 3*1024*4;
  float* wnp   = (float*)(ws + off); off += 1920*4;
  float* wdp   = (float*)(ws + off); off += 5440*4;
  off = (off + 255) & ~(size_t)255;
  u16* Ws1 = (u16*)(ws + off); off += (size_t)2048*256*2;
  u16* Ws2 = (u16*)(ws + off); off += (size_t)256*1920*2;
  gp.g[0] = (float*)(ws + off); off += (size_t)1024*1024*4;
  gp.g[1] = (float*)(ws + off); off += (size_t)512*512*4;
  gp.g[2] = (float*)(ws + off); off += (size_t)256*256*4;
  gp.g[3] = (float*)(ws + off); off += (size_t)128*128*4;
  u16* x2s64 = (u16*)(ws + off); off += (size_t)65536*256*2;
  u16* x2s32 = (u16*)(ws + off); off += (size_t)16384*256*2;
  u16* x2s16 = (u16*)(ws + off); off += (size_t)4096*256*2;
  u16* x2s8  = (u16*)(ws + off); off += (size_t)1024*256*2;
  u16* S64 = (u16*)(ws + off); off += (size_t)65536*1024*2;
  u16* S32 = (u16*)(ws + off); off += (size_t)16384*512*2;
  u16* S16 = (u16*)(ws + off); off += (size_t)4096*256*2;
  u16* S8  = (u16*)(ws + off); off += (size_t)1024*256*2;

  const size_t s1off[4] = {0, (size_t)1024*256, (size_t)1536*256, (size_t)1792*256};
  const size_t s2off[4] = {0, (size_t)256*1024, (size_t)256*1536, (size_t)256*1792};
  const u16* x2Arr[4] = {x2s64, x2s32, x2s16, x2s8};
  u16* SArr[4] = {S64, S32, S16, S8};
  const int MS[4] = {1024, 512, 256, 128};
  const int ldSArr[4] = {1024, 512, 256, 256};

  prep_k<<<2400, 256, 0, stream>>>(gp, Ws1, Ws2, part, wnp);
  wdist_gather_k<<<9536, 256, 0, stream>>>(gp, wdp, x, x2s64, x2s32);
  pool_half_k<<<4096, 256, 0, stream>>>(x2s32, x2s16, 16);
  pool_half_k<<<1024, 256, 0, stream>>>(x2s16, x2s8, 8);

  // ALL logits GEMMs on 256-tile kernel: Sb(bf16) = x2_hi * Ws1^T, K=256
  MG2 L2;
  {
    int base = 0;
    for (int bi = 0; bi < 3; bi++) {
      L2.A[bi] = x2Arr[bi]; L2.B[bi] = Ws1 + s1off[bi]; L2.C[bi] = (float*)SArr[bi];
      L2.K[bi] = 256; L2.lda[bi] = 256; L2.ldb[bi] = 256;
      L2.ldcPP[bi] = MS[bi]; L2.CH[bi] = 0;
      L2.gx[bi] = MS[bi]/256;
      L2.base[bi] = base;
      int T = 65536 >> (2*bi);
      base += (MS[bi]/256) * (T/256);
    }
    L2.A[3] = x2s8; L2.B[3] = Ws1 + s1off[3]; L2.C[3] = (float*)S8;
    L2.K[3] = 256; L2.lda[3] = 256; L2.ldb[3] = 256; L2.ldcPP[3] = 256; L2.CH[3] = 0;
    L2.gx[3] = 1; L2.base[3] = base;
    base += 4;
    L2.nwg = base;  // 1172
  }
  mgemm256_k<<<L2.nwg, 512, 0, stream>>>(L2);

  // merged row finalize (in-place att over S)
  RFP R;
  for (int bi = 0; bi < 4; bi++) {
    R.S[bi] = SArr[bi]; R.x2[bi] = x2Arr[bi];
    R.W[bi] = gp.w[bi]; R.T[bi] = 65536 >> (2*bi);
    R.ldS[bi] = ldSArr[bi];
  }
  row_fin_all_k<<<21760, 256, 0, stream>>>(R, part);

  // merged attn GEMMs on 128^2 double-buffered kernel: C = att(in S) * Ws2^T
  MGP A;
  float* recArr[4] = {out, (float*)rec32, (float*)rec16, (float*)rec8};
  {
    int base = 0;
    for (int bi = 0; bi < 4; bi++) {
      A.A[bi] = SArr[bi]; A.B[bi] = Ws2 + s2off[bi]; A.C[bi] = recArr[bi];
      A.K[bi] = MS[bi]; A.lda[bi] = ldSArr[bi]; A.ldb[bi] = MS[bi];
      A.ldcPP[bi] = (bi == 0) ? 4096 : (4096 >> (2*bi));
      A.CH[bi] = (bi == 0) ? 1024 : 256;
      A.obf[bi] = (bi == 0) ? 0 : 1;
      A.gx[bi] = 2;
      A.base[bi] = base;
      int T = 65536 >> (2*bi);
      base += 2 * (T/128);
    }
    A.nwg = base;  // 1360
  }
  mgemm128db_k<<<A.nwg, 256, 0, stream>>>(A);

  UP up; up.rec[0] = rec32; up.rec[1] = rec16; up.rec[2] = rec8;
  upsample_loss_k<<<3*16384 + 5, 256, 0, stream>>>(up, out, part, wnp, wdp, losses);
}

// Round 19
// 404.799 us; speedup vs baseline: 2.4825x; 1.0063x over previous
//
#include <hip/hip_runtime.h>

#define OUTC (16ull*1024*64*64)

typedef unsigned short u16;
typedef __attribute__((ext_vector_type(8))) __bf16 bf16x8;
typedef __attribute__((ext_vector_type(4))) float f32x4;

struct GP { const float* w[4]; float* g[4]; };
struct UP { const u16* rec[3]; };
struct MGP {
  const u16* A[4]; const u16* B[4]; float* C[4];
  int K[4]; int lda[4]; int ldb[4]; int ldcPP[4]; int CH[4]; int obf[4];
  int base[4]; int gx[4]; int nwg;
};
struct MG2 {
  const u16* A[4]; const u16* B[4]; float* C[4];
  int K[4]; int lda[4]; int ldb[4]; int ldcPP[4]; int CH[4];
  int base[4]; int gx[4]; int nwg;
};
struct RFP { u16* S[4]; const u16* x2[4]; const float* W[4]; int T[4]; int ldS[4]; };

__device__ __forceinline__ u16 f2bf(float f) {
  unsigned u = __float_as_uint(f);
  unsigned r = (u + 0x7fffu + ((u >> 16) & 1u)) >> 16;
  return (u16)r;
}
__device__ __forceinline__ float bf2f(u16 h) {
  return __uint_as_float(((unsigned)h) << 16);
}

// async global->LDS, 16B per lane; LDS dest = wave-uniform base + lane*16.
__device__ __forceinline__ void gload16(const void* gsrc, void* ldst) {
  __builtin_amdgcn_global_load_lds(
      (const __attribute__((address_space(1))) void*)gsrc,
      (__attribute__((address_space(3))) void*)ldst, 16, 0, 0);
}

__device__ __forceinline__ float block_sum(float v, float* red) {
  int tid = threadIdx.x;
  red[tid] = v; __syncthreads();
#pragma unroll
  for (int s = 128; s > 0; s >>= 1) {
    if (tid < s) red[tid] += red[tid + s];
    __syncthreads();
  }
  float r = red[0];
  __syncthreads();
  return r;
}

__device__ __forceinline__ float wave_sum(float v) {
#pragma unroll
  for (int m = 32; m > 0; m >>= 1) v += __shfl_xor(v, m, 64);
  return v;
}

// MERGED: part-zero (12) | wprep (2048: 1920 real + 128 pad) | W*W^T (340).
// grid = 2400. wnorm terms -> wnp[1920].
__global__ __launch_bounds__(256) void prep_k(GP gp,
    u16* __restrict__ Ws1, u16* __restrict__ Ws2,
    float* __restrict__ part, float* __restrict__ wnp) {
  __shared__ float As[32][64];
  __shared__ float Bs[32][64];
  __shared__ float red[256];
  int b = blockIdx.x;
  int tid = threadIdx.x;
  if (b < 12) { part[b*256 + tid] = 0.f; return; }
  if (b < 2060) {
    int wb = b - 12;
    if (wb >= 1920) {
      Ws1[(size_t)1792*256 + (size_t)(128 + (wb - 1920))*256 + tid] = 0;
      return;
    }
    int bi, m, M; size_t s1off, s2off;
    if (wb < 1024)      { bi=0; m=wb;      M=1024; s1off=0; s2off=0; }
    else if (wb < 1536) { bi=1; m=wb-1024; M=512;  s1off=(size_t)1024*256; s2off=(size_t)256*1024; }
    else if (wb < 1792) { bi=2; m=wb-1536; M=256;  s1off=(size_t)1536*256; s2off=(size_t)256*1536; }
    else                { bi=3; m=wb-1792; M=128;  s1off=(size_t)1792*256; s2off=(size_t)256*1792; }
    float w = gp.w[bi][(size_t)m*256 + tid];
    u16 h = f2bf(w);
    Ws1[s1off + (size_t)m*256 + tid] = h;
    Ws2[s2off + (size_t)tid*M + m] = h;
    float s = block_sum(w*w, red);
    if (tid == 0) wnp[wb] = fabsf(1.f - sqrtf(s)) / (float)M;
    return;
  }
  int sb = b - 2060;
  int bi, lt, M, lg;
  if (sb < 256)      { bi=0; lt=sb;     M=1024; lg=4; }
  else if (sb < 320) { bi=1; lt=sb-256; M=512;  lg=3; }
  else if (sb < 336) { bi=2; lt=sb-320; M=256;  lg=2; }
  else               { bi=3; lt=sb-336; M=128;  lg=1; }
  const float* A = gp.w[bi];
  float* C = gp.g[bi];
  int gx = 1 << lg;
  int bx = lt & (gx-1), by = lt >> lg;
  int tx = tid & 15, ty = tid >> 4;
  int row0 = by << 6, col0 = bx << 6;
  float acc[4][4] = {};
  for (int k0 = 0; k0 < 256; k0 += 32) {
#pragma unroll
    for (int l = 0; l < 2; l++) {
      int i = tid + l*256;
      int kq = i & 7, m = i >> 3;
      float4 v = *(const float4*)(A + (size_t)(row0 + m)*256 + k0 + kq*4);
      As[kq*4+0][m] = v.x; As[kq*4+1][m] = v.y; As[kq*4+2][m] = v.z; As[kq*4+3][m] = v.w;
      float4 w = *(const float4*)(A + (size_t)(col0 + m)*256 + k0 + kq*4);
      Bs[kq*4+0][m] = w.x; Bs[kq*4+1][m] = w.y; Bs[kq*4+2][m] = w.z; Bs[kq*4+3][m] = w.w;
    }
    __syncthreads();
#pragma unroll
    for (int kk = 0; kk < 32; kk++) {
      float4 a = *(const float4*)&As[kk][ty*4];
      float4 bvv = *(const float4*)&Bs[kk][tx*4];
      float av[4] = {a.x, a.y, a.z, a.w};
      float bv[4] = {bvv.x, bvv.y, bvv.z, bvv.w};
#pragma unroll
      for (int i = 0; i < 4; i++)
#pragma unroll
        for (int j = 0; j < 4; j++)
          acc[i][j] = fmaf(av[i], bv[j], acc[i][j]);
    }
    __syncthreads();
  }
#pragma unroll
  for (int i = 0; i < 4; i++)
#pragma unroll
    for (int j = 0; j < 4; j++)
      C[(size_t)(row0 + ty*4 + i)*M + col0 + tx*4 + j] = acc[i][j];
}

// MERGED: wdist (5440 -> wdp) | gather_pool (4096). grid = 9536.
__global__ __launch_bounds__(256) void wdist_gather_k(GP gp,
    float* __restrict__ wdp, const float* __restrict__ x,
    u16* __restrict__ x2s64, u16* __restrict__ x2s32) {
  __shared__ float lds[32][130];
  __shared__ float red[256];
  int b = blockIdx.x;
  int tid = threadIdx.x;
  if (b < 5440) {
    int bi, lb, M;
    if (b < 4096)      { bi=0; lb=b;      M=1024; }
    else if (b < 5120) { bi=1; lb=b-4096; M=512; }
    else if (b < 5376) { bi=2; lb=b-5120; M=256; }
    else               { bi=3; lb=b-5376; M=128; }
    const float* G = gp.g[bi];
    int idx = lb*256 + tid;
    float acc = 0.f;
    int i = idx / M, j = idx - i*M;
    if (j > i) {
      float d2 = G[(size_t)i*M + i] + G[(size_t)j*M + j] - 2.f*G[(size_t)i*M + j];
      float dist = 1.f - d2;
      if (dist > 0.f) acc = dist;
    }
    float s = block_sum(acc, red);
    if (tid == 0) wdp[b] = s * 2.f / ((float)M * (float)(M - 1));
    return;
  }
  int gb = b - 5440;
  int orow = gb & 31, ct = (gb >> 5) & 7, bb = gb >> 8;
  const float* xb = x + ((size_t)(bb*256 + ct*32))*4096 + orow*128;
#pragma unroll
  for (int p = 0; p < 4; p++) {
    int s = p*256 + tid;
    int c = s >> 5, f = s & 31;
    float4 v = *(const float4*)(xb + (size_t)c*4096 + f*4);
    lds[c][f*4+0] = v.x; lds[c][f*4+1] = v.y;
    lds[c][f*4+2] = v.z; lds[c][f*4+3] = v.w;
  }
  __syncthreads();
  {
    int cg = (tid & 3) * 8;
#pragma unroll
    for (int it = 0; it < 2; it++) {
      int tl = it*64 + (tid >> 2);
      size_t row = ((size_t)bb*4096 + (size_t)orow*128 + tl)*256 + ct*32 + cg;
      u16 hi[8];
#pragma unroll
      for (int e = 0; e < 8; e++) hi[e] = f2bf(lds[cg + e][tl]);
      *(uint4*)&x2s64[row] = *(uint4*)hi;
    }
  }
  {
    int c = tid & 31;
#pragma unroll
    for (int p = 0; p < 4; p++) {
      int w = p*8 + (tid >> 5);
      float m = fmaxf(fmaxf(lds[c][2*w], lds[c][2*w+1]),
                      fmaxf(lds[c][64+2*w], lds[c][64+2*w+1]));
      x2s32[((size_t)bb*1024 + (size_t)orow*32 + w)*256 + ct*32 + c] = f2bf(m);
    }
  }
}

// MERGED pools: blocks <4096: blk16 = 2x2 max of blk32; blocks >=4096:
// blk8 = 4x4 max of blk32 (bitwise == 2x2 of blk16 by max associativity).
// grid = 5120.
__global__ __launch_bounds__(256) void pool_small_k(const u16* __restrict__ x2s32,
    u16* __restrict__ x2s16, u16* __restrict__ x2s8) {
  int b = blockIdx.x, c = threadIdx.x;
  if (b < 4096) {
    int t = b;
    int bb = t >> 8, rw = t & 255;
    int r = rw >> 4, w = rw & 15;
    int pb = bb*1024;
    float m = -INFINITY;
#pragma unroll
    for (int dy = 0; dy < 2; dy++)
#pragma unroll
      for (int dx = 0; dx < 2; dx++)
        m = fmaxf(m, bf2f(x2s32[(size_t)(pb + (2*r+dy)*32 + 2*w+dx)*256 + c]));
    x2s16[(size_t)t*256 + c] = f2bf(m);
  } else {
    int t = b - 4096;
    int bb = t >> 6, rw = t & 63;
    int r = rw >> 3, w = rw & 7;
    int pb = bb*1024;
    float m = -INFINITY;
#pragma unroll
    for (int dy = 0; dy < 4; dy++)
#pragma unroll
      for (int dx = 0; dx < 4; dx++)
        m = fmaxf(m, bf2f(x2s32[(size_t)(pb + (4*r+dy)*32 + 4*w+dx)*256 + c]));
    x2s8[(size_t)t*256 + c] = f2bf(m);
  }
}

// 128x128-tile, DOUBLE-BUFFERED counted-vmcnt MFMA GEMM.
// Scatter epilogue: f32 (obf=0) or bf16 (obf=1).
__global__ __launch_bounds__(256) void mgemm128db_k(MGP P) {
  __shared__ __align__(16) u16 As[2][128*64];
  __shared__ __align__(16) u16 Bs[2][128*64];
  int wg = blockIdx.x;
  int nwg = P.nwg;
  int q = nwg >> 3, r = nwg & 7;
  int xcd = wg & 7, cidx = wg >> 3;
  int swz = (xcd < r ? xcd*(q+1) : r*(q+1) + (xcd - r)*q) + cidx;
  int bi = (swz >= P.base[1]) + (swz >= P.base[2]) + (swz >= P.base[3]);
  int lt = swz - P.base[bi];
  int gx = P.gx[bi];
  int bx = lt % gx, by = lt / gx;
  const u16* A = P.A[bi];
  const u16* B = P.B[bi];
  float* C = P.C[bi];
  int K = P.K[bi], lda = P.lda[bi], ldb = P.ldb[bi];

  int tid = threadIdx.x;
  int lane = tid & 63;
  int wid = tid >> 6;
  int wr = wid >> 1, wc = wid & 1;
  int fr = lane & 15, ks = lane >> 4;
  int row0 = by << 7, col0 = bx << 7;
  f32x4 acc[4][4] = {};
  int srow = tid >> 3;
  int scol = ((tid & 7) ^ (srow & 7)) * 8;
  const u16* Ap = A + (size_t)(row0 + srow)*lda + scol;
  const u16* Bp = B + (size_t)(col0 + srow)*ldb + scol;
  char* AL = (char*)&As[0][0] + (size_t)wid*1024;
  char* BL = (char*)&Bs[0][0] + (size_t)wid*1024;
  int nt = K >> 6;

#define STAGE128(b, kt) { \
    int k0 = (kt) << 6; \
    _Pragma("unroll") \
    for (int it = 0; it < 4; it++) { \
      gload16(Ap + (size_t)(it*32)*lda + k0, AL + (b)*16384 + it*4096); \
      gload16(Bp + (size_t)(it*32)*ldb + k0, BL + (b)*16384 + it*4096); \
    } \
  }

  STAGE128(0, 0);
  for (int t = 0; t < nt; t++) {
    int b = t & 1;
    if (t + 1 < nt) {
      STAGE128(b ^ 1, t + 1);
      __builtin_amdgcn_sched_barrier(0);
      asm volatile("s_waitcnt vmcnt(8)" ::: "memory");
    } else {
      __builtin_amdgcn_sched_barrier(0);
      asm volatile("s_waitcnt vmcnt(0)" ::: "memory");
    }
    __builtin_amdgcn_sched_barrier(0);
    __builtin_amdgcn_s_barrier();
    __builtin_amdgcn_sched_barrier(0);
    {
      const u16* Ab = &As[b][0];
      const u16* Bb = &Bs[b][0];
#pragma unroll
      for (int kk = 0; kk < 2; kk++) {
        bf16x8 af[4], bg[4];
#pragma unroll
        for (int i = 0; i < 4; i++) {
          int rr = wr*64 + i*16 + fr;
          af[i] = *(const bf16x8*)&Ab[rr*64 + ((kk*32 + ks*8) ^ ((rr & 7) << 3))];
        }
#pragma unroll
        for (int j = 0; j < 4; j++) {
          int rr = wc*64 + j*16 + fr;
          bg[j] = *(const bf16x8*)&Bb[rr*64 + ((kk*32 + ks*8) ^ ((rr & 7) << 3))];
        }
        __builtin_amdgcn_s_setprio(1);
#pragma unroll
        for (int i = 0; i < 4; i++)
#pragma unroll
          for (int j = 0; j < 4; j++)
            acc[i][j] = __builtin_amdgcn_mfma_f32_16x16x32_bf16(af[i], bg[j], acc[i][j], 0, 0, 0);
        __builtin_amdgcn_s_setprio(0);
      }
    }
    __builtin_amdgcn_sched_barrier(0);
    asm volatile("s_waitcnt lgkmcnt(0)" ::: "memory");
    __builtin_amdgcn_sched_barrier(0);
    __builtin_amdgcn_s_barrier();
    __builtin_amdgcn_sched_barrier(0);
  }
#undef STAGE128

  int PP = P.ldcPP[bi];
  int obf = P.obf[bi];
#pragma unroll
  for (int i = 0; i < 4; i++) {
#pragma unroll
    for (int j = 0; j < 4; j++) {
      int row = row0 + wr*64 + i*16 + ks*4;
      int col = col0 + wc*64 + j*16 + fr;
      int bb = row / PP, rw = row - bb*PP;
      size_t o = ((size_t)(bb*P.CH[bi] + col))*PP + rw;
      if (obf) {
        u16 ov[4];
#pragma unroll
        for (int rr2 = 0; rr2 < 4; rr2++) ov[rr2] = f2bf(acc[i][j][rr2]);
        *(uint2*)&((u16*)C)[o] = *(uint2*)ov;
      } else {
        *(f32x4*)&C[o] = acc[i][j];
      }
    }
  }
}

// 256x256-tile, double-buffered, counted-vmcnt MFMA GEMM. bf16 out.
__global__ __launch_bounds__(512, 2) void mgemm256_k(MG2 P) {
  __shared__ __align__(16) u16 As[2][256*64];
  __shared__ __align__(16) u16 Bs[2][256*64];
  int wg = blockIdx.x;
  int nwg = P.nwg;
  int q = nwg >> 3, r = nwg & 7;
  int xcd = wg & 7, cidx = wg >> 3;
  int swz = (xcd < r ? xcd*(q+1) : r*(q+1) + (xcd - r)*q) + cidx;
  int bi = (swz >= P.base[1]) + (swz >= P.base[2]) + (swz >= P.base[3]);
  int lt = swz - P.base[bi];
  int gx = P.gx[bi];
  int bx = lt % gx, by = lt / gx;
  const u16* A = P.A[bi];
  const u16* Bm = P.B[bi];
  float* C = P.C[bi];
  int K = P.K[bi], lda = P.lda[bi], ldb = P.ldb[bi];
  int row0 = by << 8, col0 = bx << 8;

  int tid = threadIdx.x;
  int lane = tid & 63, wid = tid >> 6;
  int wr = wid >> 2, wc = wid & 3;
  int fr = lane & 15, ks = lane >> 4;

  int arow = tid >> 3;
  int presw = ((tid & 7) ^ (arow & 7)) * 8;
  const u16* Ap = A + (size_t)(row0 + arow)*lda + presw;
  const u16* Bp = Bm + (size_t)(col0 + arow)*ldb + presw;
  char* AL = (char*)&As[0][0] + (size_t)wid*1024;
  char* BL = (char*)&Bs[0][0] + (size_t)wid*1024;

  f32x4 acc[8][4] = {};
  int nt = K >> 6;

#define STAGE256(b, kt) { \
    int k0 = (kt) << 6; \
    _Pragma("unroll") \
    for (int ia = 0; ia < 4; ia++) \
      gload16(Ap + (size_t)(ia*64)*lda + k0, AL + (b)*32768 + ia*8192); \
    _Pragma("unroll") \
    for (int ib = 0; ib < 4; ib++) \
      gload16(Bp + (size_t)(ib*64)*ldb + k0, BL + (b)*32768 + ib*8192); \
  }

  STAGE256(0, 0);
  for (int t = 0; t < nt; t++) {
    int b = t & 1;
    if (t + 1 < nt) {
      STAGE256(b ^ 1, t + 1);
      __builtin_amdgcn_sched_barrier(0);
      asm volatile("s_waitcnt vmcnt(8)" ::: "memory");
    } else {
      __builtin_amdgcn_sched_barrier(0);
      asm volatile("s_waitcnt vmcnt(0)" ::: "memory");
    }
    __builtin_amdgcn_sched_barrier(0);
    __builtin_amdgcn_s_barrier();
    __builtin_amdgcn_sched_barrier(0);
    {
      const u16* Ab = &As[b][0];
      const u16* Bb = &Bs[b][0];
#pragma unroll
      for (int kk = 0; kk < 2; kk++) {
        bf16x8 af[8], bg[4];
#pragma unroll
        for (int i = 0; i < 8; i++) {
          int rr = wr*128 + i*16 + fr;
          af[i] = *(const bf16x8*)&Ab[rr*64 + ((kk*32 + ks*8) ^ ((rr & 7) << 3))];
        }
#pragma unroll
        for (int j = 0; j < 4; j++) {
          int rr = wc*64 + j*16 + fr;
          bg[j] = *(const bf16x8*)&Bb[rr*64 + ((kk*32 + ks*8) ^ ((rr & 7) << 3))];
        }
        __builtin_amdgcn_s_setprio(1);
#pragma unroll
        for (int i = 0; i < 8; i++)
#pragma unroll
          for (int j = 0; j < 4; j++)
            acc[i][j] = __builtin_amdgcn_mfma_f32_16x16x32_bf16(af[i], bg[j], acc[i][j], 0, 0, 0);
        __builtin_amdgcn_s_setprio(0);
      }
    }
    __builtin_amdgcn_sched_barrier(0);
    asm volatile("s_waitcnt lgkmcnt(0)" ::: "memory");
    __builtin_amdgcn_sched_barrier(0);
    __builtin_amdgcn_s_barrier();
    __builtin_amdgcn_sched_barrier(0);
  }
#undef STAGE256

#pragma unroll
  for (int i = 0; i < 8; i++) {
#pragma unroll
    for (int j = 0; j < 4; j++) {
      int row = row0 + wr*128 + i*16 + ks*4;
      int col = col0 + wc*64 + j*16 + fr;
      u16* Cb = (u16*)C;
      int ldc = P.ldcPP[bi];
#pragma unroll
      for (int rr = 0; rr < 4; rr++)
        Cb[(size_t)(row + rr)*ldc + col] = f2bf(acc[i][j][rr]);
    }
  }
}

// One WAVE per token row; vectorized; writes att IN PLACE over S.
template<int R>
__device__ __forceinline__ void row_fin_body(u16* __restrict__ S_all,
    const u16* __restrict__ x2s, const float* __restrict__ Wm,
    int Tblock, float* __restrict__ part, int t, int ldS) {
  int lane = threadIdx.x & 63;
  u16* S = S_all + (size_t)t*ldS + lane*R;
  u16 sv[R];
  if constexpr (R == 16) {
    *(uint4*)&sv[0] = *(const uint4*)&S[0];
    *(uint4*)&sv[8] = *(const uint4*)&S[8];
  } else if constexpr (R == 8) {
    *(uint4*)&sv[0] = *(const uint4*)&S[0];
  } else if constexpr (R == 4) {
    *(uint2*)&sv[0] = *(const uint2*)&S[0];
  } else {
    *(unsigned*)&sv[0] = *(const unsigned*)&S[0];
  }
  float s[R];
#pragma unroll
  for (int i = 0; i < R; i++) s[i] = bf2f(sv[i]);

  float v0 = -INFINITY, v1 = -INFINITY; int j0 = 0x7fffffff, j1 = 0x7fffffff;
#pragma unroll
  for (int i = 0; i < R; i++) {
    int j = lane*R + i; float sx = s[i];
    if (sx > v0) { v1 = v0; j1 = j0; v0 = sx; j0 = j; }
    else if (sx > v1) { v1 = sx; j1 = j; }
  }
#pragma unroll
  for (int m = 32; m > 0; m >>= 1) {
    float b0 = __shfl_xor(v0, m, 64); int bi0 = __shfl_xor(j0, m, 64);
    float b1 = __shfl_xor(v1, m, 64); int bi1 = __shfl_xor(j1, m, 64);
    if (b0 > v0 || (b0 == v0 && bi0 < j0)) {
      if (v0 > b1 || (v0 == b1 && j0 < bi1)) { v1 = v0; j1 = j0; }
      else { v1 = b1; j1 = bi1; }
      v0 = b0; j0 = bi0;
    } else {
      if (b0 > v1 || (b0 == v1 && bi0 < j1)) { v1 = b0; j1 = bi0; }
    }
  }

  float z = 0.f;
#pragma unroll
  for (int i = 0; i < R; i++) { float p = expf(s[i] - v0); z += p; s[i] = p; }
  z = wave_sum(z);
  float invZ = 1.f / z;

  float l1 = 0.f;
#pragma unroll
  for (int i = 0; i < R; i++) {
    float attv = s[i] * invZ;
    float r = attv - 0.0025f;
    float a = (r > 0.f) ? (r * attv / (r + 1e-12f)) : 0.f;
    l1 += a; s[i] = a;
  }
  l1 = wave_sum(l1);
  float inv = 1.f / fmaxf(l1, 1e-12f);

  u16 ov[R];
  float e = 0.f;
#pragma unroll
  for (int i = 0; i < R; i++) {
    float an = s[i] * inv;
    ov[i] = f2bf(an);
    if (an > 0.f) e += an * logf(an + 1e-12f);
  }
  if constexpr (R == 16) {
    *(uint4*)&S[0] = *(uint4*)&ov[0];
    *(uint4*)&S[8] = *(uint4*)&ov[8];
  } else if constexpr (R == 8) {
    *(uint4*)&S[0] = *(uint4*)&ov[0];
  } else if constexpr (R == 4) {
    *(uint2*)&S[0] = *(uint2*)&ov[0];
  } else {
    *(unsigned*)&S[0] = *(unsigned*)&ov[0];
  }

  float dp2 = 0.f, dn2 = 0.f, cq2 = 0.f;
  const u16* xr = x2s + (size_t)t*256;
  const float* pw = Wm + (size_t)j0*256;
  const float* nw = Wm + (size_t)j1*256;
#pragma unroll
  for (int k2 = 0; k2 < 4; k2++) {
    int c = lane + k2*64;
    float xv = bf2f(xr[c]);
    float p = pw[c], n = nw[c];
    float dp = xv - p + 1e-6f, dn = xv - n + 1e-6f, cq = xv - p;
    dp2 += dp*dp; dn2 += dn*dn; cq2 += cq*cq;
  }
  e = wave_sum(e); dp2 = wave_sum(dp2); dn2 = wave_sum(dn2); cq2 = wave_sum(cq2);
  if (lane == 0) {
    int slot = t & 1023;
    float trip = fmaxf(sqrtf(dp2) - sqrtf(dn2) + 1.f, 0.f);
    atomicAdd(&part[0*1024 + slot], -e / (float)Tblock);
    atomicAdd(&part[1*1024 + slot], trip / (float)Tblock);
    atomicAdd(&part[2*1024 + slot], cq2 / ((float)Tblock * 256.f));
  }
}

// Merged finalize. grid = 21760 (4 waves = 4 tokens/WG).
__global__ __launch_bounds__(256) void row_fin_all_k(RFP P, float* __restrict__ part) {
  int b = blockIdx.x;
  int bi = (b >= 16384) + (b >= 20480) + (b >= 21504);
  int lb = b - (bi == 0 ? 0 : bi == 1 ? 16384 : bi == 2 ? 20480 : 21504);
  int t = lb*4 + (threadIdx.x >> 6);
  switch (bi) {
    case 0: row_fin_body<16>(P.S[0], P.x2[0], P.W[0], P.T[0], part, t, P.ldS[0]); break;
    case 1: row_fin_body<8> (P.S[1], P.x2[1], P.W[1], P.T[1], part, t, P.ldS[1]); break;
    case 2: row_fin_body<4> (P.S[2], P.x2[2], P.W[2], P.T[2], part, t, P.ldS[2]); break;
    default:row_fin_body<2> (P.S[3], P.x2[3], P.W[3], P.T[3], part, t, P.ldS[3]); break;
  }
}

// MERGED: bilinear upsample (3*16384) | loss finalize (5 blocks). grid = 49157.
__global__ __launch_bounds__(256) void upsample_loss_k(UP up, float* __restrict__ out,
    const float* __restrict__ part, const float* __restrict__ wnp,
    const float* __restrict__ wdp, float* __restrict__ losses) {
  __shared__ float red[256];
  int b = blockIdx.x;
  int tid = threadIdx.x;
  if (b >= 49152) {
    int l = b - 49152;
    float v = 0.f;
    if (l < 3) {
      for (int i = tid; i < 1024; i += 256) v += part[l*1024 + i];
    } else if (l == 3) {
      for (int i = tid; i < 1920; i += 256) v += wnp[i];
    } else {
      for (int i = tid; i < 5440; i += 256) v += wdp[i];
    }
    float s = block_sum(v, red);
    if (tid == 0) {
      int dst = (l == 0) ? 0 : (l == 1) ? 1 : (l == 2) ? 3 : (l == 3) ? 2 : 4;
      losses[dst] = s;
    }
    return;
  }
  int ri = b >> 14;
  int blk = 32 >> ri;
  int coff = (ri + 1) * 256;
  const u16* rec = up.rec[ri];
  int idx = (b & 16383)*256 + tid;
  int w4 = (idx & 15) * 4;
  int r = (idx >> 4) & 63;
  int c = (idx >> 10) & 255;
  int bb = idx >> 18;
  float s = (float)blk * (1.f/64.f);
  float py = ((float)r + 0.5f)*s - 0.5f;
  float fy0 = floorf(py);
  float fy = py - fy0;
  int y0 = (int)fy0;
  int y0c = min(max(y0, 0), blk-1), y1c = min(max(y0+1, 0), blk-1);
  const u16* rp = rec + (size_t)(bb*256 + c)*blk*blk;
  const u16* r0 = rp + y0c*blk;
  const u16* r1 = rp + y1c*blk;
  float ov[4];
#pragma unroll
  for (int e = 0; e < 4; e++) {
    int w = w4 + e;
    float px = ((float)w + 0.5f)*s - 0.5f;
    float fx0 = floorf(px);
    float fx = px - fx0;
    int x0 = (int)fx0;
    int x0c = min(max(x0, 0), blk-1), x1c = min(max(x0+1, 0), blk-1);
    float v00 = bf2f(r0[x0c]), v01 = bf2f(r0[x1c]);
    float v10 = bf2f(r1[x0c]), v11 = bf2f(r1[x1c]);
    ov[e] = (1.f-fy)*((1.f-fx)*v00 + fx*v01) + fy*((1.f-fx)*v10 + fx*v11);
  }
  *(float4*)&out[((size_t)(bb*1024 + coff + c) << 12) + (r << 6) + w4] = *(float4*)ov;
}

extern "C" void kernel_launch(void* const* d_in, const int* in_sizes, int n_in,
                              void* d_out, int out_size, void* d_ws, size_t ws_size,
                              hipStream_t stream) {
  const float* x = (const float*)d_in[0];
  GP gp;
  gp.w[0] = (const float*)d_in[2]; gp.w[1] = (const float*)d_in[3];
  gp.w[2] = (const float*)d_in[4]; gp.w[3] = (const float*)d_in[5];
  float* out = (float*)d_out;
  float* losses = out + OUTC;

  char* ws = (char*)d_ws;
  size_t off = 0;
  u16* rec32 = (u16*)(ws + off); off += (size_t)16384*256*2;
  u16* rec16 = (u16*)(ws + off); off += (size_t)4096*256*2;
  u16* rec8  = (u16*)(ws + off); off += (size_t)1024*256*2;
  float* part  = (float*)(ws + off); off += 3*1024*4;
  float* wnp   = (float*)(ws + off); off += 1920*4;
  float* wdp   = (float*)(ws + off); off += 5440*4;
  off = (off + 255) & ~(size_t)255;
  u16* Ws1 = (u16*)(ws + off); off += (size_t)2048*256*2;
  u16* Ws2 = (u16*)(ws + off); off += (size_t)256*1920*2;
  gp.g[0] = (float*)(ws + off); off += (size_t)1024*1024*4;
  gp.g[1] = (float*)(ws + off); off += (size_t)512*512*4;
  gp.g[2] = (float*)(ws + off); off += (size_t)256*256*4;
  gp.g[3] = (float*)(ws + off); off += (size_t)128*128*4;
  u16* x2s64 = (u16*)(ws + off); off += (size_t)65536*256*2;
  u16* x2s32 = (u16*)(ws + off); off += (size_t)16384*256*2;
  u16* x2s16 = (u16*)(ws + off); off += (size_t)4096*256*2;
  u16* x2s8  = (u16*)(ws + off); off += (size_t)1024*256*2;
  u16* S64 = (u16*)(ws + off); off += (size_t)65536*1024*2;
  u16* S32 = (u16*)(ws + off); off += (size_t)16384*512*2;
  u16* S16 = (u16*)(ws + off); off += (size_t)4096*256*2;
  u16* S8  = (u16*)(ws + off); off += (size_t)1024*256*2;

  const size_t s1off[4] = {0, (size_t)1024*256, (size_t)1536*256, (size_t)1792*256};
  const size_t s2off[4] = {0, (size_t)256*1024, (size_t)256*1536, (size_t)256*1792};
  const u16* x2Arr[4] = {x2s64, x2s32, x2s16, x2s8};
  u16* SArr[4] = {S64, S32, S16, S8};
  const int MS[4] = {1024, 512, 256, 128};
  const int ldSArr[4] = {1024, 512, 256, 256};

  prep_k<<<2400, 256, 0, stream>>>(gp, Ws1, Ws2, part, wnp);
  wdist_gather_k<<<9536, 256, 0, stream>>>(gp, wdp, x, x2s64, x2s32);
  pool_small_k<<<5120, 256, 0, stream>>>(x2s32, x2s16, x2s8);

  // ALL logits GEMMs on 256-tile kernel: Sb(bf16) = x2_hi * Ws1^T, K=256
  MG2 L2;
  {
    int base = 0;
    for (int bi = 0; bi < 3; bi++) {
      L2.A[bi] = x2Arr[bi]; L2.B[bi] = Ws1 + s1off[bi]; L2.C[bi] = (float*)SArr[bi];
      L2.K[bi] = 256; L2.lda[bi] = 256; L2.ldb[bi] = 256;
      L2.ldcPP[bi] = MS[bi]; L2.CH[bi] = 0;
      L2.gx[bi] = MS[bi]/256;
      L2.base[bi] = base;
      int T = 65536 >> (2*bi);
      base += (MS[bi]/256) * (T/256);
    }
    L2.A[3] = x2s8; L2.B[3] = Ws1 + s1off[3]; L2.C[3] = (float*)S8;
    L2.K[3] = 256; L2.lda[3] = 256; L2.ldb[3] = 256; L2.ldcPP[3] = 256; L2.CH[3] = 0;
    L2.gx[3] = 1; L2.base[3] = base;
    base += 4;
    L2.nwg = base;  // 1172
  }
  mgemm256_k<<<L2.nwg, 512, 0, stream>>>(L2);

  // merged row finalize (in-place att over S)
  RFP R;
  for (int bi = 0; bi < 4; bi++) {
    R.S[bi] = SArr[bi]; R.x2[bi] = x2Arr[bi];
    R.W[bi] = gp.w[bi]; R.T[bi] = 65536 >> (2*bi);
    R.ldS[bi] = ldSArr[bi];
  }
  row_fin_all_k<<<21760, 256, 0, stream>>>(R, part);

  // merged attn GEMMs on 128^2 double-buffered kernel: C = att(in S) * Ws2^T
  MGP A;
  float* recArr[4] = {out, (float*)rec32, (float*)rec16, (float*)rec8};
  {
    int base = 0;
    for (int bi = 0; bi < 4; bi++) {
      A.A[bi] = SArr[bi]; A.B[bi] = Ws2 + s2off[bi]; A.C[bi] = recArr[bi];
      A.K[bi] = MS[bi]; A.lda[bi] = ldSArr[bi]; A.ldb[bi] = MS[bi];
      A.ldcPP[bi] = (bi == 0) ? 4096 : (4096 >> (2*bi));
      A.CH[bi] = (bi == 0) ? 1024 : 256;
      A.obf[bi] = (bi == 0) ? 0 : 1;
      A.gx[bi] = 2;
      A.base[bi] = base;
      int T = 65536 >> (2*bi);
      base += 2 * (T/128);
    }
    A.nwg = base;  // 1360
  }
  mgemm128db_k<<<A.nwg, 256, 0, stream>>>(A);

  UP up; up.rec[0] = rec32; up.rec[1] = rec16; up.rec[2] = rec8;
  upsample_loss_k<<<3*16384 + 5, 256, 0, stream>>>(up, out, part, wnp, wdp, losses);
}